// Round 2
// baseline (347.738 us; speedup 1.0000x reference)
//
#include <hip/hip_runtime.h>
#include <math.h>

#define B_ 8
#define S_ 1024
#define D_ 1024
#define H_ 16
#define DK_ 64
#define EPS_ 1e-5f

typedef __bf16 bf16_t;
typedef __bf16 bf16x8 __attribute__((ext_vector_type(8)));
typedef __bf16 bf16x4v __attribute__((ext_vector_type(4)));
typedef float  f32x4  __attribute__((ext_vector_type(4)));

__device__ __forceinline__ void gld16(const void* g, void* l) {
    __builtin_amdgcn_global_load_lds(
        (const __attribute__((address_space(1))) void*)g,
        (__attribute__((address_space(3))) void*)l, 16, 0, 0);
}

// ---------------------------------------------------------------------------
// prep: fused weight transpose+convert (z=0..4) and x f32->bf16 (z=5..36).
// ---------------------------------------------------------------------------
__global__ __launch_bounds__(256)
void prep(const float* __restrict__ x,
          const float* __restrict__ Wq, const float* __restrict__ Wk,
          const float* __restrict__ Wv, const float* __restrict__ W1,
          const float* __restrict__ W2, bf16_t* __restrict__ xb,
          bf16_t* __restrict__ WtQKV, bf16_t* __restrict__ Wt1,
          bf16_t* __restrict__ Wt2)
{
    __shared__ float tile[64][65];
    const int tid = threadIdx.x;
    const int z = blockIdx.z;

    if (z >= 5) {   // x convert
        const int blk = (z - 5) * 256 + blockIdx.y * 16 + blockIdx.x;
        const int i = (blk * 256 + tid) * 4;
        const float4 v = *(const float4*)(x + i);
        bf16x4v o = { (bf16_t)v.x, (bf16_t)v.y, (bf16_t)v.z, (bf16_t)v.w };
        *(bf16x4v*)(xb + i) = o;
        return;
    }

    const int n0 = blockIdx.x * 64, k0 = blockIdx.y * 64;
    const int col = tid & 63, r0 = tid >> 6;
    const float* src = (z == 0) ? Wq : (z == 1) ? Wk : (z == 2) ? Wv
                     : (z == 3) ? W1 : W2;
    #pragma unroll
    for (int i = 0; i < 16; i++) {
        const int row = r0 + i * 4;
        float v;
        if (z < 3)
            v = src[((size_t)(n0 >> 6) << 16) + (size_t)(k0 + row) * 64 + col];
        else
            v = src[(size_t)(k0 + row) * D_ + n0 + col];
        tile[row][col] = v;
    }
    __syncthreads();
    bf16_t* dst = (z < 3) ? (WtQKV + (size_t)z * D_ * D_)
                : (z == 3) ? Wt1 : Wt2;
    #pragma unroll
    for (int i = 0; i < 16; i++) {
        const int nr = r0 + i * 4;
        dst[(size_t)(n0 + nr) * D_ + k0 + col] = (bf16_t)tile[col][nr];
    }
}

// ---------------------------------------------------------------------------
// 256x256 8-phase bf16 MFMA GEMM (T2+T3+T4+T5 per the learn_hip template).
//   - 512 thr (8 waves, 2M x 4N), per-wave 128x64 out, acc[8][4] f32x4.
//   - BK=64, LDS As/Bs[2][256][64] = 128 KiB, 1 block/CU.
//   - Staging: global_load_lds w=16, one QUADRANT-ALIGNED half-tile/phase
//     (A-half h = rows {blk*128 + h*64 + 0..63}, B-half h = rows
//     {blk*64 + h*32 + 0..31}), one K-tile ahead into buf^1. T2 XOR
//     swizzle slot^=(row&7) applied on the pre-swizzled GLOBAL source
//     (LDS dest linear, as global_load_lds requires).
//   - Phases/K-tile: A:Q00(rd A0,B0; stg A0') B:Q01(rd B1; stg B0')
//     C:Q11(rd A1; stg B1') D:Q10(regs; stg A1'). 16 MFMA each, setprio(1)
//     wrapped. Raw s_barrier (NOT __syncthreads -> no vmcnt(0) drain);
//     counted vmcnt(4) at end of A, B, D only (2 newest half-tiles stay
//     in flight across barriers). EPI: 0 plain; 1 +bias,relu,mask;
//     2 +bias,mask.
// ---------------------------------------------------------------------------
template<int EPI, typename OUT>
__global__ __launch_bounds__(512, 2)
void gemm8(const bf16_t* __restrict__ A, const bf16_t* __restrict__ Bw,
           const float* __restrict__ bias, const int* __restrict__ lens,
           OUT* __restrict__ C, int M, int N, int K)
{
    __shared__ __align__(16) bf16_t As[2][256 * 64];
    __shared__ __align__(16) bf16_t Bs[2][256 * 64];

    const int tid  = threadIdx.x;
    const int lane = tid & 63;
    const int w    = tid >> 6;
    const int quad = lane >> 4, l16 = lane & 15;
    const int wm = w & 1, wn = w >> 1;
    const int bn = blockIdx.x * 256, bm = blockIdx.y * 256;
    const int sw8 = l16 & 7;

    // staging geometry: half-tile = 1024 chunks(16B), 2 chunks/thread.
    const int ci0 = tid, ci1 = tid + 512;
    // A-halves (qm-aligned): row = ablk*128 + h*64 + rr
    const int aB0 = ci0 >> 9, aR0 = (ci0 >> 3) & 63;
    const int aC0 = (((ci0 & 7) ^ (aR0 & 7)) << 3);
    const int aB1 = ci1 >> 9, aR1 = (ci1 >> 3) & 63;
    const int aC1 = (((ci1 & 7) ^ (aR1 & 7)) << 3);
    // B-halves (qn-aligned): row = bblk*64 + h*32 + rr
    const int bB0 = ci0 >> 8, bR0 = (ci0 >> 3) & 31;
    const int bC0 = (((ci0 & 7) ^ (bR0 & 7)) << 3);
    const int bB1 = ci1 >> 8, bR1 = (ci1 >> 3) & 31;
    const int bC1 = (((ci1 & 7) ^ (bR1 & 7)) << 3);
    // wave-uniform LDS dest byte offsets (intrinsic adds lane*16)
    const int u0 = w * 64, u1 = 512 + w * 64;
    const int adD0 = (u0 >> 9) * 16384 + (u0 & 511) * 16;
    const int adD1 = (u1 >> 9) * 16384 + (u1 & 511) * 16;
    const int bdD0 = (u0 >> 8) * 8192 + (u0 & 255) * 16;
    const int bdD1 = (u1 >> 8) * 8192 + (u1 & 255) * 16;

    f32x4 acc[8][4];
    #pragma unroll
    for (int i = 0; i < 8; i++)
        #pragma unroll
        for (int j = 0; j < 4; j++)
            #pragma unroll
            for (int r = 0; r < 4; r++) acc[i][j][r] = 0.f;

#define STAGE_A(h, nb_, kt_) { \
    char* d_ = (char*)As[nb_] + (h) * 8192; \
    gld16(A + (size_t)(bm + aB0 * 128 + (h) * 64 + aR0) * K + (kt_) * 64 + aC0, d_ + adD0); \
    gld16(A + (size_t)(bm + aB1 * 128 + (h) * 64 + aR1) * K + (kt_) * 64 + aC1, d_ + adD1); }
#define STAGE_B(h, nb_, kt_) { \
    char* d_ = (char*)Bs[nb_] + (h) * 4096; \
    gld16(Bw + (size_t)(bn + bB0 * 64 + (h) * 32 + bR0) * K + (kt_) * 64 + bC0, d_ + bdD0); \
    gld16(Bw + (size_t)(bn + bB1 * 64 + (h) * 32 + bR1) * K + (kt_) * 64 + bC1, d_ + bdD1); }
#define RD_A(dst, base, qm_, i_, kh_) \
    dst = *(const bf16x8*)&base[(wm * 128 + (qm_) * 64 + (i_) * 16 + l16) * 64 + ((((kh_) * 4 + quad) ^ sw8) << 3)];
#define RD_B(dst, base, qn_, j_, kh_) \
    dst = *(const bf16x8*)&base[(wn * 64 + (qn_) * 32 + (j_) * 16 + l16) * 64 + ((((kh_) * 4 + quad) ^ sw8) << 3)];
#define MM(QI, QJ, AF, BF) \
    _Pragma("unroll") \
    for (int kh_ = 0; kh_ < 2; kh_++) \
        _Pragma("unroll") \
        for (int i_ = 0; i_ < 4; i_++) \
            _Pragma("unroll") \
            for (int j_ = 0; j_ < 2; j_++) \
                acc[(QI) * 4 + i_][(QJ) * 2 + j_] = __builtin_amdgcn_mfma_f32_16x16x32_bf16( \
                    AF[i_][kh_], BF[j_][kh_], acc[(QI) * 4 + i_][(QJ) * 2 + j_], 0, 0, 0);
#define MIDBAR() { __builtin_amdgcn_s_barrier(); \
    asm volatile("s_waitcnt lgkmcnt(0)" ::: "memory"); }

    const int NKT = K >> 6;

    // prologue: tile 0 -> buf 0, steady-state issue order (A0, B0, B1, A1)
    STAGE_A(0, 0, 0);
    STAGE_B(0, 0, 0);
    STAGE_B(1, 0, 0);
    STAGE_A(1, 0, 0);
    asm volatile("s_waitcnt vmcnt(4)" ::: "memory");
    __builtin_amdgcn_s_barrier();

    for (int t = 0; t < NKT; ++t) {
        const int cb = t & 1, nb = cb ^ 1;
        const int ktn = (t + 1 < NKT) ? t + 1 : t;   // clamped tail reload
        const bf16_t* Ac = As[cb];
        const bf16_t* Bc = Bs[cb];

        // ---- Phase A: Q00 (reads A0,B0; stages A0(t+1)) ----
        bf16x8 fa[4][2], fb[2][2];
        #pragma unroll
        for (int i = 0; i < 4; i++) { RD_A(fa[i][0], Ac, 0, i, 0); RD_A(fa[i][1], Ac, 0, i, 1); }
        #pragma unroll
        for (int j = 0; j < 2; j++) { RD_B(fb[j][0], Bc, 0, j, 0); RD_B(fb[j][1], Bc, 0, j, 1); }
        STAGE_A(0, nb, ktn);
        MIDBAR();
        __builtin_amdgcn_s_setprio(1);
        MM(0, 0, fa, fb);
        __builtin_amdgcn_s_setprio(0);
        asm volatile("s_waitcnt vmcnt(4)" ::: "memory");   // B1(t) landed
        __builtin_amdgcn_s_barrier();

        // ---- Phase B: Q01 (reads B1; stages B0(t+1)) ----
        bf16x8 gb[2][2];
        #pragma unroll
        for (int j = 0; j < 2; j++) { RD_B(gb[j][0], Bc, 1, j, 0); RD_B(gb[j][1], Bc, 1, j, 1); }
        STAGE_B(0, nb, ktn);
        MIDBAR();
        __builtin_amdgcn_s_setprio(1);
        MM(0, 1, fa, gb);
        __builtin_amdgcn_s_setprio(0);
        asm volatile("s_waitcnt vmcnt(4)" ::: "memory");   // A1(t) landed
        __builtin_amdgcn_s_barrier();

        // ---- Phase C: Q11 (reads A1; stages B1(t+1)) ----
        bf16x8 ga[4][2];
        #pragma unroll
        for (int i = 0; i < 4; i++) { RD_A(ga[i][0], Ac, 1, i, 0); RD_A(ga[i][1], Ac, 1, i, 1); }
        STAGE_B(1, nb, ktn);
        MIDBAR();
        __builtin_amdgcn_s_setprio(1);
        MM(1, 1, ga, gb);
        __builtin_amdgcn_s_setprio(0);
        __builtin_amdgcn_s_barrier();                      // no vmcnt here

        // ---- Phase D: Q10 (register-only; stages A1(t+1)) ----
        STAGE_A(1, nb, ktn);
        MIDBAR();
        __builtin_amdgcn_s_setprio(1);
        MM(1, 0, ga, fb);
        __builtin_amdgcn_s_setprio(0);
        asm volatile("s_waitcnt vmcnt(4)" ::: "memory");   // A0,B0(t+1) landed
        __builtin_amdgcn_s_barrier();
    }

#undef STAGE_A
#undef STAGE_B
#undef RD_A
#undef RD_B
#undef MM
#undef MIDBAR

    // ---- epilogue ----
    #pragma unroll
    for (int ii = 0; ii < 8; ii++) {
        #pragma unroll
        for (int r = 0; r < 4; r++) {
            const int m = bm + wm * 128 + (ii >> 2) * 64 + (ii & 3) * 16 + quad * 4 + r;
            float keep = 1.f;
            if (EPI != 0) {
                const int s = m & (S_ - 1);
                const int bb = m >> 10;
                keep = (s < lens[bb]) ? 1.f : 0.f;
            }
            #pragma unroll
            for (int jj = 0; jj < 4; jj++) {
                const int n = bn + wn * 64 + (jj >> 1) * 32 + (jj & 1) * 16 + l16;
                float v = acc[ii][jj][r];
                if (EPI != 0) {
                    v += bias[n];
                    if (EPI == 1) v = fmaxf(v, 0.f);
                    v *= keep;
                }
                C[(size_t)m * N + n] = (OUT)v;
            }
        }
    }
}

// ---------------------------------------------------------------------------
// bf16 MFMA flash attention, S^T formulation — R6: software-pipelined k-loop.
// ---------------------------------------------------------------------------
__global__ __launch_bounds__(256, 3)
void attn_mfma(const bf16_t* __restrict__ QKV, const int* __restrict__ lens,
               bf16_t* __restrict__ Z)
{
    __shared__ __align__(16) bf16_t Ks[2][64][64];   // [buf][key][d], chunk-swizzled
    __shared__ __align__(16) bf16_t Vt[2][64][72];   // [buf][d][key ^ 16*(d>>4)]
    __shared__ __align__(16) bf16_t Ps[64][72];      // [q][key], wave-private rows

    const int tid  = threadIdx.x;
    const int lane = tid & 63;
    const int w    = tid >> 6;
    const int quad = lane >> 4;
    const int l16  = lane & 15;
    const int id   = blockIdx.x;
    const int b    = id & 7;            // b fastest -> CU-load balance
    const int h    = (id >> 3) & 15;
    const int qt   = id >> 7;
    const int len  = lens[b];
    const int qbase = qt * 64;
    const bf16_t* Qp = QKV + (size_t)b * S_ * 3072 + (size_t)h * 64;
    const bf16_t* Kp = Qp + 1024;
    const bf16_t* Vp = Qp + 2048;
    const size_t zbase = (size_t)b * S_ * D_ + (size_t)h * 64;

    if (qbase >= len) {   // fully masked query tile -> zeros (bf16)
        const int r = tid >> 2, c0 = (tid & 3) * 16;
        bf16_t* zp = Z + zbase + (size_t)(qbase + r) * D_ + c0;
        uint4 zz = {0u, 0u, 0u, 0u};
        *(uint4*)zp = zz;
        *(uint4*)(zp + 8) = zz;
        return;
    }

    // Q B-frags, fixed for the whole kernel: B[k=d=quad*8+j][n=q=l16]
    const int qrow = qbase + w * 16 + l16;
    const bf16x8 bq0 = *(const bf16x8*)(Qp + (size_t)qrow * 3072 + quad * 8);
    const bf16x8 bq1 = *(const bf16x8*)(Qp + (size_t)qrow * 3072 + 32 + quad * 8);

    // K staging geometry: 2 shots of 256 lanes x 16B cover [64][64] bf16.
    const int kr0  = tid >> 3;          // shot0 row (0..31); shot1 row = kr0+32
    const int kpos = tid & 7;
    const int kc0  = (kpos ^ (kr0 & 7)) << 3;          // shot0 source d-offset
    const int kc1  = (kpos ^ ((kr0 + 32) & 7)) << 3;   // shot1 source d-offset

    // V staging map: thread -> key row vr, d cols vc0..vc0+15, swizzled col vp
    const int vr  = tid >> 2;
    const int vc0 = (tid & 3) * 16;
    const int vp  = vr ^ ((tid & 3) << 4);

    f32x4 o[4];
    #pragma unroll
    for (int dm = 0; dm < 4; dm++)
        #pragma unroll
        for (int r = 0; r < 4; r++) o[dm][r] = 0.f;
    float l_q = 0.f;

    const int ntiles = (len + 63) >> 6;

    // ---- prologue: stage K(0) -> Ks[0], load V(0) into regs ----
    gld16(Kp + (size_t)kr0 * 3072 + kc0,
          (char*)&Ks[0][0][0] + (size_t)(w * 64) * 16);
    gld16(Kp + (size_t)(kr0 + 32) * 3072 + kc1,
          (char*)&Ks[0][0][0] + (size_t)(256 + w * 64) * 16);
    bf16x8 vcur0 = *(const bf16x8*)(Vp + (size_t)vr * 3072 + vc0);
    bf16x8 vcur1 = *(const bf16x8*)(Vp + (size_t)vr * 3072 + vc0 + 8);
    __syncthreads();   // vmcnt(0) drain: Ks[0] ready

    for (int t = 0; t < ntiles; t++) {
        const int k0 = t * 64;
        const int cb = t & 1, nb = (t + 1) & 1;
        const int kn0 = (t + 1 < ntiles ? t + 1 : t) * 64;

        // ---- issue prefetch for tile t+1 (K -> Ks[nb], V -> regs) ----
        gld16(Kp + (size_t)(kn0 + kr0) * 3072 + kc0,
              (char*)&Ks[nb][0][0] + (size_t)(w * 64) * 16);
        gld16(Kp + (size_t)(kn0 + kr0 + 32) * 3072 + kc1,
              (char*)&Ks[nb][0][0] + (size_t)(256 + w * 64) * 16);
        const bf16_t* vsrc = Vp + (size_t)(kn0 + vr) * 3072 + vc0;
        const bf16x8 vn0 = *(const bf16x8*)vsrc;
        const bf16x8 vn1 = *(const bf16x8*)(vsrc + 8);
        __builtin_amdgcn_sched_barrier(0);   // pin prefetch issue at loop top

        // ---- S^T = K Q^T from Ks[cb], exp, stage P ----
        #pragma unroll
        for (int kt = 0; kt < 4; kt++) {
            const int r = kt * 16 + l16;           // r&7 == l16&7
            const bf16x8 ak0 = *(const bf16x8*)&Ks[cb][r][(quad ^ (l16 & 7)) << 3];
            const bf16x8 ak1 = *(const bf16x8*)&Ks[cb][r][((4 + quad) ^ (l16 & 7)) << 3];
            f32x4 z4 = {0.f, 0.f, 0.f, 0.f};
            z4 = __builtin_amdgcn_mfma_f32_16x16x32_bf16(ak0, bq0, z4, 0, 0, 0);
            const f32x4 sfv = __builtin_amdgcn_mfma_f32_16x16x32_bf16(ak1, bq1, z4, 0, 0, 0);
            bf16x4v pk;
            #pragma unroll
            for (int r2 = 0; r2 < 4; r2++) {
                const int key = k0 + kt * 16 + quad * 4 + r2;
                float p = __expf(sfv[r2] * 0.125f);
                p = (key < len) ? p : 0.f;
                l_q += p;
                pk[r2] = (bf16_t)p;
            }
            *(bf16x4v*)&Ps[w * 16 + l16][kt * 16 + quad * 4] = pk;
        }

        // ---- scatter V(t) regs -> Vt[cb] (transposed + XOR swizzle) ----
        #pragma unroll
        for (int i = 0; i < 8; i++) Vt[cb][vc0 + i][vp] = vcur0[i];
        #pragma unroll
        for (int i = 0; i < 8; i++) Vt[cb][vc0 + 8 + i][vp] = vcur1[i];
        vcur0 = vn0;
        vcur1 = vn1;
        __syncthreads();   // single barrier/iter

        // ---- O^T += V^T P^T ----
        const bf16x8 bp0 = *(const bf16x8*)&Ps[w * 16 + l16][quad * 8];
        const bf16x8 bp1 = *(const bf16x8*)&Ps[w * 16 + l16][32 + quad * 8];
        #pragma unroll
        for (int dm = 0; dm < 4; dm++) {
            const bf16x8 av0 = *(const bf16x8*)&Vt[cb][dm * 16 + l16][(quad * 8) ^ (dm * 16)];
            const bf16x8 av1 = *(const bf16x8*)&Vt[cb][dm * 16 + l16][(32 + quad * 8) ^ (dm * 16)];
            o[dm] = __builtin_amdgcn_mfma_f32_16x16x32_bf16(av0, bp0, o[dm], 0, 0, 0);
            o[dm] = __builtin_amdgcn_mfma_f32_16x16x32_bf16(av1, bp1, o[dm], 0, 0, 0);
        }
    }

    // ---- final l reduce + epilogue ----
    l_q += __shfl_xor(l_q, 16);
    l_q += __shfl_xor(l_q, 32);
    const int qg = qbase + w * 16 + l16;
    const float inv = (qg < len) ? 1.f / l_q : 0.f;
    bf16_t* zrow = Z + zbase + (size_t)qg * D_;
    #pragma unroll
    for (int dm = 0; dm < 4; dm++) {
        bf16x4v st;
        #pragma unroll
        for (int r = 0; r < 4; r++) st[r] = (bf16_t)(o[dm][r] * inv);
        *(bf16x4v*)(zrow + dm * 16 + quad * 4) = st;
    }
}

// ---------------------------------------------------------------------------
// Residual-add + LayerNorm, D=1024, one block per row.
// ---------------------------------------------------------------------------
__device__ __forceinline__ void ln_core(float vx, float vy, float vz, float vw,
                                        int tid, float& mean, float& rstd)
{
    __shared__ float red[8];
    float s = vx + vy + vz + vw;
    #pragma unroll
    for (int off = 32; off; off >>= 1) s += __shfl_xor(s, off, 64);
    const int wv = tid >> 6, lane = tid & 63;
    if (lane == 0) red[wv] = s;
    __syncthreads();
    mean = (red[0] + red[1] + red[2] + red[3]) * (1.f / D_);
    const float dx = vx - mean, dy = vy - mean, dz = vz - mean, dw = vw - mean;
    float s2 = dx * dx + dy * dy + dz * dz + dw * dw;
    #pragma unroll
    for (int off = 32; off; off >>= 1) s2 += __shfl_xor(s2, off, 64);
    if (lane == 0) red[4 + wv] = s2;
    __syncthreads();
    rstd = rsqrtf((red[4] + red[5] + red[6] + red[7]) * (1.f / D_) + EPS_);
}

__global__ __launch_bounds__(256)
void add_ln1(const float* __restrict__ X, const bf16_t* __restrict__ Y,
             const float* __restrict__ g, const float* __restrict__ beta,
             bf16_t* __restrict__ out)
{
    const int row = blockIdx.x, tid = threadIdx.x;
    const float4 xv = ((const float4*)(X + (size_t)row * D_))[tid];
    const bf16x4v yv = *(const bf16x4v*)(Y + (size_t)row * D_ + tid * 4);
    const float vx = xv.x + (float)yv[0], vy = xv.y + (float)yv[1];
    const float vz = xv.z + (float)yv[2], vw = xv.w + (float)yv[3];
    float mean, rstd;
    ln_core(vx, vy, vz, vw, tid, mean, rstd);
    const float4 gv = ((const float4*)g)[tid];
    const float4 bv = ((const float4*)beta)[tid];
    bf16x4v o;
    o[0] = (bf16_t)((vx - mean) * rstd * gv.x + bv.x);
    o[1] = (bf16_t)((vy - mean) * rstd * gv.y + bv.y);
    o[2] = (bf16_t)((vz - mean) * rstd * gv.z + bv.z);
    o[3] = (bf16_t)((vw - mean) * rstd * gv.w + bv.w);
    *(bf16x4v*)(out + (size_t)row * D_ + tid * 4) = o;
}

__global__ __launch_bounds__(256)
void add_ln2(const bf16_t* __restrict__ X, const float* __restrict__ Y,
             const float* __restrict__ g, const float* __restrict__ beta,
             float* __restrict__ out)
{
    const int row = blockIdx.x, tid = threadIdx.x;
    const bf16x4v xv = *(const bf16x4v*)(X + (size_t)row * D_ + tid * 4);
    const float4 yv = ((const float4*)(Y + (size_t)row * D_))[tid];
    const float vx = (float)xv[0] + yv.x, vy = (float)xv[1] + yv.y;
    const float vz = (float)xv[2] + yv.z, vw = (float)xv[3] + yv.w;
    float mean, rstd;
    ln_core(vx, vy, vz, vw, tid, mean, rstd);
    const float4 gv = ((const float4*)g)[tid];
    const float4 bv = ((const float4*)beta)[tid];
    float4 o;
    o.x = (vx - mean) * rstd * gv.x + bv.x;
    o.y = (vy - mean) * rstd * gv.y + bv.y;
    o.z = (vz - mean) * rstd * gv.z + bv.z;
    o.w = (vw - mean) * rstd * gv.w + bv.w;
    ((float4*)(out + (size_t)row * D_))[tid] = o;
}

// ---------------------------------------------------------------------------
extern "C" void kernel_launch(void* const* d_in, const int* in_sizes, int n_in,
                              void* d_out, int out_size, void* d_ws, size_t ws_size,
                              hipStream_t stream)
{
    const float* x    = (const float*)d_in[0];
    const float* Wq   = (const float*)d_in[1];
    const float* Wk   = (const float*)d_in[2];
    const float* Wv   = (const float*)d_in[3];
    const float* fc1w = (const float*)d_in[4];
    const float* fc1b = (const float*)d_in[5];
    const float* fc2w = (const float*)d_in[6];
    const float* fc2b = (const float*)d_in[7];
    const float* ln1w = (const float*)d_in[8];
    const float* ln1b = (const float*)d_in[9];
    const float* ln2w = (const float*)d_in[10];
    const float* ln2b = (const float*)d_in[11];
    const int*   lens = (const int*)d_in[12];
    float* out = (float*)d_out;

    char* ws = (char*)d_ws;
    const size_t MB = 1024 * 1024;
    bf16_t* QKVb  = (bf16_t*)(ws);              // 48 MB: [8192][3072]
    bf16_t* Zb    = (bf16_t*)(ws + 48 * MB);    // 16 MB: [8192][1024] bf16
    bf16_t* X1b   = (bf16_t*)(ws + 80 * MB);    // 16 MB
    bf16_t* xb    = (bf16_t*)(ws + 96 * MB);    // 16 MB (dead after QKV)
    bf16_t* H1b   = (bf16_t*)(ws + 96 * MB);    //   reuses xb slot
    float*  FF    = (float*)(ws + 48 * MB);     //   reuses Zb slot (32 MB)
    bf16_t* WtQKV = (bf16_t*)(ws + 112 * MB);   // 6 MB
    bf16_t* Wt1   = (bf16_t*)(ws + 118 * MB);   // 2 MB
    bf16_t* Wt2   = (bf16_t*)(ws + 120 * MB);   // 2 MB

    const int M = B_ * S_;

    prep<<<dim3(16, 16, 37), 256, 0, stream>>>(x, Wq, Wk, Wv, fc1w, fc2w,
                                               xb, WtQKV, Wt1, Wt2);

    gemm8<0, bf16_t><<<dim3(3072 / 256, M / 256), 512, 0, stream>>>(
        xb, WtQKV, nullptr, nullptr, QKVb, M, 3072, D_);

    attn_mfma<<<dim3(2048), 256, 0, stream>>>(QKVb, lens, Zb);

    add_ln1<<<M, 256, 0, stream>>>(x, Zb, ln1w, ln1b, X1b);

    gemm8<1, bf16_t><<<dim3(D_ / 256, M / 256), 512, 0, stream>>>(
        X1b, Wt1, fc1b, lens, H1b, M, D_, D_);
    gemm8<2, float><<<dim3(D_ / 256, M / 256), 512, 0, stream>>>(
        H1b, Wt2, fc2b, lens, FF, M, D_, D_);

    add_ln2<<<M, 256, 0, stream>>>(X1b, FF, ln2w, ln2b, out);
}

// Round 3
// 329.957 us; speedup vs baseline: 1.0539x; 1.0539x over previous
//
#include <hip/hip_runtime.h>
#include <math.h>

#define B_ 8
#define S_ 1024
#define D_ 1024
#define H_ 16
#define DK_ 64
#define EPS_ 1e-5f

typedef __bf16 bf16_t;
typedef __bf16 bf16x8 __attribute__((ext_vector_type(8)));
typedef __bf16 bf16x4v __attribute__((ext_vector_type(4)));
typedef float  f32x4  __attribute__((ext_vector_type(4)));

__device__ __forceinline__ void gld16(const void* g, void* l) {
    __builtin_amdgcn_global_load_lds(
        (const __attribute__((address_space(1))) void*)g,
        (__attribute__((address_space(3))) void*)l, 16, 0, 0);
}

// ---------------------------------------------------------------------------
// prep: fused weight transpose+convert (z=0..4) and x f32->bf16 (z=5..36).
// ---------------------------------------------------------------------------
__global__ __launch_bounds__(256)
void prep(const float* __restrict__ x,
          const float* __restrict__ Wq, const float* __restrict__ Wk,
          const float* __restrict__ Wv, const float* __restrict__ W1,
          const float* __restrict__ W2, bf16_t* __restrict__ xb,
          bf16_t* __restrict__ WtQKV, bf16_t* __restrict__ Wt1,
          bf16_t* __restrict__ Wt2)
{
    __shared__ float tile[64][65];
    const int tid = threadIdx.x;
    const int z = blockIdx.z;

    if (z >= 5) {   // x convert
        const int blk = (z - 5) * 256 + blockIdx.y * 16 + blockIdx.x;
        const int i = (blk * 256 + tid) * 4;
        const float4 v = *(const float4*)(x + i);
        bf16x4v o = { (bf16_t)v.x, (bf16_t)v.y, (bf16_t)v.z, (bf16_t)v.w };
        *(bf16x4v*)(xb + i) = o;
        return;
    }

    const int n0 = blockIdx.x * 64, k0 = blockIdx.y * 64;
    const int col = tid & 63, r0 = tid >> 6;
    const float* src = (z == 0) ? Wq : (z == 1) ? Wk : (z == 2) ? Wv
                     : (z == 3) ? W1 : W2;
    #pragma unroll
    for (int i = 0; i < 16; i++) {
        const int row = r0 + i * 4;
        float v;
        if (z < 3)
            v = src[((size_t)(n0 >> 6) << 16) + (size_t)(k0 + row) * 64 + col];
        else
            v = src[(size_t)(k0 + row) * D_ + n0 + col];
        tile[row][col] = v;
    }
    __syncthreads();
    bf16_t* dst = (z < 3) ? (WtQKV + (size_t)z * D_ * D_)
                : (z == 3) ? Wt1 : Wt2;
    #pragma unroll
    for (int i = 0; i < 16; i++) {
        const int nr = r0 + i * 4;
        dst[(size_t)(n0 + nr) * D_ + k0 + col] = (bf16_t)tile[col][nr];
    }
}

// ---------------------------------------------------------------------------
// 256xBN bf16 MFMA GEMM, full-K-tile double buffer, 2 barriers/K-tile.
//   R3 rationale: R2's 8-barrier/4-lgkmcnt(0) phase lockstep serialized the
//   LDS burst (~2330 cyc/K-tile) against the MFMA burst (~2480) -> 26.6%
//   MfmaUtil. With a full-tile dbuf the minimal safe schedule is:
//     STAGE(t+1 -> buf^1)            (8 or 6 gld16, w=16, chunk-XOR swizzled
//                                     global source, linear LDS dest)
//     s_waitcnt vmcnt(NLD)           counted: own tile-t stages landed,
//                                    t+1 stays in flight (T4, never 0)
//     s_barrier                      all waves' tile-t data visible
//     [24 ds_read_b128 + 64 MFMA]    compiler fine-grained lgkmcnt (m97),
//                                    setprio(1) round MFMA clusters (T5)
//     s_barrier                      reads drained (MFMA lgkm interlock)
//   sched_barrier(0) pins around each s_barrier stop ds_read hoist/sink
//   across buffers (compiler is blind to cross-wave LDS aliasing).
//   Race check: STAGE(t+1) into buf (t+1)&1 is issued after BAR2(t-1), which
//   post-dates every wave's completed reads of that buffer (tile t-1).
//   BN=256: QKV (12x32=384 wg). BN=128: fc (8x32=256 wg = 1/CU exactly).
//   Bijective XCD-chunked swizzle (nwg%8==0 for all launches).
//   EPI: 0 plain; 1 +bias,relu,mask; 2 +bias,mask.
// ---------------------------------------------------------------------------
template<int EPI, int BN, typename OUT>
__global__ __launch_bounds__(512, 2)
void gemm8(const bf16_t* __restrict__ A, const bf16_t* __restrict__ Bw,
           const float* __restrict__ bias, const int* __restrict__ lens,
           OUT* __restrict__ C, int M, int N, int K)
{
    constexpr int NSB = BN / 64;    // B staging shots (4 or 2)
    constexpr int WN  = BN / 4;     // per-wave N span (64 or 32)
    constexpr int NJ  = WN / 16;    // acc N-frags per wave (4 or 2)

    __shared__ __align__(16) bf16_t As[2][256 * 64];
    __shared__ __align__(16) bf16_t Bs[2][BN * 64];

    const int tid  = threadIdx.x;
    const int lane = tid & 63;
    const int w    = tid >> 6;
    const int quad = lane >> 4, l16 = lane & 15;
    const int wm = w & 1, wn = w >> 1;
    const int sw8 = l16 & 7;

    // bijective XCD-chunked swizzle (requires nwg % 8 == 0)
    const int nwg  = gridDim.x * gridDim.y;
    const int orig = blockIdx.y * gridDim.x + blockIdx.x;
    const int swz  = (orig & 7) * (nwg >> 3) + (orig >> 3);
    const int bn = (swz % gridDim.x) * BN;
    const int bm = (swz / gridDim.x) * 256;

    // staging geometry: shot s covers rows [s*64, s*64+64), 8 chunks/row,
    // chunk c of row r sourced from col (c ^ (r&7))*8 -> linear LDS dest.
    const int rS  = tid >> 3;                       // 0..63
    const int cS  = ((tid & 7) ^ (rS & 7)) << 3;    // swizzled source col
    const int dOf = w * 64 * 16;                    // wave-uniform dest base

    f32x4 acc[8][NJ];
    #pragma unroll
    for (int i = 0; i < 8; i++)
        #pragma unroll
        for (int j = 0; j < NJ; j++)
            #pragma unroll
            for (int r = 0; r < 4; r++) acc[i][j][r] = 0.f;

#define STAGE(buf_, kt_) { \
    _Pragma("unroll") \
    for (int s_ = 0; s_ < 4; s_++) \
        gld16(A + (size_t)(bm + s_ * 64 + rS) * K + (kt_) * 64 + cS, \
              (char*)As[buf_] + s_ * 8192 + dOf); \
    _Pragma("unroll") \
    for (int s_ = 0; s_ < NSB; s_++) \
        gld16(Bw + (size_t)(bn + s_ * 64 + rS) * K + (kt_) * 64 + cS, \
              (char*)Bs[buf_] + s_ * 8192 + dOf); }
#define RD_A(dst, qm_, i_, kh_) \
    dst = *(const bf16x8*)&Ac[(wm * 128 + (qm_) * 64 + (i_) * 16 + l16) * 64 + ((((kh_) * 4 + quad) ^ sw8) << 3)];
#define RD_B(dst, qn_, j_, kh_) \
    dst = *(const bf16x8*)&Bc[(wn * WN + (qn_) * 32 + (j_) * 16 + l16) * 64 + ((((kh_) * 4 + quad) ^ sw8) << 3)];
#define MM(QI, QJ, AF, BF) \
    _Pragma("unroll") \
    for (int kh_ = 0; kh_ < 2; kh_++) \
        _Pragma("unroll") \
        for (int i_ = 0; i_ < 4; i_++) \
            _Pragma("unroll") \
            for (int j_ = 0; j_ < 2; j_++) \
                acc[(QI) * 4 + i_][(QJ) * 2 + j_] = __builtin_amdgcn_mfma_f32_16x16x32_bf16( \
                    AF[i_][kh_], BF[j_][kh_], acc[(QI) * 4 + i_][(QJ) * 2 + j_], 0, 0, 0);

    const int NKT = K >> 6;

    STAGE(0, 0);                       // prologue: tile 0 -> buf 0

    for (int t = 0; t < NKT; ++t) {
        const int cb = t & 1, nb = cb ^ 1;
        const int ktn = (t + 1 < NKT) ? t + 1 : t;   // clamped tail reload
        const bf16_t* Ac = As[cb];
        const bf16_t* Bc = Bs[cb];

        STAGE(nb, ktn);
        if constexpr (BN == 256)
            asm volatile("s_waitcnt vmcnt(8)" ::: "memory");
        else
            asm volatile("s_waitcnt vmcnt(6)" ::: "memory");
        __builtin_amdgcn_sched_barrier(0);
        __builtin_amdgcn_s_barrier();      // BAR1: tile-t data in LDS
        __builtin_amdgcn_sched_barrier(0);

        bf16x8 fa[4][2], fb[2][2];
        #pragma unroll
        for (int i = 0; i < 4; i++) { RD_A(fa[i][0], 0, i, 0); RD_A(fa[i][1], 0, i, 1); }
        #pragma unroll
        for (int j = 0; j < 2; j++) { RD_B(fb[j][0], 0, j, 0); RD_B(fb[j][1], 0, j, 1); }
        __builtin_amdgcn_s_setprio(1);
        MM(0, 0, fa, fb);
        __builtin_amdgcn_s_setprio(0);

        if constexpr (BN == 256) {
            bf16x8 gb[2][2];
            #pragma unroll
            for (int j = 0; j < 2; j++) { RD_B(gb[j][0], 1, j, 0); RD_B(gb[j][1], 1, j, 1); }
            __builtin_amdgcn_s_setprio(1);
            MM(0, 1, fa, gb);
            __builtin_amdgcn_s_setprio(0);
            bf16x8 ga[4][2];
            #pragma unroll
            for (int i = 0; i < 4; i++) { RD_A(ga[i][0], 1, i, 0); RD_A(ga[i][1], 1, i, 1); }
            __builtin_amdgcn_s_setprio(1);
            MM(1, 1, ga, gb);
            MM(1, 0, ga, fb);
            __builtin_amdgcn_s_setprio(0);
        } else {
            bf16x8 ga[4][2];
            #pragma unroll
            for (int i = 0; i < 4; i++) { RD_A(ga[i][0], 1, i, 0); RD_A(ga[i][1], 1, i, 1); }
            __builtin_amdgcn_s_setprio(1);
            MM(1, 0, ga, fb);
            __builtin_amdgcn_s_setprio(0);
        }

        __builtin_amdgcn_sched_barrier(0);
        __builtin_amdgcn_s_barrier();      // BAR2: all reads of buf cb drained
    }

#undef STAGE
#undef RD_A
#undef RD_B
#undef MM

    // ---- epilogue ----
    #pragma unroll
    for (int ii = 0; ii < 8; ii++) {
        #pragma unroll
        for (int r = 0; r < 4; r++) {
            const int m = bm + wm * 128 + (ii >> 2) * 64 + (ii & 3) * 16 + quad * 4 + r;
            float keep = 1.f;
            if (EPI != 0) {
                const int s = m & (S_ - 1);
                const int bb = m >> 10;
                keep = (s < lens[bb]) ? 1.f : 0.f;
            }
            #pragma unroll
            for (int jj = 0; jj < NJ; jj++) {
                const int n = bn + wn * WN + (jj >> 1) * 32 + (jj & 1) * 16 + l16;
                float v = acc[ii][jj][r];
                if (EPI != 0) {
                    v += bias[n];
                    if (EPI == 1) v = fmaxf(v, 0.f);
                    v *= keep;
                }
                C[(size_t)m * N + n] = (OUT)v;
            }
        }
    }
}

// ---------------------------------------------------------------------------
// bf16 MFMA flash attention, S^T formulation — R6: software-pipelined k-loop.
// ---------------------------------------------------------------------------
__global__ __launch_bounds__(256, 3)
void attn_mfma(const bf16_t* __restrict__ QKV, const int* __restrict__ lens,
               bf16_t* __restrict__ Z)
{
    __shared__ __align__(16) bf16_t Ks[2][64][64];   // [buf][key][d], chunk-swizzled
    __shared__ __align__(16) bf16_t Vt[2][64][72];   // [buf][d][key ^ 16*(d>>4)]
    __shared__ __align__(16) bf16_t Ps[64][72];      // [q][key], wave-private rows

    const int tid  = threadIdx.x;
    const int lane = tid & 63;
    const int w    = tid >> 6;
    const int quad = lane >> 4;
    const int l16  = lane & 15;
    const int id   = blockIdx.x;
    const int b    = id & 7;            // b fastest -> CU-load balance
    const int h    = (id >> 3) & 15;
    const int qt   = id >> 7;
    const int len  = lens[b];
    const int qbase = qt * 64;
    const bf16_t* Qp = QKV + (size_t)b * S_ * 3072 + (size_t)h * 64;
    const bf16_t* Kp = Qp + 1024;
    const bf16_t* Vp = Qp + 2048;
    const size_t zbase = (size_t)b * S_ * D_ + (size_t)h * 64;

    if (qbase >= len) {   // fully masked query tile -> zeros (bf16)
        const int r = tid >> 2, c0 = (tid & 3) * 16;
        bf16_t* zp = Z + zbase + (size_t)(qbase + r) * D_ + c0;
        uint4 zz = {0u, 0u, 0u, 0u};
        *(uint4*)zp = zz;
        *(uint4*)(zp + 8) = zz;
        return;
    }

    // Q B-frags, fixed for the whole kernel: B[k=d=quad*8+j][n=q=l16]
    const int qrow = qbase + w * 16 + l16;
    const bf16x8 bq0 = *(const bf16x8*)(Qp + (size_t)qrow * 3072 + quad * 8);
    const bf16x8 bq1 = *(const bf16x8*)(Qp + (size_t)qrow * 3072 + 32 + quad * 8);

    // K staging geometry: 2 shots of 256 lanes x 16B cover [64][64] bf16.
    const int kr0  = tid >> 3;          // shot0 row (0..31); shot1 row = kr0+32
    const int kpos = tid & 7;
    const int kc0  = (kpos ^ (kr0 & 7)) << 3;          // shot0 source d-offset
    const int kc1  = (kpos ^ ((kr0 + 32) & 7)) << 3;   // shot1 source d-offset

    // V staging map: thread -> key row vr, d cols vc0..vc0+15, swizzled col vp
    const int vr  = tid >> 2;
    const int vc0 = (tid & 3) * 16;
    const int vp  = vr ^ ((tid & 3) << 4);

    f32x4 o[4];
    #pragma unroll
    for (int dm = 0; dm < 4; dm++)
        #pragma unroll
        for (int r = 0; r < 4; r++) o[dm][r] = 0.f;
    float l_q = 0.f;

    const int ntiles = (len + 63) >> 6;

    // ---- prologue: stage K(0) -> Ks[0], load V(0) into regs ----
    gld16(Kp + (size_t)kr0 * 3072 + kc0,
          (char*)&Ks[0][0][0] + (size_t)(w * 64) * 16);
    gld16(Kp + (size_t)(kr0 + 32) * 3072 + kc1,
          (char*)&Ks[0][0][0] + (size_t)(256 + w * 64) * 16);
    bf16x8 vcur0 = *(const bf16x8*)(Vp + (size_t)vr * 3072 + vc0);
    bf16x8 vcur1 = *(const bf16x8*)(Vp + (size_t)vr * 3072 + vc0 + 8);
    __syncthreads();   // vmcnt(0) drain: Ks[0] ready

    for (int t = 0; t < ntiles; t++) {
        const int k0 = t * 64;
        const int cb = t & 1, nb = (t + 1) & 1;
        const int kn0 = (t + 1 < ntiles ? t + 1 : t) * 64;

        // ---- issue prefetch for tile t+1 (K -> Ks[nb], V -> regs) ----
        gld16(Kp + (size_t)(kn0 + kr0) * 3072 + kc0,
              (char*)&Ks[nb][0][0] + (size_t)(w * 64) * 16);
        gld16(Kp + (size_t)(kn0 + kr0 + 32) * 3072 + kc1,
              (char*)&Ks[nb][0][0] + (size_t)(256 + w * 64) * 16);
        const bf16_t* vsrc = Vp + (size_t)(kn0 + vr) * 3072 + vc0;
        const bf16x8 vn0 = *(const bf16x8*)vsrc;
        const bf16x8 vn1 = *(const bf16x8*)(vsrc + 8);
        __builtin_amdgcn_sched_barrier(0);   // pin prefetch issue at loop top

        // ---- S^T = K Q^T from Ks[cb], exp, stage P ----
        #pragma unroll
        for (int kt = 0; kt < 4; kt++) {
            const int r = kt * 16 + l16;           // r&7 == l16&7
            const bf16x8 ak0 = *(const bf16x8*)&Ks[cb][r][(quad ^ (l16 & 7)) << 3];
            const bf16x8 ak1 = *(const bf16x8*)&Ks[cb][r][((4 + quad) ^ (l16 & 7)) << 3];
            f32x4 z4 = {0.f, 0.f, 0.f, 0.f};
            z4 = __builtin_amdgcn_mfma_f32_16x16x32_bf16(ak0, bq0, z4, 0, 0, 0);
            const f32x4 sfv = __builtin_amdgcn_mfma_f32_16x16x32_bf16(ak1, bq1, z4, 0, 0, 0);
            bf16x4v pk;
            #pragma unroll
            for (int r2 = 0; r2 < 4; r2++) {
                const int key = k0 + kt * 16 + quad * 4 + r2;
                float p = __expf(sfv[r2] * 0.125f);
                p = (key < len) ? p : 0.f;
                l_q += p;
                pk[r2] = (bf16_t)p;
            }
            *(bf16x4v*)&Ps[w * 16 + l16][kt * 16 + quad * 4] = pk;
        }

        // ---- scatter V(t) regs -> Vt[cb] (transposed + XOR swizzle) ----
        #pragma unroll
        for (int i = 0; i < 8; i++) Vt[cb][vc0 + i][vp] = vcur0[i];
        #pragma unroll
        for (int i = 0; i < 8; i++) Vt[cb][vc0 + 8 + i][vp] = vcur1[i];
        vcur0 = vn0;
        vcur1 = vn1;
        __syncthreads();   // single barrier/iter

        // ---- O^T += V^T P^T ----
        const bf16x8 bp0 = *(const bf16x8*)&Ps[w * 16 + l16][quad * 8];
        const bf16x8 bp1 = *(const bf16x8*)&Ps[w * 16 + l16][32 + quad * 8];
        #pragma unroll
        for (int dm = 0; dm < 4; dm++) {
            const bf16x8 av0 = *(const bf16x8*)&Vt[cb][dm * 16 + l16][(quad * 8) ^ (dm * 16)];
            const bf16x8 av1 = *(const bf16x8*)&Vt[cb][dm * 16 + l16][(32 + quad * 8) ^ (dm * 16)];
            o[dm] = __builtin_amdgcn_mfma_f32_16x16x32_bf16(av0, bp0, o[dm], 0, 0, 0);
            o[dm] = __builtin_amdgcn_mfma_f32_16x16x32_bf16(av1, bp1, o[dm], 0, 0, 0);
        }
    }

    // ---- final l reduce + epilogue ----
    l_q += __shfl_xor(l_q, 16);
    l_q += __shfl_xor(l_q, 32);
    const int qg = qbase + w * 16 + l16;
    const float inv = (qg < len) ? 1.f / l_q : 0.f;
    bf16_t* zrow = Z + zbase + (size_t)qg * D_;
    #pragma unroll
    for (int dm = 0; dm < 4; dm++) {
        bf16x4v st;
        #pragma unroll
        for (int r = 0; r < 4; r++) st[r] = (bf16_t)(o[dm][r] * inv);
        *(bf16x4v*)(zrow + dm * 16 + quad * 4) = st;
    }
}

// ---------------------------------------------------------------------------
// Residual-add + LayerNorm, D=1024, one block per row.
// ---------------------------------------------------------------------------
__device__ __forceinline__ void ln_core(float vx, float vy, float vz, float vw,
                                        int tid, float& mean, float& rstd)
{
    __shared__ float red[8];
    float s = vx + vy + vz + vw;
    #pragma unroll
    for (int off = 32; off; off >>= 1) s += __shfl_xor(s, off, 64);
    const int wv = tid >> 6, lane = tid & 63;
    if (lane == 0) red[wv] = s;
    __syncthreads();
    mean = (red[0] + red[1] + red[2] + red[3]) * (1.f / D_);
    const float dx = vx - mean, dy = vy - mean, dz = vz - mean, dw = vw - mean;
    float s2 = dx * dx + dy * dy + dz * dz + dw * dw;
    #pragma unroll
    for (int off = 32; off; off >>= 1) s2 += __shfl_xor(s2, off, 64);
    if (lane == 0) red[4 + wv] = s2;
    __syncthreads();
    rstd = rsqrtf((red[4] + red[5] + red[6] + red[7]) * (1.f / D_) + EPS_);
}

__global__ __launch_bounds__(256)
void add_ln1(const float* __restrict__ X, const bf16_t* __restrict__ Y,
             const float* __restrict__ g, const float* __restrict__ beta,
             bf16_t* __restrict__ out)
{
    const int row = blockIdx.x, tid = threadIdx.x;
    const float4 xv = ((const float4*)(X + (size_t)row * D_))[tid];
    const bf16x4v yv = *(const bf16x4v*)(Y + (size_t)row * D_ + tid * 4);
    const float vx = xv.x + (float)yv[0], vy = xv.y + (float)yv[1];
    const float vz = xv.z + (float)yv[2], vw = xv.w + (float)yv[3];
    float mean, rstd;
    ln_core(vx, vy, vz, vw, tid, mean, rstd);
    const float4 gv = ((const float4*)g)[tid];
    const float4 bv = ((const float4*)beta)[tid];
    bf16x4v o;
    o[0] = (bf16_t)((vx - mean) * rstd * gv.x + bv.x);
    o[1] = (bf16_t)((vy - mean) * rstd * gv.y + bv.y);
    o[2] = (bf16_t)((vz - mean) * rstd * gv.z + bv.z);
    o[3] = (bf16_t)((vw - mean) * rstd * gv.w + bv.w);
    *(bf16x4v*)(out + (size_t)row * D_ + tid * 4) = o;
}

__global__ __launch_bounds__(256)
void add_ln2(const bf16_t* __restrict__ X, const float* __restrict__ Y,
             const float* __restrict__ g, const float* __restrict__ beta,
             float* __restrict__ out)
{
    const int row = blockIdx.x, tid = threadIdx.x;
    const bf16x4v xv = *(const bf16x4v*)(X + (size_t)row * D_ + tid * 4);
    const float4 yv = ((const float4*)(Y + (size_t)row * D_))[tid];
    const float vx = (float)xv[0] + yv.x, vy = (float)xv[1] + yv.y;
    const float vz = (float)xv[2] + yv.z, vw = (float)xv[3] + yv.w;
    float mean, rstd;
    ln_core(vx, vy, vz, vw, tid, mean, rstd);
    const float4 gv = ((const float4*)g)[tid];
    const float4 bv = ((const float4*)beta)[tid];
    float4 o;
    o.x = (vx - mean) * rstd * gv.x + bv.x;
    o.y = (vy - mean) * rstd * gv.y + bv.y;
    o.z = (vz - mean) * rstd * gv.z + bv.z;
    o.w = (vw - mean) * rstd * gv.w + bv.w;
    ((float4*)(out + (size_t)row * D_))[tid] = o;
}

// ---------------------------------------------------------------------------
extern "C" void kernel_launch(void* const* d_in, const int* in_sizes, int n_in,
                              void* d_out, int out_size, void* d_ws, size_t ws_size,
                              hipStream_t stream)
{
    const float* x    = (const float*)d_in[0];
    const float* Wq   = (const float*)d_in[1];
    const float* Wk   = (const float*)d_in[2];
    const float* Wv   = (const float*)d_in[3];
    const float* fc1w = (const float*)d_in[4];
    const float* fc1b = (const float*)d_in[5];
    const float* fc2w = (const float*)d_in[6];
    const float* fc2b = (const float*)d_in[7];
    const float* ln1w = (const float*)d_in[8];
    const float* ln1b = (const float*)d_in[9];
    const float* ln2w = (const float*)d_in[10];
    const float* ln2b = (const float*)d_in[11];
    const int*   lens = (const int*)d_in[12];
    float* out = (float*)d_out;

    char* ws = (char*)d_ws;
    const size_t MB = 1024 * 1024;
    bf16_t* QKVb  = (bf16_t*)(ws);              // 48 MB: [8192][3072]
    bf16_t* Zb    = (bf16_t*)(ws + 48 * MB);    // 16 MB: [8192][1024] bf16
    bf16_t* X1b   = (bf16_t*)(ws + 80 * MB);    // 16 MB
    bf16_t* xb    = (bf16_t*)(ws + 96 * MB);    // 16 MB (dead after QKV)
    bf16_t* H1b   = (bf16_t*)(ws + 96 * MB);    //   reuses xb slot
    float*  FF    = (float*)(ws + 48 * MB);     //   reuses Zb slot (32 MB)
    bf16_t* WtQKV = (bf16_t*)(ws + 112 * MB);   // 6 MB
    bf16_t* Wt1   = (bf16_t*)(ws + 118 * MB);   // 2 MB
    bf16_t* Wt2   = (bf16_t*)(ws + 120 * MB);   // 2 MB

    const int M = B_ * S_;

    prep<<<dim3(16, 16, 37), 256, 0, stream>>>(x, Wq, Wk, Wv, fc1w, fc2w,
                                               xb, WtQKV, Wt1, Wt2);

    gemm8<0, 256, bf16_t><<<dim3(3072 / 256, M / 256), 512, 0, stream>>>(
        xb, WtQKV, nullptr, nullptr, QKVb, M, 3072, D_);

    attn_mfma<<<dim3(2048), 256, 0, stream>>>(QKVb, lens, Zb);

    add_ln1<<<M, 256, 0, stream>>>(x, Zb, ln1w, ln1b, X1b);

    gemm8<1, 128, bf16_t><<<dim3(D_ / 128, M / 256), 512, 0, stream>>>(
        X1b, Wt1, fc1b, lens, H1b, M, D_, D_);
    gemm8<2, 128, float><<<dim3(D_ / 128, M / 256), 512, 0, stream>>>(
        H1b, Wt2, fc2b, lens, FF, M, D_, D_);

    add_ln2<<<M, 256, 0, stream>>>(X1b, FF, ln2w, ln2b, out);
}

// Round 4
// 327.015 us; speedup vs baseline: 1.0634x; 1.0090x over previous
//
#include <hip/hip_runtime.h>
#include <math.h>

#define B_ 8
#define S_ 1024
#define D_ 1024
#define H_ 16
#define DK_ 64
#define EPS_ 1e-5f

typedef __bf16 bf16_t;
typedef __bf16 bf16x8 __attribute__((ext_vector_type(8)));
typedef __bf16 bf16x4v __attribute__((ext_vector_type(4)));
typedef float  f32x4  __attribute__((ext_vector_type(4)));

__device__ __forceinline__ void gld16(const void* g, void* l) {
    __builtin_amdgcn_global_load_lds(
        (const __attribute__((address_space(1))) void*)g,
        (__attribute__((address_space(3))) void*)l, 16, 0, 0);
}

// ---------------------------------------------------------------------------
// prep: fused weight transpose+convert (z=0..4) and x f32->bf16 (z=5..36).
// ---------------------------------------------------------------------------
__global__ __launch_bounds__(256)
void prep(const float* __restrict__ x,
          const float* __restrict__ Wq, const float* __restrict__ Wk,
          const float* __restrict__ Wv, const float* __restrict__ W1,
          const float* __restrict__ W2, bf16_t* __restrict__ xb,
          bf16_t* __restrict__ WtQKV, bf16_t* __restrict__ Wt1,
          bf16_t* __restrict__ Wt2)
{
    __shared__ float tile[64][65];
    const int tid = threadIdx.x;
    const int z = blockIdx.z;

    if (z >= 5) {   // x convert
        const int blk = (z - 5) * 256 + blockIdx.y * 16 + blockIdx.x;
        const int i = (blk * 256 + tid) * 4;
        const float4 v = *(const float4*)(x + i);
        bf16x4v o = { (bf16_t)v.x, (bf16_t)v.y, (bf16_t)v.z, (bf16_t)v.w };
        *(bf16x4v*)(xb + i) = o;
        return;
    }

    const int n0 = blockIdx.x * 64, k0 = blockIdx.y * 64;
    const int col = tid & 63, r0 = tid >> 6;
    const float* src = (z == 0) ? Wq : (z == 1) ? Wk : (z == 2) ? Wv
                     : (z == 3) ? W1 : W2;
    #pragma unroll
    for (int i = 0; i < 16; i++) {
        const int row = r0 + i * 4;
        float v;
        if (z < 3)
            v = src[((size_t)(n0 >> 6) << 16) + (size_t)(k0 + row) * 64 + col];
        else
            v = src[(size_t)(k0 + row) * D_ + n0 + col];
        tile[row][col] = v;
    }
    __syncthreads();
    bf16_t* dst = (z < 3) ? (WtQKV + (size_t)z * D_ * D_)
                : (z == 3) ? Wt1 : Wt2;
    #pragma unroll
    for (int i = 0; i < 16; i++) {
        const int nr = r0 + i * 4;
        dst[(size_t)(n0 + nr) * D_ + k0 + col] = (bf16_t)tile[col][nr];
    }
}

// ---------------------------------------------------------------------------
// 256xBN bf16 MFMA GEMM — R4: m201-faithful fine phases + derived wait ledger.
//   R2 (fine phases, vmcnt distance ~1.5 phases) and R3 (coarse, long
//   distances) both hit 26% MfmaUtil: R2 stalled on DMA latency each phase;
//   R3 serialized the LDS burst (2300 cyc) against the MFMA burst (2480).
//   This version: 4 phases/K-tile of 16 (or 8) MFMA each,
//     phase = { ds_read frags; stage gld16s; [counted vmcnt];
//               sched_barrier; s_barrier; lgkmcnt(0); sched_barrier;
//               setprio(1); MFMA cluster; setprio(0); sched_barrier; s_barrier }
//   Stage grouping of tile t+1 (during iter t) + wait ledger (per thread):
//     BN=256: phA {B0,B1}  phB {B2,B3,A0,A2}+vmcnt(6)  phC {}  phD {A1,A3}+vmcnt(2)
//     BN=128: phA {B0,B1}  phB {A0,A2}+vmcnt(4)        phC {}  phD {A1,A3}+vmcnt(2)
//   Consumption (iter t+1): phA reads A0|A2 (2-3 phases after stage) and
//   B-shot(wn) lo (3-4 ph); phB reads B-shot(wn) hi; phC reads A1|A3 (3 ph).
//   Every vmcnt drains only loads >=~1.5 phases old; never vmcnt(0) (T4).
//   Chunk-XOR swizzle on the global source, linear LDS dest (T2);
//   conflict-free ds_read_b128 verified (0 SQ_LDS_BANK_CONFLICT in R2/R3).
//   Bijective XCD-chunked block swizzle (nwg % 8 == 0 in all launches).
//   EPI: 0 plain; 1 +bias,relu,mask; 2 +bias,mask.
// ---------------------------------------------------------------------------
template<int EPI, int BN, typename OUT>
__global__ __launch_bounds__(512, 2)
void gemm8(const bf16_t* __restrict__ A, const bf16_t* __restrict__ Bw,
           const float* __restrict__ bias, const int* __restrict__ lens,
           OUT* __restrict__ C, int M, int N, int K)
{
    constexpr int WN  = BN / 4;     // per-wave N span (64 or 32)
    constexpr int NJ  = WN / 16;    // acc N-frags per wave (4 or 2)
    constexpr int NJB = NJ / 2;     // N-frags per quadrant (2 or 1)

    __shared__ __align__(16) bf16_t As[2][256 * 64];
    __shared__ __align__(16) bf16_t Bs[2][BN * 64];

    const int tid  = threadIdx.x;
    const int lane = tid & 63;
    const int w    = tid >> 6;
    const int quad = lane >> 4, l16 = lane & 15;
    const int wm = w & 1, wn = w >> 1;
    const int sw8 = l16 & 7;

    // bijective XCD-chunked swizzle (requires nwg % 8 == 0)
    const int nwg  = gridDim.x * gridDim.y;
    const int orig = blockIdx.y * gridDim.x + blockIdx.x;
    const int swz  = (orig & 7) * (nwg >> 3) + (orig >> 3);
    const int bn = (swz % gridDim.x) * BN;
    const int bm = (swz / gridDim.x) * 256;

    // staging geometry: shot s covers rows [s*64, s*64+64); thread -> row
    // rS = tid>>3, source col swizzled cS = ((tid&7)^(rS&7))*8, LDS linear.
    const int rS  = tid >> 3;
    const int cS  = ((tid & 7) ^ (rS & 7)) << 3;
    const int dOf = w * 1024;       // wave-uniform dest byte base (+lane*16)

    f32x4 acc[8][NJ];
    #pragma unroll
    for (int i = 0; i < 8; i++)
        #pragma unroll
        for (int j = 0; j < NJ; j++)
            #pragma unroll
            for (int r = 0; r < 4; r++) acc[i][j][r] = 0.f;

#define SA(s_, b_, kt_) \
    gld16(A + (size_t)(bm + (s_) * 64 + rS) * K + (kt_) * 64 + cS, \
          (char*)As[b_] + (s_) * 8192 + dOf);
#define SBW(s_, b_, kt_) \
    gld16(Bw + (size_t)(bn + (s_) * 64 + rS) * K + (kt_) * 64 + cS, \
          (char*)Bs[b_] + (s_) * 8192 + dOf);
#define RD_A(dst, qm_, i_, kh_) \
    dst = *(const bf16x8*)&Ac[(wm * 128 + (qm_) * 64 + (i_) * 16 + l16) * 64 + ((((kh_) * 4 + quad) ^ sw8) << 3)];
#define RD_B(dst, qn_, j_, kh_) \
    dst = *(const bf16x8*)&Bc[(wn * WN + (qn_) * (WN / 2) + (j_) * 16 + l16) * 64 + ((((kh_) * 4 + quad) ^ sw8) << 3)];
#define MM(QI, QJ, AF, BF) \
    _Pragma("unroll") \
    for (int kh_ = 0; kh_ < 2; kh_++) \
        _Pragma("unroll") \
        for (int i_ = 0; i_ < 4; i_++) \
            _Pragma("unroll") \
            for (int j_ = 0; j_ < NJB; j_++) \
                acc[(QI) * 4 + i_][(QJ) * NJB + j_] = __builtin_amdgcn_mfma_f32_16x16x32_bf16( \
                    AF[i_][kh_], BF[j_][kh_], acc[(QI) * 4 + i_][(QJ) * NJB + j_], 0, 0, 0);
#define SB0() __builtin_amdgcn_sched_barrier(0)
#define BARR() __builtin_amdgcn_s_barrier()
#define LGK0() asm volatile("s_waitcnt lgkmcnt(0)" ::: "memory")

    const int NKT = K >> 6;

    // prologue: tile 0 -> buf 0, ledger-consistent order; A1,A3 left in flight
    SBW(0, 0, 0); SBW(1, 0, 0);
    if constexpr (BN == 256) { SBW(2, 0, 0); SBW(3, 0, 0); }
    SA(0, 0, 0); SA(2, 0, 0);
    SA(1, 0, 0); SA(3, 0, 0);
    asm volatile("s_waitcnt vmcnt(2)" ::: "memory");
    BARR();

    for (int t = 0; t < NKT; ++t) {
        const int cb = t & 1, nb = cb ^ 1;
        const int ktn = (t + 1 < NKT) ? t + 1 : t;   // clamped tail reload
        const bf16_t* Ac = As[cb];
        const bf16_t* Bc = Bs[cb];

        // ---- Phase A: Q00 (reads A0-half + B-lo; stages B0,B1) ----
        bf16x8 fa[4][2], fb[NJB][2];
        #pragma unroll
        for (int i = 0; i < 4; i++) { RD_A(fa[i][0], 0, i, 0); RD_A(fa[i][1], 0, i, 1); }
        #pragma unroll
        for (int j = 0; j < NJB; j++) { RD_B(fb[j][0], 0, j, 0); RD_B(fb[j][1], 0, j, 1); }
        SBW(0, nb, ktn); SBW(1, nb, ktn);
        SB0(); BARR(); LGK0(); SB0();
        __builtin_amdgcn_s_setprio(1);
        MM(0, 0, fa, fb);
        __builtin_amdgcn_s_setprio(0);
        SB0(); BARR();

        // ---- Phase B: Q01 (reads B-hi; stages B2,B3 (256) + A0,A2) ----
        bf16x8 gb[NJB][2];
        #pragma unroll
        for (int j = 0; j < NJB; j++) { RD_B(gb[j][0], 1, j, 0); RD_B(gb[j][1], 1, j, 1); }
        if constexpr (BN == 256) { SBW(2, nb, ktn); SBW(3, nb, ktn); }
        SA(0, nb, ktn); SA(2, nb, ktn);
        if constexpr (BN == 256)
            asm volatile("s_waitcnt vmcnt(6)" ::: "memory");
        else
            asm volatile("s_waitcnt vmcnt(4)" ::: "memory");
        SB0(); BARR(); LGK0(); SB0();
        __builtin_amdgcn_s_setprio(1);
        MM(0, 1, fa, gb);
        __builtin_amdgcn_s_setprio(0);
        SB0(); BARR();

        // ---- Phase C: Q11 (reads A1-half; no staging) ----
        bf16x8 ga[4][2];
        #pragma unroll
        for (int i = 0; i < 4; i++) { RD_A(ga[i][0], 1, i, 0); RD_A(ga[i][1], 1, i, 1); }
        SB0(); BARR(); LGK0(); SB0();
        __builtin_amdgcn_s_setprio(1);
        MM(1, 1, ga, gb);
        __builtin_amdgcn_s_setprio(0);
        SB0(); BARR();

        // ---- Phase D: Q10 (register-only; stages A1,A3) ----
        SA(1, nb, ktn); SA(3, nb, ktn);
        asm volatile("s_waitcnt vmcnt(2)" ::: "memory");
        SB0(); BARR(); SB0();
        __builtin_amdgcn_s_setprio(1);
        MM(1, 0, ga, fb);
        __builtin_amdgcn_s_setprio(0);
        SB0(); BARR();
    }

#undef SA
#undef SBW
#undef RD_A
#undef RD_B
#undef MM
#undef SB0
#undef BARR
#undef LGK0

    // ---- epilogue ----
    #pragma unroll
    for (int ii = 0; ii < 8; ii++) {
        #pragma unroll
        for (int r = 0; r < 4; r++) {
            const int m = bm + wm * 128 + (ii >> 2) * 64 + (ii & 3) * 16 + quad * 4 + r;
            float keep = 1.f;
            if (EPI != 0) {
                const int s = m & (S_ - 1);
                const int bb = m >> 10;
                keep = (s < lens[bb]) ? 1.f : 0.f;
            }
            #pragma unroll
            for (int jj = 0; jj < NJ; jj++) {
                const int n = bn + wn * WN + (jj >> 1) * 32 + (jj & 1) * 16 + l16;
                float v = acc[ii][jj][r];
                if (EPI != 0) {
                    v += bias[n];
                    if (EPI == 1) v = fmaxf(v, 0.f);
                    v *= keep;
                }
                C[(size_t)m * N + n] = (OUT)v;
            }
        }
    }
}

// ---------------------------------------------------------------------------
// bf16 MFMA flash attention, S^T formulation — R6: software-pipelined k-loop.
// ---------------------------------------------------------------------------
__global__ __launch_bounds__(256, 3)
void attn_mfma(const bf16_t* __restrict__ QKV, const int* __restrict__ lens,
               bf16_t* __restrict__ Z)
{
    __shared__ __align__(16) bf16_t Ks[2][64][64];   // [buf][key][d], chunk-swizzled
    __shared__ __align__(16) bf16_t Vt[2][64][72];   // [buf][d][key ^ 16*(d>>4)]
    __shared__ __align__(16) bf16_t Ps[64][72];      // [q][key], wave-private rows

    const int tid  = threadIdx.x;
    const int lane = tid & 63;
    const int w    = tid >> 6;
    const int quad = lane >> 4;
    const int l16  = lane & 15;
    const int id   = blockIdx.x;
    const int b    = id & 7;            // b fastest -> CU-load balance
    const int h    = (id >> 3) & 15;
    const int qt   = id >> 7;
    const int len  = lens[b];
    const int qbase = qt * 64;
    const bf16_t* Qp = QKV + (size_t)b * S_ * 3072 + (size_t)h * 64;
    const bf16_t* Kp = Qp + 1024;
    const bf16_t* Vp = Qp + 2048;
    const size_t zbase = (size_t)b * S_ * D_ + (size_t)h * 64;

    if (qbase >= len) {   // fully masked query tile -> zeros (bf16)
        const int r = tid >> 2, c0 = (tid & 3) * 16;
        bf16_t* zp = Z + zbase + (size_t)(qbase + r) * D_ + c0;
        uint4 zz = {0u, 0u, 0u, 0u};
        *(uint4*)zp = zz;
        *(uint4*)(zp + 8) = zz;
        return;
    }

    // Q B-frags, fixed for the whole kernel: B[k=d=quad*8+j][n=q=l16]
    const int qrow = qbase + w * 16 + l16;
    const bf16x8 bq0 = *(const bf16x8*)(Qp + (size_t)qrow * 3072 + quad * 8);
    const bf16x8 bq1 = *(const bf16x8*)(Qp + (size_t)qrow * 3072 + 32 + quad * 8);

    // K staging geometry: 2 shots of 256 lanes x 16B cover [64][64] bf16.
    const int kr0  = tid >> 3;          // shot0 row (0..31); shot1 row = kr0+32
    const int kpos = tid & 7;
    const int kc0  = (kpos ^ (kr0 & 7)) << 3;          // shot0 source d-offset
    const int kc1  = (kpos ^ ((kr0 + 32) & 7)) << 3;   // shot1 source d-offset

    // V staging map: thread -> key row vr, d cols vc0..vc0+15, swizzled col vp
    const int vr  = tid >> 2;
    const int vc0 = (tid & 3) * 16;
    const int vp  = vr ^ ((tid & 3) << 4);

    f32x4 o[4];
    #pragma unroll
    for (int dm = 0; dm < 4; dm++)
        #pragma unroll
        for (int r = 0; r < 4; r++) o[dm][r] = 0.f;
    float l_q = 0.f;

    const int ntiles = (len + 63) >> 6;

    // ---- prologue: stage K(0) -> Ks[0], load V(0) into regs ----
    gld16(Kp + (size_t)kr0 * 3072 + kc0,
          (char*)&Ks[0][0][0] + (size_t)(w * 64) * 16);
    gld16(Kp + (size_t)(kr0 + 32) * 3072 + kc1,
          (char*)&Ks[0][0][0] + (size_t)(256 + w * 64) * 16);
    bf16x8 vcur0 = *(const bf16x8*)(Vp + (size_t)vr * 3072 + vc0);
    bf16x8 vcur1 = *(const bf16x8*)(Vp + (size_t)vr * 3072 + vc0 + 8);
    __syncthreads();   // vmcnt(0) drain: Ks[0] ready

    for (int t = 0; t < ntiles; t++) {
        const int k0 = t * 64;
        const int cb = t & 1, nb = (t + 1) & 1;
        const int kn0 = (t + 1 < ntiles ? t + 1 : t) * 64;

        // ---- issue prefetch for tile t+1 (K -> Ks[nb], V -> regs) ----
        gld16(Kp + (size_t)(kn0 + kr0) * 3072 + kc0,
              (char*)&Ks[nb][0][0] + (size_t)(w * 64) * 16);
        gld16(Kp + (size_t)(kn0 + kr0 + 32) * 3072 + kc1,
              (char*)&Ks[nb][0][0] + (size_t)(256 + w * 64) * 16);
        const bf16_t* vsrc = Vp + (size_t)(kn0 + vr) * 3072 + vc0;
        const bf16x8 vn0 = *(const bf16x8*)vsrc;
        const bf16x8 vn1 = *(const bf16x8*)(vsrc + 8);
        __builtin_amdgcn_sched_barrier(0);   // pin prefetch issue at loop top

        // ---- S^T = K Q^T from Ks[cb], exp, stage P ----
        #pragma unroll
        for (int kt = 0; kt < 4; kt++) {
            const int r = kt * 16 + l16;           // r&7 == l16&7
            const bf16x8 ak0 = *(const bf16x8*)&Ks[cb][r][(quad ^ (l16 & 7)) << 3];
            const bf16x8 ak1 = *(const bf16x8*)&Ks[cb][r][((4 + quad) ^ (l16 & 7)) << 3];
            f32x4 z4 = {0.f, 0.f, 0.f, 0.f};
            z4 = __builtin_amdgcn_mfma_f32_16x16x32_bf16(ak0, bq0, z4, 0, 0, 0);
            const f32x4 sfv = __builtin_amdgcn_mfma_f32_16x16x32_bf16(ak1, bq1, z4, 0, 0, 0);
            bf16x4v pk;
            #pragma unroll
            for (int r2 = 0; r2 < 4; r2++) {
                const int key = k0 + kt * 16 + quad * 4 + r2;
                float p = __expf(sfv[r2] * 0.125f);
                p = (key < len) ? p : 0.f;
                l_q += p;
                pk[r2] = (bf16_t)p;
            }
            *(bf16x4v*)&Ps[w * 16 + l16][kt * 16 + quad * 4] = pk;
        }

        // ---- scatter V(t) regs -> Vt[cb] (transposed + XOR swizzle) ----
        #pragma unroll
        for (int i = 0; i < 8; i++) Vt[cb][vc0 + i][vp] = vcur0[i];
        #pragma unroll
        for (int i = 0; i < 8; i++) Vt[cb][vc0 + 8 + i][vp] = vcur1[i];
        vcur0 = vn0;
        vcur1 = vn1;
        __syncthreads();   // single barrier/iter

        // ---- O^T += V^T P^T ----
        const bf16x8 bp0 = *(const bf16x8*)&Ps[w * 16 + l16][quad * 8];
        const bf16x8 bp1 = *(const bf16x8*)&Ps[w * 16 + l16][32 + quad * 8];
        #pragma unroll
        for (int dm = 0; dm < 4; dm++) {
            const bf16x8 av0 = *(const bf16x8*)&Vt[cb][dm * 16 + l16][(quad * 8) ^ (dm * 16)];
            const bf16x8 av1 = *(const bf16x8*)&Vt[cb][dm * 16 + l16][(32 + quad * 8) ^ (dm * 16)];
            o[dm] = __builtin_amdgcn_mfma_f32_16x16x32_bf16(av0, bp0, o[dm], 0, 0, 0);
            o[dm] = __builtin_amdgcn_mfma_f32_16x16x32_bf16(av1, bp1, o[dm], 0, 0, 0);
        }
    }

    // ---- final l reduce + epilogue ----
    l_q += __shfl_xor(l_q, 16);
    l_q += __shfl_xor(l_q, 32);
    const int qg = qbase + w * 16 + l16;
    const float inv = (qg < len) ? 1.f / l_q : 0.f;
    bf16_t* zrow = Z + zbase + (size_t)qg * D_;
    #pragma unroll
    for (int dm = 0; dm < 4; dm++) {
        bf16x4v st;
        #pragma unroll
        for (int r = 0; r < 4; r++) st[r] = (bf16_t)(o[dm][r] * inv);
        *(bf16x4v*)(zrow + dm * 16 + quad * 4) = st;
    }
}

// ---------------------------------------------------------------------------
// Residual-add + LayerNorm, D=1024, one block per row.
// ---------------------------------------------------------------------------
__device__ __forceinline__ void ln_core(float vx, float vy, float vz, float vw,
                                        int tid, float& mean, float& rstd)
{
    __shared__ float red[8];
    float s = vx + vy + vz + vw;
    #pragma unroll
    for (int off = 32; off; off >>= 1) s += __shfl_xor(s, off, 64);
    const int wv = tid >> 6, lane = tid & 63;
    if (lane == 0) red[wv] = s;
    __syncthreads();
    mean = (red[0] + red[1] + red[2] + red[3]) * (1.f / D_);
    const float dx = vx - mean, dy = vy - mean, dz = vz - mean, dw = vw - mean;
    float s2 = dx * dx + dy * dy + dz * dz + dw * dw;
    #pragma unroll
    for (int off = 32; off; off >>= 1) s2 += __shfl_xor(s2, off, 64);
    if (lane == 0) red[4 + wv] = s2;
    __syncthreads();
    rstd = rsqrtf((red[4] + red[5] + red[6] + red[7]) * (1.f / D_) + EPS_);
}

__global__ __launch_bounds__(256)
void add_ln1(const float* __restrict__ X, const bf16_t* __restrict__ Y,
             const float* __restrict__ g, const float* __restrict__ beta,
             bf16_t* __restrict__ out)
{
    const int row = blockIdx.x, tid = threadIdx.x;
    const float4 xv = ((const float4*)(X + (size_t)row * D_))[tid];
    const bf16x4v yv = *(const bf16x4v*)(Y + (size_t)row * D_ + tid * 4);
    const float vx = xv.x + (float)yv[0], vy = xv.y + (float)yv[1];
    const float vz = xv.z + (float)yv[2], vw = xv.w + (float)yv[3];
    float mean, rstd;
    ln_core(vx, vy, vz, vw, tid, mean, rstd);
    const float4 gv = ((const float4*)g)[tid];
    const float4 bv = ((const float4*)beta)[tid];
    bf16x4v o;
    o[0] = (bf16_t)((vx - mean) * rstd * gv.x + bv.x);
    o[1] = (bf16_t)((vy - mean) * rstd * gv.y + bv.y);
    o[2] = (bf16_t)((vz - mean) * rstd * gv.z + bv.z);
    o[3] = (bf16_t)((vw - mean) * rstd * gv.w + bv.w);
    *(bf16x4v*)(out + (size_t)row * D_ + tid * 4) = o;
}

__global__ __launch_bounds__(256)
void add_ln2(const bf16_t* __restrict__ X, const float* __restrict__ Y,
             const float* __restrict__ g, const float* __restrict__ beta,
             float* __restrict__ out)
{
    const int row = blockIdx.x, tid = threadIdx.x;
    const bf16x4v xv = *(const bf16x4v*)(X + (size_t)row * D_ + tid * 4);
    const float4 yv = ((const float4*)(Y + (size_t)row * D_))[tid];
    const float vx = (float)xv[0] + yv.x, vy = (float)xv[1] + yv.y;
    const float vz = (float)xv[2] + yv.z, vw = (float)xv[3] + yv.w;
    float mean, rstd;
    ln_core(vx, vy, vz, vw, tid, mean, rstd);
    const float4 gv = ((const float4*)g)[tid];
    const float4 bv = ((const float4*)beta)[tid];
    float4 o;
    o.x = (vx - mean) * rstd * gv.x + bv.x;
    o.y = (vy - mean) * rstd * gv.y + bv.y;
    o.z = (vz - mean) * rstd * gv.z + bv.z;
    o.w = (vw - mean) * rstd * gv.w + bv.w;
    ((float4*)(out + (size_t)row * D_))[tid] = o;
}

// ---------------------------------------------------------------------------
extern "C" void kernel_launch(void* const* d_in, const int* in_sizes, int n_in,
                              void* d_out, int out_size, void* d_ws, size_t ws_size,
                              hipStream_t stream)
{
    const float* x    = (const float*)d_in[0];
    const float* Wq   = (const float*)d_in[1];
    const float* Wk   = (const float*)d_in[2];
    const float* Wv   = (const float*)d_in[3];
    const float* fc1w = (const float*)d_in[4];
    const float* fc1b = (const float*)d_in[5];
    const float* fc2w = (const float*)d_in[6];
    const float* fc2b = (const float*)d_in[7];
    const float* ln1w = (const float*)d_in[8];
    const float* ln1b = (const float*)d_in[9];
    const float* ln2w = (const float*)d_in[10];
    const float* ln2b = (const float*)d_in[11];
    const int*   lens = (const int*)d_in[12];
    float* out = (float*)d_out;

    char* ws = (char*)d_ws;
    const size_t MB = 1024 * 1024;
    bf16_t* QKVb  = (bf16_t*)(ws);              // 48 MB: [8192][3072]
    bf16_t* Zb    = (bf16_t*)(ws + 48 * MB);    // 16 MB: [8192][1024] bf16
    bf16_t* X1b   = (bf16_t*)(ws + 80 * MB);    // 16 MB
    bf16_t* xb    = (bf16_t*)(ws + 96 * MB);    // 16 MB (dead after QKV)
    bf16_t* H1b   = (bf16_t*)(ws + 96 * MB);    //   reuses xb slot
    float*  FF    = (float*)(ws + 48 * MB);     //   reuses Zb slot (32 MB)
    bf16_t* WtQKV = (bf16_t*)(ws + 112 * MB);   // 6 MB
    bf16_t* Wt1   = (bf16_t*)(ws + 118 * MB);   // 2 MB
    bf16_t* Wt2   = (bf16_t*)(ws + 120 * MB);   // 2 MB

    const int M = B_ * S_;

    prep<<<dim3(16, 16, 37), 256, 0, stream>>>(x, Wq, Wk, Wv, fc1w, fc2w,
                                               xb, WtQKV, Wt1, Wt2);

    gemm8<0, 256, bf16_t><<<dim3(3072 / 256, M / 256), 512, 0, stream>>>(
        xb, WtQKV, nullptr, nullptr, QKVb, M, 3072, D_);

    attn_mfma<<<dim3(2048), 256, 0, stream>>>(QKVb, lens, Zb);

    add_ln1<<<M, 256, 0, stream>>>(x, Zb, ln1w, ln1b, X1b);

    gemm8<1, 128, bf16_t><<<dim3(D_ / 128, M / 256), 512, 0, stream>>>(
        X1b, Wt1, fc1b, lens, H1b, M, D_, D_);
    gemm8<2, 128, float><<<dim3(D_ / 128, M / 256), 512, 0, stream>>>(
        H1b, Wt2, fc2b, lens, FF, M, D_, D_);

    add_ln2<<<M, 256, 0, stream>>>(X1b, FF, ln2w, ln2b, out);
}

// Round 5
// 310.585 us; speedup vs baseline: 1.1196x; 1.0529x over previous
//
#include <hip/hip_runtime.h>
#include <math.h>

#define B_ 8
#define S_ 1024
#define D_ 1024
#define H_ 16
#define DK_ 64
#define EPS_ 1e-5f

typedef __bf16 bf16_t;
typedef __bf16 bf16x8 __attribute__((ext_vector_type(8)));
typedef __bf16 bf16x4v __attribute__((ext_vector_type(4)));
typedef float  f32x4  __attribute__((ext_vector_type(4)));

__device__ __forceinline__ void gld16(const void* g, void* l) {
    __builtin_amdgcn_global_load_lds(
        (const __attribute__((address_space(1))) void*)g,
        (__attribute__((address_space(3))) void*)l, 16, 0, 0);
}

// ---------------------------------------------------------------------------
// prep: weight transpose+convert+PACK (z=0..4) and x f32->bf16 (z=5..36).
// B-pack layout (R5): elem(n,k) -> [n>>4][k>>3][n&15][k&7]
//   i.e. idx = ((n>>4)*(K/8) + (k>>3))*128 + (n&15)*8 + (k&7),  K = 1024.
// A wave's MFMA B-frag (16 n-rows x 8 k) is then 1 KB CONTIGUOUS -> one
// perfectly-coalesced global_load_dwordx4 per frag, no LDS staging for B.
// ---------------------------------------------------------------------------
__global__ __launch_bounds__(256)
void prep(const float* __restrict__ x,
          const float* __restrict__ Wq, const float* __restrict__ Wk,
          const float* __restrict__ Wv, const float* __restrict__ W1,
          const float* __restrict__ W2, bf16_t* __restrict__ xb,
          bf16_t* __restrict__ WtQKV, bf16_t* __restrict__ Wt1,
          bf16_t* __restrict__ Wt2)
{
    __shared__ float tile[64][65];
    const int tid = threadIdx.x;
    const int z = blockIdx.z;

    if (z >= 5) {   // x convert
        const int blk = (z - 5) * 256 + blockIdx.y * 16 + blockIdx.x;
        const int i = (blk * 256 + tid) * 4;
        const float4 v = *(const float4*)(x + i);
        bf16x4v o = { (bf16_t)v.x, (bf16_t)v.y, (bf16_t)v.z, (bf16_t)v.w };
        *(bf16x4v*)(xb + i) = o;
        return;
    }

    const int n0 = blockIdx.x * 64, k0 = blockIdx.y * 64;
    const int col = tid & 63, r0 = tid >> 6;
    const float* src = (z == 0) ? Wq : (z == 1) ? Wk : (z == 2) ? Wv
                     : (z == 3) ? W1 : W2;
    #pragma unroll
    for (int i = 0; i < 16; i++) {
        const int row = r0 + i * 4;
        float v;
        if (z < 3)
            v = src[((size_t)(n0 >> 6) << 16) + (size_t)(k0 + row) * 64 + col];
        else
            v = src[(size_t)(k0 + row) * D_ + n0 + col];
        tile[row][col] = v;
    }
    __syncthreads();
    // packed store: value for (n = n0+nr, k = k0+col) is tile[col][nr].
    // z-offset works because n-tiles are 16-aligned: z*D*D elems exactly.
    bf16_t* dst = (z < 3) ? (WtQKV + (size_t)z * D_ * D_)
                : (z == 3) ? Wt1 : Wt2;
    #pragma unroll
    for (int i = 0; i < 16; i++) {
        const int nr = r0 + i * 4;
        const int n = n0 + nr, k = k0 + col;
        const size_t pidx = ((size_t)(n >> 4) * (D_ >> 3) + (k >> 3)) * 128
                          + (size_t)(n & 15) * 8 + (k & 7);
        dst[pidx] = (bf16_t)tile[col][nr];
    }
}

// ---------------------------------------------------------------------------
// 128x128 bf16 MFMA GEMM, R5: A via LDS dbuf (global_load_lds), B direct
// to REGISTERS from the packed layout (no B LDS at all).
//   Rationale: R1-R4 all pinned at 26-27% MfmaUtil across four different
//   sync schedules -> the saturated resource was the LDS pipe (~2800 cyc
//   per 256x256 K-tile: 192 ds_read_b128 + 64KB DMA write vs 2480 cyc
//   MFMA), not the schedule. Removing B from LDS halves LDS traffic
//   (A-frags only: 8 ds_read/wave/K-tile) and halves the DMA; B-frags are
//   1KB-contiguous coalesced loads from the packed weights (L2-resident),
//   prefetched one K-tile ahead into ping-pong regs (x2 unroll, no copies
//   -> no forced vmcnt(0)).
//   Block: 256 thr, 4 waves (2m x 2n), per-wave 64x64, acc 4x4 f32x4.
//   BK=64, LDS = 2 x 16 KB -> 2 blocks/CU (inter-block overlap, m114).
//   Per K-tile: { SA(t+1) 4 gld16; LB(t+1) 8 coalesced b128; compute
//   8 ds_read + 32 MFMA; vmcnt(8) [A(t+1) landed, B(t+1) in flight];
//   s_barrier }. Single barrier, counted vmcnt, never 0.
//   EPI: 0 plain; 1 +bias,relu,mask; 2 +bias,mask.
// ---------------------------------------------------------------------------
template<int EPI, typename OUT>
__global__ __launch_bounds__(256, 2)
void gemm_bp(const bf16_t* __restrict__ A, const bf16_t* __restrict__ Bp,
             const float* __restrict__ bias, const int* __restrict__ lens,
             OUT* __restrict__ C, int M, int N, int K)
{
    __shared__ __align__(16) bf16_t As[2][128 * 64];

    const int tid  = threadIdx.x;
    const int lane = tid & 63;
    const int w    = tid >> 6;
    const int quad = lane >> 4, l16 = lane & 15;
    const int wm = w & 1, wn = w >> 1;
    const int sw8 = l16 & 7;

    // bijective XCD-chunked swizzle (nwg % 8 == 0 in all launches)
    const int nwg  = gridDim.x * gridDim.y;
    const int orig = blockIdx.y * gridDim.x + blockIdx.x;
    const int swz  = (orig & 7) * (nwg >> 3) + (orig >> 3);
    const int bn = (swz % gridDim.x) * 128;
    const int bm = (swz / gridDim.x) * 128;

    // A staging: 4 shots x 256 thr x 16B = 16 KB (128 rows x 64 cols).
    // shot s: row = s*32 + (tid>>3); source col chunk-XOR swizzled; LDS linear.
    const int rS  = tid >> 3;
    const int cS  = ((tid & 7) ^ (rS & 7)) << 3;
    const int dOf = w * 1024;

    // B packed: per-lane base for (quad, l16); frag (j,kh) at K-tile t is
    // + j*ntStride + (t*8 + kh*4)*128 elems (uniform offset -> imm/sgpr).
    const size_t ntStride = (size_t)(K >> 3) * 128;
    const bf16_t* Bw = Bp + ((size_t)(bn >> 4) + (size_t)wn * 4) * ntStride
                          + (size_t)quad * 128 + (size_t)l16 * 8;

    f32x4 acc[4][4];
    #pragma unroll
    for (int i = 0; i < 4; i++)
        #pragma unroll
        for (int j = 0; j < 4; j++)
            #pragma unroll
            for (int r = 0; r < 4; r++) acc[i][j][r] = 0.f;

#define SA(b_, kt_) { \
    _Pragma("unroll") \
    for (int s_ = 0; s_ < 4; s_++) \
        gld16(A + (size_t)(bm + s_ * 32 + rS) * K + (kt_) * 64 + cS, \
              (char*)As[b_] + s_ * 4096 + dOf); }
#define LB(dst_, kt_) { \
    _Pragma("unroll") \
    for (int j_ = 0; j_ < 4; j_++) \
        _Pragma("unroll") \
        for (int kh_ = 0; kh_ < 2; kh_++) \
            dst_[j_][kh_] = *(const bf16x8*)(Bw + (size_t)j_ * ntStride \
                                             + ((kt_) * 8 + kh_ * 4) * 128); }
#define KSTEP(cb_, nb_, BC_, BX_, t_) { \
    const int ktn_ = ((t_) + 1 < NKT) ? (t_) + 1 : (t_); \
    SA(nb_, ktn_); \
    LB(BX_, ktn_); \
    __builtin_amdgcn_sched_barrier(0); \
    const bf16_t* Ac = As[cb_]; \
    _Pragma("unroll") \
    for (int kh_ = 0; kh_ < 2; kh_++) { \
        bf16x8 a_[4]; \
        _Pragma("unroll") \
        for (int i_ = 0; i_ < 4; i_++) \
            a_[i_] = *(const bf16x8*)&Ac[(wm * 64 + i_ * 16 + l16) * 64 \
                                         + (((kh_ * 4 + quad) ^ sw8) << 3)]; \
        _Pragma("unroll") \
        for (int i_ = 0; i_ < 4; i_++) \
            _Pragma("unroll") \
            for (int j_ = 0; j_ < 4; j_++) \
                acc[i_][j_] = __builtin_amdgcn_mfma_f32_16x16x32_bf16( \
                    a_[i_], BC_[j_][kh_], acc[i_][j_], 0, 0, 0); \
    } \
    __builtin_amdgcn_sched_barrier(0); \
    asm volatile("s_waitcnt vmcnt(8)" ::: "memory"); \
    __builtin_amdgcn_s_barrier(); }

    const int NKT = K >> 6;   // always even here (K = 1024)

    bf16x8 bA[4][2], bB[4][2];
    SA(0, 0);
    LB(bA, 0);
    asm volatile("s_waitcnt vmcnt(8)" ::: "memory");   // A(0) landed
    __builtin_amdgcn_s_barrier();

    for (int t = 0; t < NKT; t += 2) {
        KSTEP(0, 1, bA, bB, t);
        KSTEP(1, 0, bB, bA, t + 1);
    }

#undef SA
#undef LB
#undef KSTEP

    // ---- epilogue ----
    #pragma unroll
    for (int i = 0; i < 4; i++) {
        #pragma unroll
        for (int r = 0; r < 4; r++) {
            const int m = bm + wm * 64 + i * 16 + quad * 4 + r;
            float keep = 1.f;
            if (EPI != 0) {
                const int s = m & (S_ - 1);
                const int bb = m >> 10;
                keep = (s < lens[bb]) ? 1.f : 0.f;
            }
            #pragma unroll
            for (int j = 0; j < 4; j++) {
                const int n = bn + wn * 64 + j * 16 + l16;
                float v = acc[i][j][r];
                if (EPI != 0) {
                    v += bias[n];
                    if (EPI == 1) v = fmaxf(v, 0.f);
                    v *= keep;
                }
                C[(size_t)m * N + n] = (OUT)v;
            }
        }
    }
}

// ---------------------------------------------------------------------------
// bf16 MFMA flash attention, S^T formulation — software-pipelined k-loop.
// ---------------------------------------------------------------------------
__global__ __launch_bounds__(256, 3)
void attn_mfma(const bf16_t* __restrict__ QKV, const int* __restrict__ lens,
               bf16_t* __restrict__ Z)
{
    __shared__ __align__(16) bf16_t Ks[2][64][64];   // [buf][key][d], chunk-swizzled
    __shared__ __align__(16) bf16_t Vt[2][64][72];   // [buf][d][key ^ 16*(d>>4)]
    __shared__ __align__(16) bf16_t Ps[64][72];      // [q][key], wave-private rows

    const int tid  = threadIdx.x;
    const int lane = tid & 63;
    const int w    = tid >> 6;
    const int quad = lane >> 4;
    const int l16  = lane & 15;
    const int id   = blockIdx.x;
    const int b    = id & 7;            // b fastest -> CU-load balance
    const int h    = (id >> 3) & 15;
    const int qt   = id >> 7;
    const int len  = lens[b];
    const int qbase = qt * 64;
    const bf16_t* Qp = QKV + (size_t)b * S_ * 3072 + (size_t)h * 64;
    const bf16_t* Kp = Qp + 1024;
    const bf16_t* Vp = Qp + 2048;
    const size_t zbase = (size_t)b * S_ * D_ + (size_t)h * 64;

    if (qbase >= len) {   // fully masked query tile -> zeros (bf16)
        const int r = tid >> 2, c0 = (tid & 3) * 16;
        bf16_t* zp = Z + zbase + (size_t)(qbase + r) * D_ + c0;
        uint4 zz = {0u, 0u, 0u, 0u};
        *(uint4*)zp = zz;
        *(uint4*)(zp + 8) = zz;
        return;
    }

    // Q B-frags, fixed for the whole kernel: B[k=d=quad*8+j][n=q=l16]
    const int qrow = qbase + w * 16 + l16;
    const bf16x8 bq0 = *(const bf16x8*)(Qp + (size_t)qrow * 3072 + quad * 8);
    const bf16x8 bq1 = *(const bf16x8*)(Qp + (size_t)qrow * 3072 + 32 + quad * 8);

    // K staging geometry: 2 shots of 256 lanes x 16B cover [64][64] bf16.
    const int kr0  = tid >> 3;          // shot0 row (0..31); shot1 row = kr0+32
    const int kpos = tid & 7;
    const int kc0  = (kpos ^ (kr0 & 7)) << 3;          // shot0 source d-offset
    const int kc1  = (kpos ^ ((kr0 + 32) & 7)) << 3;   // shot1 source d-offset

    // V staging map: thread -> key row vr, d cols vc0..vc0+15, swizzled col vp
    const int vr  = tid >> 2;
    const int vc0 = (tid & 3) * 16;
    const int vp  = vr ^ ((tid & 3) << 4);

    f32x4 o[4];
    #pragma unroll
    for (int dm = 0; dm < 4; dm++)
        #pragma unroll
        for (int r = 0; r < 4; r++) o[dm][r] = 0.f;
    float l_q = 0.f;

    const int ntiles = (len + 63) >> 6;

    // ---- prologue: stage K(0) -> Ks[0], load V(0) into regs ----
    gld16(Kp + (size_t)kr0 * 3072 + kc0,
          (char*)&Ks[0][0][0] + (size_t)(w * 64) * 16);
    gld16(Kp + (size_t)(kr0 + 32) * 3072 + kc1,
          (char*)&Ks[0][0][0] + (size_t)(256 + w * 64) * 16);
    bf16x8 vcur0 = *(const bf16x8*)(Vp + (size_t)vr * 3072 + vc0);
    bf16x8 vcur1 = *(const bf16x8*)(Vp + (size_t)vr * 3072 + vc0 + 8);
    __syncthreads();   // vmcnt(0) drain: Ks[0] ready

    for (int t = 0; t < ntiles; t++) {
        const int k0 = t * 64;
        const int cb = t & 1, nb = (t + 1) & 1;
        const int kn0 = (t + 1 < ntiles ? t + 1 : t) * 64;

        // ---- issue prefetch for tile t+1 (K -> Ks[nb], V -> regs) ----
        gld16(Kp + (size_t)(kn0 + kr0) * 3072 + kc0,
              (char*)&Ks[nb][0][0] + (size_t)(w * 64) * 16);
        gld16(Kp + (size_t)(kn0 + kr0 + 32) * 3072 + kc1,
              (char*)&Ks[nb][0][0] + (size_t)(256 + w * 64) * 16);
        const bf16_t* vsrc = Vp + (size_t)(kn0 + vr) * 3072 + vc0;
        const bf16x8 vn0 = *(const bf16x8*)vsrc;
        const bf16x8 vn1 = *(const bf16x8*)(vsrc + 8);
        __builtin_amdgcn_sched_barrier(0);   // pin prefetch issue at loop top

        // ---- S^T = K Q^T from Ks[cb], exp, stage P ----
        #pragma unroll
        for (int kt = 0; kt < 4; kt++) {
            const int r = kt * 16 + l16;           // r&7 == l16&7
            const bf16x8 ak0 = *(const bf16x8*)&Ks[cb][r][(quad ^ (l16 & 7)) << 3];
            const bf16x8 ak1 = *(const bf16x8*)&Ks[cb][r][((4 + quad) ^ (l16 & 7)) << 3];
            f32x4 z4 = {0.f, 0.f, 0.f, 0.f};
            z4 = __builtin_amdgcn_mfma_f32_16x16x32_bf16(ak0, bq0, z4, 0, 0, 0);
            const f32x4 sfv = __builtin_amdgcn_mfma_f32_16x16x32_bf16(ak1, bq1, z4, 0, 0, 0);
            bf16x4v pk;
            #pragma unroll
            for (int r2 = 0; r2 < 4; r2++) {
                const int key = k0 + kt * 16 + quad * 4 + r2;
                float p = __expf(sfv[r2] * 0.125f);
                p = (key < len) ? p : 0.f;
                l_q += p;
                pk[r2] = (bf16_t)p;
            }
            *(bf16x4v*)&Ps[w * 16 + l16][kt * 16 + quad * 4] = pk;
        }

        // ---- scatter V(t) regs -> Vt[cb] (transposed + XOR swizzle) ----
        #pragma unroll
        for (int i = 0; i < 8; i++) Vt[cb][vc0 + i][vp] = vcur0[i];
        #pragma unroll
        for (int i = 0; i < 8; i++) Vt[cb][vc0 + 8 + i][vp] = vcur1[i];
        vcur0 = vn0;
        vcur1 = vn1;
        __syncthreads();   // single barrier/iter

        // ---- O^T += V^T P^T ----
        const bf16x8 bp0 = *(const bf16x8*)&Ps[w * 16 + l16][quad * 8];
        const bf16x8 bp1 = *(const bf16x8*)&Ps[w * 16 + l16][32 + quad * 8];
        #pragma unroll
        for (int dm = 0; dm < 4; dm++) {
            const bf16x8 av0 = *(const bf16x8*)&Vt[cb][dm * 16 + l16][(quad * 8) ^ (dm * 16)];
            const bf16x8 av1 = *(const bf16x8*)&Vt[cb][dm * 16 + l16][(32 + quad * 8) ^ (dm * 16)];
            o[dm] = __builtin_amdgcn_mfma_f32_16x16x32_bf16(av0, bp0, o[dm], 0, 0, 0);
            o[dm] = __builtin_amdgcn_mfma_f32_16x16x32_bf16(av1, bp1, o[dm], 0, 0, 0);
        }
    }

    // ---- final l reduce + epilogue ----
    l_q += __shfl_xor(l_q, 16);
    l_q += __shfl_xor(l_q, 32);
    const int qg = qbase + w * 16 + l16;
    const float inv = (qg < len) ? 1.f / l_q : 0.f;
    bf16_t* zrow = Z + zbase + (size_t)qg * D_;
    #pragma unroll
    for (int dm = 0; dm < 4; dm++) {
        bf16x4v st;
        #pragma unroll
        for (int r = 0; r < 4; r++) st[r] = (bf16_t)(o[dm][r] * inv);
        *(bf16x4v*)(zrow + dm * 16 + quad * 4) = st;
    }
}

// ---------------------------------------------------------------------------
// Residual-add + LayerNorm, D=1024, one block per row.
// ---------------------------------------------------------------------------
__device__ __forceinline__ void ln_core(float vx, float vy, float vz, float vw,
                                        int tid, float& mean, float& rstd)
{
    __shared__ float red[8];
    float s = vx + vy + vz + vw;
    #pragma unroll
    for (int off = 32; off; off >>= 1) s += __shfl_xor(s, off, 64);
    const int wv = tid >> 6, lane = tid & 63;
    if (lane == 0) red[wv] = s;
    __syncthreads();
    mean = (red[0] + red[1] + red[2] + red[3]) * (1.f / D_);
    const float dx = vx - mean, dy = vy - mean, dz = vz - mean, dw = vw - mean;
    float s2 = dx * dx + dy * dy + dz * dz + dw * dw;
    #pragma unroll
    for (int off = 32; off; off >>= 1) s2 += __shfl_xor(s2, off, 64);
    if (lane == 0) red[4 + wv] = s2;
    __syncthreads();
    rstd = rsqrtf((red[4] + red[5] + red[6] + red[7]) * (1.f / D_) + EPS_);
}

__global__ __launch_bounds__(256)
void add_ln1(const float* __restrict__ X, const bf16_t* __restrict__ Y,
             const float* __restrict__ g, const float* __restrict__ beta,
             bf16_t* __restrict__ out)
{
    const int row = blockIdx.x, tid = threadIdx.x;
    const float4 xv = ((const float4*)(X + (size_t)row * D_))[tid];
    const bf16x4v yv = *(const bf16x4v*)(Y + (size_t)row * D_ + tid * 4);
    const float vx = xv.x + (float)yv[0], vy = xv.y + (float)yv[1];
    const float vz = xv.z + (float)yv[2], vw = xv.w + (float)yv[3];
    float mean, rstd;
    ln_core(vx, vy, vz, vw, tid, mean, rstd);
    const float4 gv = ((const float4*)g)[tid];
    const float4 bv = ((const float4*)beta)[tid];
    bf16x4v o;
    o[0] = (bf16_t)((vx - mean) * rstd * gv.x + bv.x);
    o[1] = (bf16_t)((vy - mean) * rstd * gv.y + bv.y);
    o[2] = (bf16_t)((vz - mean) * rstd * gv.z + bv.z);
    o[3] = (bf16_t)((vw - mean) * rstd * gv.w + bv.w);
    *(bf16x4v*)(out + (size_t)row * D_ + tid * 4) = o;
}

__global__ __launch_bounds__(256)
void add_ln2(const bf16_t* __restrict__ X, const float* __restrict__ Y,
             const float* __restrict__ g, const float* __restrict__ beta,
             float* __restrict__ out)
{
    const int row = blockIdx.x, tid = threadIdx.x;
    const bf16x4v xv = *(const bf16x4v*)(X + (size_t)row * D_ + tid * 4);
    const float4 yv = ((const float4*)(Y + (size_t)row * D_))[tid];
    const float vx = (float)xv[0] + yv.x, vy = (float)xv[1] + yv.y;
    const float vz = (float)xv[2] + yv.z, vw = (float)xv[3] + yv.w;
    float mean, rstd;
    ln_core(vx, vy, vz, vw, tid, mean, rstd);
    const float4 gv = ((const float4*)g)[tid];
    const float4 bv = ((const float4*)beta)[tid];
    float4 o;
    o.x = (vx - mean) * rstd * gv.x + bv.x;
    o.y = (vy - mean) * rstd * gv.y + bv.y;
    o.z = (vz - mean) * rstd * gv.z + bv.z;
    o.w = (vw - mean) * rstd * gv.w + bv.w;
    ((float4*)(out + (size_t)row * D_))[tid] = o;
}

// ---------------------------------------------------------------------------
extern "C" void kernel_launch(void* const* d_in, const int* in_sizes, int n_in,
                              void* d_out, int out_size, void* d_ws, size_t ws_size,
                              hipStream_t stream)
{
    const float* x    = (const float*)d_in[0];
    const float* Wq   = (const float*)d_in[1];
    const float* Wk   = (const float*)d_in[2];
    const float* Wv   = (const float*)d_in[3];
    const float* fc1w = (const float*)d_in[4];
    const float* fc1b = (const float*)d_in[5];
    const float* fc2w = (const float*)d_in[6];
    const float* fc2b = (const float*)d_in[7];
    const float* ln1w = (const float*)d_in[8];
    const float* ln1b = (const float*)d_in[9];
    const float* ln2w = (const float*)d_in[10];
    const float* ln2b = (const float*)d_in[11];
    const int*   lens = (const int*)d_in[12];
    float* out = (float*)d_out;

    char* ws = (char*)d_ws;
    const size_t MB = 1024 * 1024;
    bf16_t* QKVb  = (bf16_t*)(ws);              // 48 MB: [8192][3072]
    bf16_t* Zb    = (bf16_t*)(ws + 48 * MB);    // 16 MB: [8192][1024] bf16
    bf16_t* X1b   = (bf16_t*)(ws + 80 * MB);    // 16 MB
    bf16_t* xb    = (bf16_t*)(ws + 96 * MB);    // 16 MB (dead after QKV)
    bf16_t* H1b   = (bf16_t*)(ws + 96 * MB);    //   reuses xb slot
    float*  FF    = (float*)(ws + 48 * MB);     //   reuses Zb slot (32 MB)
    bf16_t* WtQKV = (bf16_t*)(ws + 112 * MB);   // 6 MB (packed)
    bf16_t* Wt1   = (bf16_t*)(ws + 118 * MB);   // 2 MB (packed)
    bf16_t* Wt2   = (bf16_t*)(ws + 120 * MB);   // 2 MB (packed)

    const int M = B_ * S_;

    prep<<<dim3(16, 16, 37), 256, 0, stream>>>(x, Wq, Wk, Wv, fc1w, fc2w,
                                               xb, WtQKV, Wt1, Wt2);

    gemm_bp<0, bf16_t><<<dim3(3072 / 128, M / 128), 256, 0, stream>>>(
        xb, WtQKV, nullptr, nullptr, QKVb, M, 3072, D_);

    attn_mfma<<<dim3(2048), 256, 0, stream>>>(QKVb, lens, Zb);

    add_ln1<<<M, 256, 0, stream>>>(x, Zb, ln1w, ln1b, X1b);

    gemm_bp<1, bf16_t><<<dim3(D_ / 128, M / 128), 256, 0, stream>>>(
        X1b, Wt1, fc1b, lens, H1b, M, D_, D_);
    gemm_bp<2, float><<<dim3(D_ / 128, M / 128), 256, 0, stream>>>(
        H1b, Wt2, fc2b, lens, FF, M, D_, D_);

    add_ln2<<<M, 256, 0, stream>>>(X1b, FF, ln2w, ln2b, out);
}

// Round 6
// 305.352 us; speedup vs baseline: 1.1388x; 1.0171x over previous
//
#include <hip/hip_runtime.h>
#include <math.h>

#define B_ 8
#define S_ 1024
#define D_ 1024
#define H_ 16
#define DK_ 64
#define EPS_ 1e-5f

typedef __bf16 bf16_t;
typedef __bf16 bf16x8 __attribute__((ext_vector_type(8)));
typedef __bf16 bf16x4v __attribute__((ext_vector_type(4)));
typedef float  f32x4  __attribute__((ext_vector_type(4)));

__device__ __forceinline__ void gld16(const void* g, void* l) {
    __builtin_amdgcn_global_load_lds(
        (const __attribute__((address_space(1))) void*)g,
        (__attribute__((address_space(3))) void*)l, 16, 0, 0);
}

// ---------------------------------------------------------------------------
// prep: weight transpose+convert+PACK (z=0..4) and x f32->bf16 (z=5..36).
// B-pack layout: elem(n,k) -> [n>>4][k>>3][n&15][k&7]; a wave's MFMA B-frag
// (16 n x 8 k) is 1 KB contiguous -> one coalesced b128 load, no B LDS.
// ---------------------------------------------------------------------------
__global__ __launch_bounds__(256)
void prep(const float* __restrict__ x,
          const float* __restrict__ Wq, const float* __restrict__ Wk,
          const float* __restrict__ Wv, const float* __restrict__ W1,
          const float* __restrict__ W2, bf16_t* __restrict__ xb,
          bf16_t* __restrict__ WtQKV, bf16_t* __restrict__ Wt1,
          bf16_t* __restrict__ Wt2)
{
    __shared__ float tile[64][65];
    const int tid = threadIdx.x;
    const int z = blockIdx.z;

    if (z >= 5) {   // x convert
        const int blk = (z - 5) * 256 + blockIdx.y * 16 + blockIdx.x;
        const int i = (blk * 256 + tid) * 4;
        const float4 v = *(const float4*)(x + i);
        bf16x4v o = { (bf16_t)v.x, (bf16_t)v.y, (bf16_t)v.z, (bf16_t)v.w };
        *(bf16x4v*)(xb + i) = o;
        return;
    }

    const int n0 = blockIdx.x * 64, k0 = blockIdx.y * 64;
    const int col = tid & 63, r0 = tid >> 6;
    const float* src = (z == 0) ? Wq : (z == 1) ? Wk : (z == 2) ? Wv
                     : (z == 3) ? W1 : W2;
    #pragma unroll
    for (int i = 0; i < 16; i++) {
        const int row = r0 + i * 4;
        float v;
        if (z < 3)
            v = src[((size_t)(n0 >> 6) << 16) + (size_t)(k0 + row) * 64 + col];
        else
            v = src[(size_t)(k0 + row) * D_ + n0 + col];
        tile[row][col] = v;
    }
    __syncthreads();
    bf16_t* dst = (z < 3) ? (WtQKV + (size_t)z * D_ * D_)
                : (z == 3) ? Wt1 : Wt2;
    #pragma unroll
    for (int i = 0; i < 16; i++) {
        const int nr = r0 + i * 4;
        const int n = n0 + nr, k = k0 + col;
        const size_t pidx = ((size_t)(n >> 4) * (D_ >> 3) + (k >> 3)) * 128
                          + (size_t)(n & 15) * 8 + (k & 7);
        dst[pidx] = (bf16_t)tile[col][nr];
    }
}

// ---------------------------------------------------------------------------
// 128x128 bf16 MFMA GEMM: A via LDS dbuf (global_load_lds), B direct to
// registers from packed layout (no B LDS). Verified R5: removed the LDS-pipe
// saturation that pinned R1-R4 at 26-27% MfmaUtil.
// ---------------------------------------------------------------------------
template<int EPI, typename OUT>
__global__ __launch_bounds__(256, 2)
void gemm_bp(const bf16_t* __restrict__ A, const bf16_t* __restrict__ Bp,
             const float* __restrict__ bias, const int* __restrict__ lens,
             OUT* __restrict__ C, int M, int N, int K)
{
    __shared__ __align__(16) bf16_t As[2][128 * 64];

    const int tid  = threadIdx.x;
    const int lane = tid & 63;
    const int w    = tid >> 6;
    const int quad = lane >> 4, l16 = lane & 15;
    const int wm = w & 1, wn = w >> 1;
    const int sw8 = l16 & 7;

    const int nwg  = gridDim.x * gridDim.y;
    const int orig = blockIdx.y * gridDim.x + blockIdx.x;
    const int swz  = (orig & 7) * (nwg >> 3) + (orig >> 3);
    const int bn = (swz % gridDim.x) * 128;
    const int bm = (swz / gridDim.x) * 128;

    const int rS  = tid >> 3;
    const int cS  = ((tid & 7) ^ (rS & 7)) << 3;
    const int dOf = w * 1024;

    const size_t ntStride = (size_t)(K >> 3) * 128;
    const bf16_t* Bw = Bp + ((size_t)(bn >> 4) + (size_t)wn * 4) * ntStride
                          + (size_t)quad * 128 + (size_t)l16 * 8;

    f32x4 acc[4][4];
    #pragma unroll
    for (int i = 0; i < 4; i++)
        #pragma unroll
        for (int j = 0; j < 4; j++)
            #pragma unroll
            for (int r = 0; r < 4; r++) acc[i][j][r] = 0.f;

#define SA(b_, kt_) { \
    _Pragma("unroll") \
    for (int s_ = 0; s_ < 4; s_++) \
        gld16(A + (size_t)(bm + s_ * 32 + rS) * K + (kt_) * 64 + cS, \
              (char*)As[b_] + s_ * 4096 + dOf); }
#define LB(dst_, kt_) { \
    _Pragma("unroll") \
    for (int j_ = 0; j_ < 4; j_++) \
        _Pragma("unroll") \
        for (int kh_ = 0; kh_ < 2; kh_++) \
            dst_[j_][kh_] = *(const bf16x8*)(Bw + (size_t)j_ * ntStride \
                                             + ((kt_) * 8 + kh_ * 4) * 128); }
#define KSTEP(cb_, nb_, BC_, BX_, t_) { \
    const int ktn_ = ((t_) + 1 < NKT) ? (t_) + 1 : (t_); \
    SA(nb_, ktn_); \
    LB(BX_, ktn_); \
    __builtin_amdgcn_sched_barrier(0); \
    const bf16_t* Ac = As[cb_]; \
    _Pragma("unroll") \
    for (int kh_ = 0; kh_ < 2; kh_++) { \
        bf16x8 a_[4]; \
        _Pragma("unroll") \
        for (int i_ = 0; i_ < 4; i_++) \
            a_[i_] = *(const bf16x8*)&Ac[(wm * 64 + i_ * 16 + l16) * 64 \
                                         + (((kh_ * 4 + quad) ^ sw8) << 3)]; \
        _Pragma("unroll") \
        for (int i_ = 0; i_ < 4; i_++) \
            _Pragma("unroll") \
            for (int j_ = 0; j_ < 4; j_++) \
                acc[i_][j_] = __builtin_amdgcn_mfma_f32_16x16x32_bf16( \
                    a_[i_], BC_[j_][kh_], acc[i_][j_], 0, 0, 0); \
    } \
    __builtin_amdgcn_sched_barrier(0); \
    asm volatile("s_waitcnt vmcnt(8)" ::: "memory"); \
    __builtin_amdgcn_s_barrier(); }

    const int NKT = K >> 6;

    bf16x8 bA[4][2], bB[4][2];
    SA(0, 0);
    LB(bA, 0);
    asm volatile("s_waitcnt vmcnt(8)" ::: "memory");
    __builtin_amdgcn_s_barrier();

    for (int t = 0; t < NKT; t += 2) {
        KSTEP(0, 1, bA, bB, t);
        KSTEP(1, 0, bB, bA, t + 1);
    }

#undef SA
#undef LB
#undef KSTEP

    #pragma unroll
    for (int i = 0; i < 4; i++) {
        #pragma unroll
        for (int r = 0; r < 4; r++) {
            const int m = bm + wm * 64 + i * 16 + quad * 4 + r;
            float keep = 1.f;
            if (EPI != 0) {
                const int s = m & (S_ - 1);
                const int bb = m >> 10;
                keep = (s < lens[bb]) ? 1.f : 0.f;
            }
            #pragma unroll
            for (int j = 0; j < 4; j++) {
                const int n = bn + wn * 64 + j * 16 + l16;
                float v = acc[i][j][r];
                if (EPI != 0) {
                    v += bias[n];
                    if (EPI == 1) v = fmaxf(v, 0.f);
                    v *= keep;
                }
                C[(size_t)m * N + n] = (OUT)v;
            }
        }
    }
}

// ---------------------------------------------------------------------------
// bf16 MFMA flash attention, S^T formulation — R6: QBLK=128, 8 waves.
//   R5 showed attn latency-bound at 1760 cyc/block-iter (MfmaUtil 9.9%) with
//   per-iter fixed costs (K staging, V scatter, barrier, exp) amortized over
//   only 64 q-rows. QBLK 64->128 (512 thr): machine iteration count halves
//   (24.6K -> 12.3K block-tiles), K/V HBM traffic halves, staged-tile MFMA
//   doubles; per-wave inner loop unchanged. LDS 52 KB -> 3 blocks/CU.
//   K staging = ONE 512-thread gld16 shot. All swizzle/race invariants
//   carry over (scatter col = key ^ ((d>>4)<<4) matches PV read XOR).
// ---------------------------------------------------------------------------
__global__ __launch_bounds__(512, 4)
void attn_mfma(const bf16_t* __restrict__ QKV, const int* __restrict__ lens,
               bf16_t* __restrict__ Z)
{
    __shared__ __align__(16) bf16_t Ks[2][64][64];   // [buf][key][d], chunk-swizzled
    __shared__ __align__(16) bf16_t Vt[2][64][72];   // [buf][d][key ^ 16*(d>>4)]
    __shared__ __align__(16) bf16_t Ps[128][72];     // [q][key], wave-private rows

    const int tid  = threadIdx.x;
    const int lane = tid & 63;
    const int w    = tid >> 6;          // 0..7
    const int quad = lane >> 4;
    const int l16  = lane & 15;
    const int id   = blockIdx.x;        // 1024 blocks
    const int b    = id & 7;            // b fastest -> CU-load balance
    const int h    = (id >> 3) & 15;
    const int qt   = id >> 7;           // 0..7
    const int len  = lens[b];
    const int qbase = qt * 128;
    const bf16_t* Qp = QKV + (size_t)b * S_ * 3072 + (size_t)h * 64;
    const bf16_t* Kp = Qp + 1024;
    const bf16_t* Vp = Qp + 2048;
    const size_t zbase = (size_t)b * S_ * D_ + (size_t)h * 64;

    if (qbase >= len) {   // fully masked query tile -> zeros (bf16)
        const int r = tid >> 2, c0 = (tid & 3) * 16;
        bf16_t* zp = Z + zbase + (size_t)(qbase + r) * D_ + c0;
        uint4 zz = {0u, 0u, 0u, 0u};
        *(uint4*)zp = zz;
        *(uint4*)(zp + 8) = zz;
        return;
    }

    // Q B-frags, fixed for the whole kernel: B[k=d=quad*8+j][n=q=l16]
    const int qrow = qbase + w * 16 + l16;
    const bf16x8 bq0 = *(const bf16x8*)(Qp + (size_t)qrow * 3072 + quad * 8);
    const bf16x8 bq1 = *(const bf16x8*)(Qp + (size_t)qrow * 3072 + 32 + quad * 8);

    // K staging: ONE shot, 512 lanes x 16B = [64][64] bf16.
    const int kr = tid >> 3;                        // 0..63
    const int kc = ((tid & 7) ^ (kr & 7)) << 3;     // swizzled source d-offset

    // V staging: thread -> key row vr, d cols vc0..vc0+7, swizzled col vp
    const int vr  = tid >> 3;                       // 0..63
    const int cg8 = tid & 7;
    const int vc0 = cg8 * 8;
    const int vp  = vr ^ ((cg8 >> 1) << 4);

    f32x4 o[4];
    #pragma unroll
    for (int dm = 0; dm < 4; dm++)
        #pragma unroll
        for (int r = 0; r < 4; r++) o[dm][r] = 0.f;
    float l_q = 0.f;

    const int ntiles = (len + 63) >> 6;

    // ---- prologue: stage K(0) -> Ks[0], load V(0) into regs ----
    gld16(Kp + (size_t)kr * 3072 + kc, (char*)&Ks[0][0][0] + w * 1024);
    bf16x8 vcur = *(const bf16x8*)(Vp + (size_t)vr * 3072 + vc0);
    __syncthreads();   // vmcnt(0) drain: Ks[0] ready

    for (int t = 0; t < ntiles; t++) {
        const int k0 = t * 64;
        const int cb = t & 1, nb = (t + 1) & 1;
        const int kn0 = (t + 1 < ntiles ? t + 1 : t) * 64;

        // ---- issue prefetch for tile t+1 (K -> Ks[nb], V -> regs) ----
        gld16(Kp + (size_t)(kn0 + kr) * 3072 + kc, (char*)&Ks[nb][0][0] + w * 1024);
        const bf16x8 vn = *(const bf16x8*)(Vp + (size_t)(kn0 + vr) * 3072 + vc0);
        __builtin_amdgcn_sched_barrier(0);   // pin prefetch issue at loop top

        // ---- S^T = K Q^T from Ks[cb], exp, stage P ----
        #pragma unroll
        for (int kt = 0; kt < 4; kt++) {
            const int r = kt * 16 + l16;           // r&7 == l16&7
            const bf16x8 ak0 = *(const bf16x8*)&Ks[cb][r][(quad ^ (l16 & 7)) << 3];
            const bf16x8 ak1 = *(const bf16x8*)&Ks[cb][r][((4 + quad) ^ (l16 & 7)) << 3];
            f32x4 z4 = {0.f, 0.f, 0.f, 0.f};
            z4 = __builtin_amdgcn_mfma_f32_16x16x32_bf16(ak0, bq0, z4, 0, 0, 0);
            const f32x4 sfv = __builtin_amdgcn_mfma_f32_16x16x32_bf16(ak1, bq1, z4, 0, 0, 0);
            bf16x4v pk;
            #pragma unroll
            for (int r2 = 0; r2 < 4; r2++) {
                const int key = k0 + kt * 16 + quad * 4 + r2;
                float p = __expf(sfv[r2] * 0.125f);
                p = (key < len) ? p : 0.f;
                l_q += p;
                pk[r2] = (bf16_t)p;
            }
            *(bf16x4v*)&Ps[w * 16 + l16][kt * 16 + quad * 4] = pk;
        }

        // ---- scatter V(t) regs -> Vt[cb] (transposed + XOR swizzle) ----
        #pragma unroll
        for (int i = 0; i < 8; i++) Vt[cb][vc0 + i][vp] = vcur[i];
        vcur = vn;
        __syncthreads();   // single barrier/iter

        // ---- O^T += V^T P^T ----
        const bf16x8 bp0 = *(const bf16x8*)&Ps[w * 16 + l16][quad * 8];
        const bf16x8 bp1 = *(const bf16x8*)&Ps[w * 16 + l16][32 + quad * 8];
        #pragma unroll
        for (int dm = 0; dm < 4; dm++) {
            const bf16x8 av0 = *(const bf16x8*)&Vt[cb][dm * 16 + l16][(quad * 8) ^ (dm * 16)];
            const bf16x8 av1 = *(const bf16x8*)&Vt[cb][dm * 16 + l16][(32 + quad * 8) ^ (dm * 16)];
            o[dm] = __builtin_amdgcn_mfma_f32_16x16x32_bf16(av0, bp0, o[dm], 0, 0, 0);
            o[dm] = __builtin_amdgcn_mfma_f32_16x16x32_bf16(av1, bp1, o[dm], 0, 0, 0);
        }
    }

    // ---- final l reduce + epilogue ----
    l_q += __shfl_xor(l_q, 16);
    l_q += __shfl_xor(l_q, 32);
    const int qg = qbase + w * 16 + l16;
    const float inv = (qg < len) ? 1.f / l_q : 0.f;
    bf16_t* zrow = Z + zbase + (size_t)qg * D_;
    #pragma unroll
    for (int dm = 0; dm < 4; dm++) {
        bf16x4v st;
        #pragma unroll
        for (int r = 0; r < 4; r++) st[r] = (bf16_t)(o[dm][r] * inv);
        *(bf16x4v*)(zrow + dm * 16 + quad * 4) = st;
    }
}

// ---------------------------------------------------------------------------
// Residual-add + LayerNorm, D=1024, one block per row.
// ---------------------------------------------------------------------------
__device__ __forceinline__ void ln_core(float vx, float vy, float vz, float vw,
                                        int tid, float& mean, float& rstd)
{
    __shared__ float red[8];
    float s = vx + vy + vz + vw;
    #pragma unroll
    for (int off = 32; off; off >>= 1) s += __shfl_xor(s, off, 64);
    const int wv = tid >> 6, lane = tid & 63;
    if (lane == 0) red[wv] = s;
    __syncthreads();
    mean = (red[0] + red[1] + red[2] + red[3]) * (1.f / D_);
    const float dx = vx - mean, dy = vy - mean, dz = vz - mean, dw = vw - mean;
    float s2 = dx * dx + dy * dy + dz * dz + dw * dw;
    #pragma unroll
    for (int off = 32; off; off >>= 1) s2 += __shfl_xor(s2, off, 64);
    if (lane == 0) red[4 + wv] = s2;
    __syncthreads();
    rstd = rsqrtf((red[4] + red[5] + red[6] + red[7]) * (1.f / D_) + EPS_);
}

__global__ __launch_bounds__(256)
void add_ln1(const float* __restrict__ X, const bf16_t* __restrict__ Y,
             const float* __restrict__ g, const float* __restrict__ beta,
             bf16_t* __restrict__ out)
{
    const int row = blockIdx.x, tid = threadIdx.x;
    const float4 xv = ((const float4*)(X + (size_t)row * D_))[tid];
    const bf16x4v yv = *(const bf16x4v*)(Y + (size_t)row * D_ + tid * 4);
    const float vx = xv.x + (float)yv[0], vy = xv.y + (float)yv[1];
    const float vz = xv.z + (float)yv[2], vw = xv.w + (float)yv[3];
    float mean, rstd;
    ln_core(vx, vy, vz, vw, tid, mean, rstd);
    const float4 gv = ((const float4*)g)[tid];
    const float4 bv = ((const float4*)beta)[tid];
    bf16x4v o;
    o[0] = (bf16_t)((vx - mean) * rstd * gv.x + bv.x);
    o[1] = (bf16_t)((vy - mean) * rstd * gv.y + bv.y);
    o[2] = (bf16_t)((vz - mean) * rstd * gv.z + bv.z);
    o[3] = (bf16_t)((vw - mean) * rstd * gv.w + bv.w);
    *(bf16x4v*)(out + (size_t)row * D_ + tid * 4) = o;
}

__global__ __launch_bounds__(256)
void add_ln2(const bf16_t* __restrict__ X, const float* __restrict__ Y,
             const float* __restrict__ g, const float* __restrict__ beta,
             float* __restrict__ out)
{
    const int row = blockIdx.x, tid = threadIdx.x;
    const bf16x4v xv = *(const bf16x4v*)(X + (size_t)row * D_ + tid * 4);
    const float4 yv = ((const float4*)(Y + (size_t)row * D_))[tid];
    const float vx = (float)xv[0] + yv.x, vy = (float)xv[1] + yv.y;
    const float vz = (float)xv[2] + yv.z, vw = (float)xv[3] + yv.w;
    float mean, rstd;
    ln_core(vx, vy, vz, vw, tid, mean, rstd);
    const float4 gv = ((const float4*)g)[tid];
    const float4 bv = ((const float4*)beta)[tid];
    float4 o;
    o.x = (vx - mean) * rstd * gv.x + bv.x;
    o.y = (vy - mean) * rstd * gv.y + bv.y;
    o.z = (vz - mean) * rstd * gv.z + bv.z;
    o.w = (vw - mean) * rstd * gv.w + bv.w;
    ((float4*)(out + (size_t)row * D_))[tid] = o;
}

// ---------------------------------------------------------------------------
extern "C" void kernel_launch(void* const* d_in, const int* in_sizes, int n_in,
                              void* d_out, int out_size, void* d_ws, size_t ws_size,
                              hipStream_t stream)
{
    const float* x    = (const float*)d_in[0];
    const float* Wq   = (const float*)d_in[1];
    const float* Wk   = (const float*)d_in[2];
    const float* Wv   = (const float*)d_in[3];
    const float* fc1w = (const float*)d_in[4];
    const float* fc1b = (const float*)d_in[5];
    const float* fc2w = (const float*)d_in[6];
    const float* fc2b = (const float*)d_in[7];
    const float* ln1w = (const float*)d_in[8];
    const float* ln1b = (const float*)d_in[9];
    const float* ln2w = (const float*)d_in[10];
    const float* ln2b = (const float*)d_in[11];
    const int*   lens = (const int*)d_in[12];
    float* out = (float*)d_out;

    char* ws = (char*)d_ws;
    const size_t MB = 1024 * 1024;
    bf16_t* QKVb  = (bf16_t*)(ws);              // 48 MB: [8192][3072]
    bf16_t* Zb    = (bf16_t*)(ws + 48 * MB);    // 16 MB: [8192][1024] bf16
    bf16_t* X1b   = (bf16_t*)(ws + 80 * MB);    // 16 MB
    bf16_t* xb    = (bf16_t*)(ws + 96 * MB);    // 16 MB (dead after QKV)
    bf16_t* H1b   = (bf16_t*)(ws + 96 * MB);    //   reuses xb slot
    float*  FF    = (float*)(ws + 48 * MB);     //   reuses Zb slot (32 MB)
    bf16_t* WtQKV = (bf16_t*)(ws + 112 * MB);   // 6 MB (packed)
    bf16_t* Wt1   = (bf16_t*)(ws + 118 * MB);   // 2 MB (packed)
    bf16_t* Wt2   = (bf16_t*)(ws + 120 * MB);   // 2 MB (packed)

    const int M = B_ * S_;

    prep<<<dim3(16, 16, 37), 256, 0, stream>>>(x, Wq, Wk, Wv, fc1w, fc2w,
                                               xb, WtQKV, Wt1, Wt2);

    gemm_bp<0, bf16_t><<<dim3(3072 / 128, M / 128), 256, 0, stream>>>(
        xb, WtQKV, nullptr, nullptr, QKVb, M, 3072, D_);

    attn_mfma<<<dim3(1024), 512, 0, stream>>>(QKVb, lens, Zb);

    add_ln1<<<M, 256, 0, stream>>>(x, Zb, ln1w, ln1b, X1b);

    gemm_bp<1, bf16_t><<<dim3(D_ / 128, M / 128), 256, 0, stream>>>(
        X1b, Wt1, fc1b, lens, H1b, M, D_, D_);
    gemm_bp<2, float><<<dim3(D_ / 128, M / 128), 256, 0, stream>>>(
        H1b, Wt2, fc2b, lens, FF, M, D_, D_);

    add_ln2<<<M, 256, 0, stream>>>(X1b, FF, ln2w, ln2b, out);
}

// Round 7
// 304.354 us; speedup vs baseline: 1.1425x; 1.0033x over previous
//
#include <hip/hip_runtime.h>
#include <math.h>

#define B_ 8
#define S_ 1024
#define D_ 1024
#define H_ 16
#define DK_ 64
#define EPS_ 1e-5f

typedef __bf16 bf16_t;
typedef __bf16 bf16x8 __attribute__((ext_vector_type(8)));
typedef __bf16 bf16x4v __attribute__((ext_vector_type(4)));
typedef float  f32x4  __attribute__((ext_vector_type(4)));

__device__ __forceinline__ void gld16(const void* g, void* l) {
    __builtin_amdgcn_global_load_lds(
        (const __attribute__((address_space(1))) void*)g,
        (__attribute__((address_space(3))) void*)l, 16, 0, 0);
}

// ---------------------------------------------------------------------------
// prep: weight transpose+convert+PACK (z=0..4) and x f32->bf16 (z=5..36).
// B-pack layout: elem(n,k) -> [n>>4][k>>3][n&15][k&7]; a wave's MFMA B-frag
// (16 n x 8 k) is 1 KB contiguous -> one coalesced b128 load, no B LDS.
// ---------------------------------------------------------------------------
__global__ __launch_bounds__(256)
void prep(const float* __restrict__ x,
          const float* __restrict__ Wq, const float* __restrict__ Wk,
          const float* __restrict__ Wv, const float* __restrict__ W1,
          const float* __restrict__ W2, bf16_t* __restrict__ xb,
          bf16_t* __restrict__ WtQKV, bf16_t* __restrict__ Wt1,
          bf16_t* __restrict__ Wt2)
{
    __shared__ float tile[64][65];
    const int tid = threadIdx.x;
    const int z = blockIdx.z;

    if (z >= 5) {   // x convert
        const int blk = (z - 5) * 256 + blockIdx.y * 16 + blockIdx.x;
        const int i = (blk * 256 + tid) * 4;
        const float4 v = *(const float4*)(x + i);
        bf16x4v o = { (bf16_t)v.x, (bf16_t)v.y, (bf16_t)v.z, (bf16_t)v.w };
        *(bf16x4v*)(xb + i) = o;
        return;
    }

    const int n0 = blockIdx.x * 64, k0 = blockIdx.y * 64;
    const int col = tid & 63, r0 = tid >> 6;
    const float* src = (z == 0) ? Wq : (z == 1) ? Wk : (z == 2) ? Wv
                     : (z == 3) ? W1 : W2;
    #pragma unroll
    for (int i = 0; i < 16; i++) {
        const int row = r0 + i * 4;
        float v;
        if (z < 3)
            v = src[((size_t)(n0 >> 6) << 16) + (size_t)(k0 + row) * 64 + col];
        else
            v = src[(size_t)(k0 + row) * D_ + n0 + col];
        tile[row][col] = v;
    }
    __syncthreads();
    bf16_t* dst = (z < 3) ? (WtQKV + (size_t)z * D_ * D_)
                : (z == 3) ? Wt1 : Wt2;
    #pragma unroll
    for (int i = 0; i < 16; i++) {
        const int nr = r0 + i * 4;
        const int n = n0 + nr, k = k0 + col;
        const size_t pidx = ((size_t)(n >> 4) * (D_ >> 3) + (k >> 3)) * 128
                          + (size_t)(n & 15) * 8 + (k & 7);
        dst[pidx] = (bf16_t)tile[col][nr];
    }
}

// ---------------------------------------------------------------------------
// 128x128 bf16 MFMA GEMM: A via LDS dbuf (global_load_lds), B direct to
// registers from packed layout (no B LDS). R5-verified structure.
// R7: EPI==0 (QKV) writes n<2048 (Q,K) to C at stride NC=2048, and the V
// block columns (bn>=2048) TRANSPOSED into VT[(b*16+h)*64+d][tok] — the
// accumulator's 4 r-values are 4 consecutive tokens -> 8B bf16x4 stores.
// This lets attn stage V^T via global_load_lds (no in-kernel transpose).
// ---------------------------------------------------------------------------
template<int EPI, typename OUT>
__global__ __launch_bounds__(256, 2)
void gemm_bp(const bf16_t* __restrict__ A, const bf16_t* __restrict__ Bp,
             const float* __restrict__ bias, const int* __restrict__ lens,
             OUT* __restrict__ C, bf16_t* __restrict__ VTout,
             int M, int N, int NC, int K)
{
    __shared__ __align__(16) bf16_t As[2][128 * 64];

    const int tid  = threadIdx.x;
    const int lane = tid & 63;
    const int w    = tid >> 6;
    const int quad = lane >> 4, l16 = lane & 15;
    const int wm = w & 1, wn = w >> 1;
    const int sw8 = l16 & 7;

    const int nwg  = gridDim.x * gridDim.y;
    const int orig = blockIdx.y * gridDim.x + blockIdx.x;
    const int swz  = (orig & 7) * (nwg >> 3) + (orig >> 3);
    const int bn = (swz % gridDim.x) * 128;
    const int bm = (swz / gridDim.x) * 128;

    const int rS  = tid >> 3;
    const int cS  = ((tid & 7) ^ (rS & 7)) << 3;
    const int dOf = w * 1024;

    const size_t ntStride = (size_t)(K >> 3) * 128;
    const bf16_t* Bw = Bp + ((size_t)(bn >> 4) + (size_t)wn * 4) * ntStride
                          + (size_t)quad * 128 + (size_t)l16 * 8;

    f32x4 acc[4][4];
    #pragma unroll
    for (int i = 0; i < 4; i++)
        #pragma unroll
        for (int j = 0; j < 4; j++)
            #pragma unroll
            for (int r = 0; r < 4; r++) acc[i][j][r] = 0.f;

#define SA(b_, kt_) { \
    _Pragma("unroll") \
    for (int s_ = 0; s_ < 4; s_++) \
        gld16(A + (size_t)(bm + s_ * 32 + rS) * K + (kt_) * 64 + cS, \
              (char*)As[b_] + s_ * 4096 + dOf); }
#define LB(dst_, kt_) { \
    _Pragma("unroll") \
    for (int j_ = 0; j_ < 4; j_++) \
        _Pragma("unroll") \
        for (int kh_ = 0; kh_ < 2; kh_++) \
            dst_[j_][kh_] = *(const bf16x8*)(Bw + (size_t)j_ * ntStride \
                                             + ((kt_) * 8 + kh_ * 4) * 128); }
#define KSTEP(cb_, nb_, BC_, BX_, t_) { \
    const int ktn_ = ((t_) + 1 < NKT) ? (t_) + 1 : (t_); \
    SA(nb_, ktn_); \
    LB(BX_, ktn_); \
    __builtin_amdgcn_sched_barrier(0); \
    const bf16_t* Ac = As[cb_]; \
    _Pragma("unroll") \
    for (int kh_ = 0; kh_ < 2; kh_++) { \
        bf16x8 a_[4]; \
        _Pragma("unroll") \
        for (int i_ = 0; i_ < 4; i_++) \
            a_[i_] = *(const bf16x8*)&Ac[(wm * 64 + i_ * 16 + l16) * 64 \
                                         + (((kh_ * 4 + quad) ^ sw8) << 3)]; \
        _Pragma("unroll") \
        for (int i_ = 0; i_ < 4; i_++) \
            _Pragma("unroll") \
            for (int j_ = 0; j_ < 4; j_++) \
                acc[i_][j_] = __builtin_amdgcn_mfma_f32_16x16x32_bf16( \
                    a_[i_], BC_[j_][kh_], acc[i_][j_], 0, 0, 0); \
    } \
    __builtin_amdgcn_sched_barrier(0); \
    asm volatile("s_waitcnt vmcnt(8)" ::: "memory"); \
    __builtin_amdgcn_s_barrier(); }

    const int NKT = K >> 6;

    bf16x8 bA[4][2], bB[4][2];
    SA(0, 0);
    LB(bA, 0);
    asm volatile("s_waitcnt vmcnt(8)" ::: "memory");
    __builtin_amdgcn_s_barrier();

    for (int t = 0; t < NKT; t += 2) {
        KSTEP(0, 1, bA, bB, t);
        KSTEP(1, 0, bB, bA, t + 1);
    }

#undef SA
#undef LB
#undef KSTEP

    // ---- epilogue ----
    if (EPI == 0 && bn >= 2048) {
        // V block: transposed store into VT[(n-2048)][tok], 8B per (i,j).
        #pragma unroll
        for (int i = 0; i < 4; i++) {
            const int m0 = bm + wm * 64 + i * 16 + quad * 4;   // 4-aligned
            const int bb = m0 >> 10, s0 = m0 & 1023;
            #pragma unroll
            for (int j = 0; j < 4; j++) {
                const int n = bn + wn * 64 + j * 16 + l16;
                bf16x4v vv;
                #pragma unroll
                for (int r = 0; r < 4; r++) vv[r] = (bf16_t)acc[i][j][r];
                *(bf16x4v*)(VTout + ((size_t)bb * 1024 + (n - 2048)) * 1024 + s0) = vv;
            }
        }
        return;
    }
    #pragma unroll
    for (int i = 0; i < 4; i++) {
        #pragma unroll
        for (int r = 0; r < 4; r++) {
            const int m = bm + wm * 64 + i * 16 + quad * 4 + r;
            float keep = 1.f;
            if (EPI != 0) {
                const int s = m & (S_ - 1);
                const int bb = m >> 10;
                keep = (s < lens[bb]) ? 1.f : 0.f;
            }
            #pragma unroll
            for (int j = 0; j < 4; j++) {
                const int n = bn + wn * 64 + j * 16 + l16;
                float v = acc[i][j][r];
                if (EPI != 0) {
                    v += bias[n];
                    if (EPI == 1) v = fmaxf(v, 0.f);
                    v *= keep;
                }
                C[(size_t)m * NC + n] = (OUT)v;
            }
        }
    }
}

// ---------------------------------------------------------------------------
// bf16 MFMA flash attention, S^T formulation — R7: V^T staged via DMA.
//   R6 analysis: per-CU throughput-bound on LDS+VALU; the V transpose
//   scatter (8 scalar ds_write_b16/thread + 5.3M bank conflicts + flat
//   loads) was the largest removable consumer. V now arrives pre-transposed
//   from the QKV GEMM (VT[(b*16+h)*64+d][tok]) and is staged with
//   global_load_lds exactly like K (same chunk-XOR swizzle, one 512-thread
//   shot). LDS ops/wave-iter 30 -> 22, conflicts -> ~0.
//   Two barriers/iter: bar1 (__syncthreads: vmcnt drain, K/V(t+1) + Ps
//   visibility before PV), bar2 (raw s_barrier after PV so next-iter DMA
//   cannot overwrite Vs[cb] while a lagging wave still reads it).
//   LDS: Ks 2x8K + Vs 2x8K + Ps 18K = 51200 B -> 3 blocks/CU (24 waves).
// ---------------------------------------------------------------------------
__global__ __launch_bounds__(512, 6)
void attn_mfma(const bf16_t* __restrict__ QK, const bf16_t* __restrict__ VT,
               const int* __restrict__ lens, bf16_t* __restrict__ Z)
{
    __shared__ __align__(16) bf16_t Ks[2][64][64];   // [buf][key][d], chunk-swizzled
    __shared__ __align__(16) bf16_t Vs[2][64][64];   // [buf][d][tok], chunk-swizzled
    __shared__ __align__(16) bf16_t Ps[128][72];     // [q][key], wave-private rows

    const int tid  = threadIdx.x;
    const int lane = tid & 63;
    const int w    = tid >> 6;          // 0..7
    const int quad = lane >> 4;
    const int l16  = lane & 15;
    const int id   = blockIdx.x;        // 1024 blocks; 128-apart share (b,h) -> same XCD
    const int b    = id & 7;
    const int h    = (id >> 3) & 15;
    const int qt   = id >> 7;           // 0..7
    const int len  = lens[b];
    const int qbase = qt * 128;
    const bf16_t* Qp  = QK + (size_t)b * S_ * 2048 + (size_t)h * 64;
    const bf16_t* Kp  = Qp + 1024;
    const bf16_t* Vtp = VT + ((size_t)b * 16 + h) * 64 * 1024;  // [64 d][1024 tok]
    const size_t zbase = (size_t)b * S_ * D_ + (size_t)h * 64;

    if (qbase >= len) {   // fully masked query tile -> zeros (bf16)
        const int r = tid >> 2, c0 = (tid & 3) * 16;
        bf16_t* zp = Z + zbase + (size_t)(qbase + r) * D_ + c0;
        uint4 zz = {0u, 0u, 0u, 0u};
        *(uint4*)zp = zz;
        *(uint4*)(zp + 8) = zz;
        return;
    }

    // Q B-frags, fixed for the whole kernel: B[k=d=quad*8+j][n=q=l16]
    const int qrow = qbase + w * 16 + l16;
    const bf16x8 bq0 = *(const bf16x8*)(Qp + (size_t)qrow * 2048 + quad * 8);
    const bf16x8 bq1 = *(const bf16x8*)(Qp + (size_t)qrow * 2048 + 32 + quad * 8);

    // staging geometry (K and V^T alike): row sr = tid>>3 (0..63); source
    // chunk = (tid&7) ^ (sr&7); LDS linear dest (thread tid -> byte tid*16).
    const int sr = tid >> 3;
    const int sc = ((tid & 7) ^ (sr & 7)) << 3;

    f32x4 o[4];
    #pragma unroll
    for (int dm = 0; dm < 4; dm++)
        #pragma unroll
        for (int r = 0; r < 4; r++) o[dm][r] = 0.f;
    float l_q = 0.f;

    const int ntiles = (len + 63) >> 6;

    // ---- prologue: stage K(0), V^T(0) ----
    gld16(Kp  + (size_t)sr * 2048 + sc, (char*)&Ks[0][0][0] + w * 1024);
    gld16(Vtp + (size_t)sr * 1024 + sc, (char*)&Vs[0][0][0] + w * 1024);
    __syncthreads();

    for (int t = 0; t < ntiles; t++) {
        const int k0 = t * 64;
        const int cb = t & 1, nb = (t + 1) & 1;
        const int kn0 = (t + 1 < ntiles ? t + 1 : t) * 64;

        // ---- issue DMA prefetch for tile t+1 ----
        gld16(Kp  + (size_t)(kn0 + sr) * 2048 + sc, (char*)&Ks[nb][0][0] + w * 1024);
        gld16(Vtp + (size_t)sr * 1024 + kn0 + sc,   (char*)&Vs[nb][0][0] + w * 1024);
        __builtin_amdgcn_sched_barrier(0);

        // ---- S^T = K Q^T from Ks[cb], exp, stage P ----
        #pragma unroll
        for (int kt = 0; kt < 4; kt++) {
            const int r = kt * 16 + l16;           // r&7 == l16&7
            const bf16x8 ak0 = *(const bf16x8*)&Ks[cb][r][(quad ^ (l16 & 7)) << 3];
            const bf16x8 ak1 = *(const bf16x8*)&Ks[cb][r][((4 + quad) ^ (l16 & 7)) << 3];
            f32x4 z4 = {0.f, 0.f, 0.f, 0.f};
            z4 = __builtin_amdgcn_mfma_f32_16x16x32_bf16(ak0, bq0, z4, 0, 0, 0);
            const f32x4 sfv = __builtin_amdgcn_mfma_f32_16x16x32_bf16(ak1, bq1, z4, 0, 0, 0);
            bf16x4v pk;
            #pragma unroll
            for (int r2 = 0; r2 < 4; r2++) {
                const int key = k0 + kt * 16 + quad * 4 + r2;
                float p = __expf(sfv[r2] * 0.125f);
                p = (key < len) ? p : 0.f;
                l_q += p;
                pk[r2] = (bf16_t)p;
            }
            *(bf16x4v*)&Ps[w * 16 + l16][kt * 16 + quad * 4] = pk;
        }

        __syncthreads();   // bar1: K/V(t+1) DMA drained, Ps rows complete

        // ---- O^T += V^T P^T from Vs[cb] ----
        const bf16x8 bp0 = *(const bf16x8*)&Ps[w * 16 + l16][quad * 8];
        const bf16x8 bp1 = *(const bf16x8*)&Ps[w * 16 + l16][32 + quad * 8];
        #pragma unroll
        for (int dm = 0; dm < 4; dm++) {
            const int vr = dm * 16 + l16;          // vr&7 == l16&7
            const bf16x8 av0 = *(const bf16x8*)&Vs[cb][vr][(quad ^ (l16 & 7)) << 3];
            const bf16x8 av1 = *(const bf16x8*)&Vs[cb][vr][((4 + quad) ^ (l16 & 7)) << 3];
            o[dm] = __builtin_amdgcn_mfma_f32_16x16x32_bf16(av0, bp0, o[dm], 0, 0, 0);
            o[dm] = __builtin_amdgcn_mfma_f32_16x16x32_bf16(av1, bp1, o[dm], 0, 0, 0);
        }

        // bar2: all waves done reading Vs[cb]/Ks[cb] before next-iter DMA
        // re-targets buffer cb (nb(t+1) == cb(t)).
        __builtin_amdgcn_sched_barrier(0);
        __builtin_amdgcn_s_barrier();
        __builtin_amdgcn_sched_barrier(0);
    }

    // ---- final l reduce + epilogue ----
    l_q += __shfl_xor(l_q, 16);
    l_q += __shfl_xor(l_q, 32);
    const int qg = qbase + w * 16 + l16;
    const float inv = (qg < len) ? 1.f / l_q : 0.f;
    bf16_t* zrow = Z + zbase + (size_t)qg * D_;
    #pragma unroll
    for (int dm = 0; dm < 4; dm++) {
        bf16x4v st;
        #pragma unroll
        for (int r = 0; r < 4; r++) st[r] = (bf16_t)(o[dm][r] * inv);
        *(bf16x4v*)(zrow + dm * 16 + quad * 4) = st;
    }
}

// ---------------------------------------------------------------------------
// Residual-add + LayerNorm, D=1024, one block per row.
// ---------------------------------------------------------------------------
__device__ __forceinline__ void ln_core(float vx, float vy, float vz, float vw,
                                        int tid, float& mean, float& rstd)
{
    __shared__ float red[8];
    float s = vx + vy + vz + vw;
    #pragma unroll
    for (int off = 32; off; off >>= 1) s += __shfl_xor(s, off, 64);
    const int wv = tid >> 6, lane = tid & 63;
    if (lane == 0) red[wv] = s;
    __syncthreads();
    mean = (red[0] + red[1] + red[2] + red[3]) * (1.f / D_);
    const float dx = vx - mean, dy = vy - mean, dz = vz - mean, dw = vw - mean;
    float s2 = dx * dx + dy * dy + dz * dz + dw * dw;
    #pragma unroll
    for (int off = 32; off; off >>= 1) s2 += __shfl_xor(s2, off, 64);
    if (lane == 0) red[4 + wv] = s2;
    __syncthreads();
    rstd = rsqrtf((red[4] + red[5] + red[6] + red[7]) * (1.f / D_) + EPS_);
}

__global__ __launch_bounds__(256)
void add_ln1(const float* __restrict__ X, const bf16_t* __restrict__ Y,
             const float* __restrict__ g, const float* __restrict__ beta,
             bf16_t* __restrict__ out)
{
    const int row = blockIdx.x, tid = threadIdx.x;
    const float4 xv = ((const float4*)(X + (size_t)row * D_))[tid];
    const bf16x4v yv = *(const bf16x4v*)(Y + (size_t)row * D_ + tid * 4);
    const float vx = xv.x + (float)yv[0], vy = xv.y + (float)yv[1];
    const float vz = xv.z + (float)yv[2], vw = xv.w + (float)yv[3];
    float mean, rstd;
    ln_core(vx, vy, vz, vw, tid, mean, rstd);
    const float4 gv = ((const float4*)g)[tid];
    const float4 bv = ((const float4*)beta)[tid];
    bf16x4v o;
    o[0] = (bf16_t)((vx - mean) * rstd * gv.x + bv.x);
    o[1] = (bf16_t)((vy - mean) * rstd * gv.y + bv.y);
    o[2] = (bf16_t)((vz - mean) * rstd * gv.z + bv.z);
    o[3] = (bf16_t)((vw - mean) * rstd * gv.w + bv.w);
    *(bf16x4v*)(out + (size_t)row * D_ + tid * 4) = o;
}

__global__ __launch_bounds__(256)
void add_ln2(const bf16_t* __restrict__ X, const float* __restrict__ Y,
             const float* __restrict__ g, const float* __restrict__ beta,
             float* __restrict__ out)
{
    const int row = blockIdx.x, tid = threadIdx.x;
    const bf16x4v xv = *(const bf16x4v*)(X + (size_t)row * D_ + tid * 4);
    const float4 yv = ((const float4*)(Y + (size_t)row * D_))[tid];
    const float vx = (float)xv[0] + yv.x, vy = (float)xv[1] + yv.y;
    const float vz = (float)xv[2] + yv.z, vw = (float)xv[3] + yv.w;
    float mean, rstd;
    ln_core(vx, vy, vz, vw, tid, mean, rstd);
    const float4 gv = ((const float4*)g)[tid];
    const float4 bv = ((const float4*)beta)[tid];
    float4 o;
    o.x = (vx - mean) * rstd * gv.x + bv.x;
    o.y = (vy - mean) * rstd * gv.y + bv.y;
    o.z = (vz - mean) * rstd * gv.z + bv.z;
    o.w = (vw - mean) * rstd * gv.w + bv.w;
    ((float4*)(out + (size_t)row * D_))[tid] = o;
}

// ---------------------------------------------------------------------------
extern "C" void kernel_launch(void* const* d_in, const int* in_sizes, int n_in,
                              void* d_out, int out_size, void* d_ws, size_t ws_size,
                              hipStream_t stream)
{
    const float* x    = (const float*)d_in[0];
    const float* Wq   = (const float*)d_in[1];
    const float* Wk   = (const float*)d_in[2];
    const float* Wv   = (const float*)d_in[3];
    const float* fc1w = (const float*)d_in[4];
    const float* fc1b = (const float*)d_in[5];
    const float* fc2w = (const float*)d_in[6];
    const float* fc2b = (const float*)d_in[7];
    const float* ln1w = (const float*)d_in[8];
    const float* ln1b = (const float*)d_in[9];
    const float* ln2w = (const float*)d_in[10];
    const float* ln2b = (const float*)d_in[11];
    const int*   lens = (const int*)d_in[12];
    float* out = (float*)d_out;

    char* ws = (char*)d_ws;
    const size_t MB = 1024 * 1024;
    bf16_t* QKb   = (bf16_t*)(ws);              // 32 MB: [8192][2048] (Q,K)
    bf16_t* VTb   = (bf16_t*)(ws + 32 * MB);    // 16 MB: [8*16*64][1024] (V^T)
    bf16_t* Zb    = (bf16_t*)(ws + 48 * MB);    // 16 MB: [8192][1024] bf16
    bf16_t* X1b   = (bf16_t*)(ws + 80 * MB);    // 16 MB
    bf16_t* xb    = (bf16_t*)(ws + 96 * MB);    // 16 MB (dead after QKV)
    bf16_t* H1b   = (bf16_t*)(ws + 96 * MB);    //   reuses xb slot
    float*  FF    = (float*)(ws + 48 * MB);     //   reuses Zb slot (32 MB)
    bf16_t* WtQKV = (bf16_t*)(ws + 112 * MB);   // 6 MB (packed)
    bf16_t* Wt1   = (bf16_t*)(ws + 118 * MB);   // 2 MB (packed)
    bf16_t* Wt2   = (bf16_t*)(ws + 120 * MB);   // 2 MB (packed)

    const int M = B_ * S_;

    prep<<<dim3(16, 16, 37), 256, 0, stream>>>(x, Wq, Wk, Wv, fc1w, fc2w,
                                               xb, WtQKV, Wt1, Wt2);

    gemm_bp<0, bf16_t><<<dim3(3072 / 128, M / 128), 256, 0, stream>>>(
        xb, WtQKV, nullptr, nullptr, QKb, VTb, M, 3072, 2048, D_);

    attn_mfma<<<dim3(1024), 512, 0, stream>>>(QKb, VTb, lens, Zb);

    add_ln1<<<M, 256, 0, stream>>>(x, Zb, ln1w, ln1b, X1b);

    gemm_bp<1, bf16_t><<<dim3(D_ / 128, M / 128), 256, 0, stream>>>(
        X1b, Wt1, fc1b, lens, H1b, nullptr, M, D_, D_, D_);
    gemm_bp<2, float><<<dim3(D_ / 128, M / 128), 256, 0, stream>>>(
        H1b, Wt2, fc2b, lens, FF, nullptr, M, D_, D_, D_);

    add_ln2<<<M, 256, 0, stream>>>(X1b, FF, ln2w, ln2b, out);
}

// Round 9
// 303.860 us; speedup vs baseline: 1.1444x; 1.0016x over previous
//
#include <hip/hip_runtime.h>
#include <math.h>

#define B_ 8
#define S_ 1024
#define D_ 1024
#define H_ 16
#define DK_ 64
#define EPS_ 1e-5f

typedef __bf16 bf16_t;
typedef __bf16 bf16x8 __attribute__((ext_vector_type(8)));
typedef __bf16 bf16x4v __attribute__((ext_vector_type(4)));
typedef float  f32x4  __attribute__((ext_vector_type(4)));

__device__ __forceinline__ void gld16(const void* g, void* l) {
    __builtin_amdgcn_global_load_lds(
        (const __attribute__((address_space(1))) void*)g,
        (__attribute__((address_space(3))) void*)l, 16, 0, 0);
}

// ---------------------------------------------------------------------------
// prep: weight transpose+convert+PACK (z=0..4) and x f32->bf16 (z=5..36).
// B-pack layout: elem(n,k) -> [n>>4][k>>3][n&15][k&7]; a wave's MFMA B-frag
// (16 n x 8 k) is 1 KB contiguous -> one coalesced b128 load, no B LDS.
// ---------------------------------------------------------------------------
__global__ __launch_bounds__(256)
void prep(const float* __restrict__ x,
          const float* __restrict__ Wq, const float* __restrict__ Wk,
          const float* __restrict__ Wv, const float* __restrict__ W1,
          const float* __restrict__ W2, bf16_t* __restrict__ xb,
          bf16_t* __restrict__ WtQKV, bf16_t* __restrict__ Wt1,
          bf16_t* __restrict__ Wt2)
{
    __shared__ float tile[64][65];
    const int tid = threadIdx.x;
    const int z = blockIdx.z;

    if (z >= 5) {   // x convert
        const int blk = (z - 5) * 256 + blockIdx.y * 16 + blockIdx.x;
        const int i = (blk * 256 + tid) * 4;
        const float4 v = *(const float4*)(x + i);
        bf16x4v o = { (bf16_t)v.x, (bf16_t)v.y, (bf16_t)v.z, (bf16_t)v.w };
        *(bf16x4v*)(xb + i) = o;
        return;
    }

    const int n0 = blockIdx.x * 64, k0 = blockIdx.y * 64;
    const int col = tid & 63, r0 = tid >> 6;
    const float* src = (z == 0) ? Wq : (z == 1) ? Wk : (z == 2) ? Wv
                     : (z == 3) ? W1 : W2;
    #pragma unroll
    for (int i = 0; i < 16; i++) {
        const int row = r0 + i * 4;
        float v;
        if (z < 3)
            v = src[((size_t)(n0 >> 6) << 16) + (size_t)(k0 + row) * 64 + col];
        else
            v = src[(size_t)(k0 + row) * D_ + n0 + col];
        tile[row][col] = v;
    }
    __syncthreads();
    bf16_t* dst = (z < 3) ? (WtQKV + (size_t)z * D_ * D_)
                : (z == 3) ? Wt1 : Wt2;
    #pragma unroll
    for (int i = 0; i < 16; i++) {
        const int nr = r0 + i * 4;
        const int n = n0 + nr, k = k0 + col;
        const size_t pidx = ((size_t)(n >> 4) * (D_ >> 3) + (k >> 3)) * 128
                          + (size_t)(n & 15) * 8 + (k & 7);
        dst[pidx] = (bf16_t)tile[col][nr];
    }
}

// ---------------------------------------------------------------------------
// 128x128 bf16 MFMA GEMM: A via LDS (global_load_lds), B direct to registers
// from packed layout. R8: A pipeline deepened to 2 tiles (3-buffer rotation).
//   R7 ledger audit: SA(t+1) was issued at the top of iter t and awaited by
//   vmcnt(8) at the bottom of the SAME iter -> only ~300 cyc to cover
//   200-900 cyc DMA latency; per-K-tile stall pinned MfmaUtil at 32%.
//   Now iter t stages A(t+2) into buf (t+2)%3 and computes buf t%3; the
//   end-of-iter vmcnt(12) (A(t+2)x4 + B(t+1)x8 in flight) only VERIFIES
//   A(t+1), issued a full iteration earlier. The compiler's mid-iter wait
//   on B(t) (older queue entries) drains A(t+1) for free. Never vmcnt(0).
//   Race: buf (t+2)%3 holds A(t-1), last read in iter t-1, sealed by that
//   iter's end barrier. LDS 48 KB -> 3 blocks/CU (12 waves, launch 256,3).
//   EPI==0 (QKV): n<2048 (Q,K) -> C stride NC; V cols (bn>=2048) stored
//   TRANSPOSED into VT[(b*16+h)*64+d][tok] (acc r-values = 4 consecutive
//   tokens -> 8B stores) so attn can DMA-stage V^T like K.
// ---------------------------------------------------------------------------
template<int EPI, typename OUT>
__global__ __launch_bounds__(256, 3)
void gemm_bp(const bf16_t* __restrict__ A, const bf16_t* __restrict__ Bp,
             const float* __restrict__ bias, const int* __restrict__ lens,
             OUT* __restrict__ C, bf16_t* __restrict__ VTout,
             int M, int N, int NC, int K)
{
    __shared__ __align__(16) bf16_t As[3][128 * 64];

    const int tid  = threadIdx.x;
    const int lane = tid & 63;
    const int w    = tid >> 6;
    const int quad = lane >> 4, l16 = lane & 15;
    const int wm = w & 1, wn = w >> 1;
    const int sw8 = l16 & 7;

    const int nwg  = gridDim.x * gridDim.y;
    const int orig = blockIdx.y * gridDim.x + blockIdx.x;
    const int swz  = (orig & 7) * (nwg >> 3) + (orig >> 3);
    const int bn = (swz % gridDim.x) * 128;
    const int bm = (swz / gridDim.x) * 128;

    const int rS  = tid >> 3;
    const int cS  = ((tid & 7) ^ (rS & 7)) << 3;
    const int dOf = w * 1024;

    const size_t ntStride = (size_t)(K >> 3) * 128;
    const bf16_t* Bw = Bp + ((size_t)(bn >> 4) + (size_t)wn * 4) * ntStride
                          + (size_t)quad * 128 + (size_t)l16 * 8;

    f32x4 acc[4][4];
    #pragma unroll
    for (int i = 0; i < 4; i++)
        #pragma unroll
        for (int j = 0; j < 4; j++)
            #pragma unroll
            for (int r = 0; r < 4; r++) acc[i][j][r] = 0.f;

#define SA(b_, kt_) { \
    _Pragma("unroll") \
    for (int s_ = 0; s_ < 4; s_++) \
        gld16(A + (size_t)(bm + s_ * 32 + rS) * K + (kt_) * 64 + cS, \
              (char*)As[b_] + s_ * 4096 + dOf); }
#define LB(dst_, kt_) { \
    _Pragma("unroll") \
    for (int j_ = 0; j_ < 4; j_++) \
        _Pragma("unroll") \
        for (int kh_ = 0; kh_ < 2; kh_++) \
            dst_[j_][kh_] = *(const bf16x8*)(Bw + (size_t)j_ * ntStride \
                                             + ((kt_) * 8 + kh_ * 4) * 128); }
#define KSTEP(cb_, sb_, BC_, BX_, t_) { \
    const int ktn_ = ((t_) + 1 < NKT) ? (t_) + 1 : NKT - 1; \
    const int kt2_ = ((t_) + 2 < NKT) ? (t_) + 2 : NKT - 1; \
    SA(sb_, kt2_); \
    LB(BX_, ktn_); \
    __builtin_amdgcn_sched_barrier(0); \
    const bf16_t* Ac = As[cb_]; \
    _Pragma("unroll") \
    for (int kh_ = 0; kh_ < 2; kh_++) { \
        bf16x8 a_[4]; \
        _Pragma("unroll") \
        for (int i_ = 0; i_ < 4; i_++) \
            a_[i_] = *(const bf16x8*)&Ac[(wm * 64 + i_ * 16 + l16) * 64 \
                                         + (((kh_ * 4 + quad) ^ sw8) << 3)]; \
        _Pragma("unroll") \
        for (int i_ = 0; i_ < 4; i_++) \
            _Pragma("unroll") \
            for (int j_ = 0; j_ < 4; j_++) \
                acc[i_][j_] = __builtin_amdgcn_mfma_f32_16x16x32_bf16( \
                    a_[i_], BC_[j_][kh_], acc[i_][j_], 0, 0, 0); \
    } \
    __builtin_amdgcn_sched_barrier(0); \
    asm volatile("s_waitcnt vmcnt(12)" ::: "memory"); \
    __builtin_amdgcn_s_barrier(); }

    const int NKT = K >> 6;   // 16 here (even; unroll-2 loop)

    bf16x8 bA[4][2], bB[4][2];
    SA(0, 0);                  // A(0) -> buf 0
    SA(1, 1);                  // A(1) -> buf 1
    LB(bA, 0);                 // B(0) -> regs
    asm volatile("s_waitcnt vmcnt(12)" ::: "memory");   // A(0) landed
    __builtin_amdgcn_s_barrier();

    int cb = 0;
    for (int t = 0; t < NKT; t += 2) {
        const int sb0 = cb ? cb - 1 : 2;          // (cb+2)%3
        KSTEP(cb, sb0, bA, bB, t);
        const int cb1 = (cb + 1 == 3) ? 0 : cb + 1;
        const int sb1 = cb1 ? cb1 - 1 : 2;
        KSTEP(cb1, sb1, bB, bA, t + 1);
        cb = (cb1 + 1 == 3) ? 0 : cb1 + 1;
    }

#undef SA
#undef LB
#undef KSTEP

    // ---- epilogue ----
    if (EPI == 0 && bn >= 2048) {
        // V block: transposed store into VT[(n-2048)][tok], 8B per (i,j).
        #pragma unroll
        for (int i = 0; i < 4; i++) {
            const int m0 = bm + wm * 64 + i * 16 + quad * 4;   // 4-aligned
            const int bb = m0 >> 10, s0 = m0 & 1023;
            #pragma unroll
            for (int j = 0; j < 4; j++) {
                const int n = bn + wn * 64 + j * 16 + l16;
                bf16x4v vv;
                #pragma unroll
                for (int r = 0; r < 4; r++) vv[r] = (bf16_t)acc[i][j][r];
                *(bf16x4v*)(VTout + ((size_t)bb * 1024 + (n - 2048)) * 1024 + s0) = vv;
            }
        }
        return;
    }
    #pragma unroll
    for (int i = 0; i < 4; i++) {
        #pragma unroll
        for (int r = 0; r < 4; r++) {
            const int m = bm + wm * 64 + i * 16 + quad * 4 + r;
            float keep = 1.f;
            if (EPI != 0) {
                const int s = m & (S_ - 1);
                const int bb = m >> 10;
                keep = (s < lens[bb]) ? 1.f : 0.f;
            }
            #pragma unroll
            for (int j = 0; j < 4; j++) {
                const int n = bn + wn * 64 + j * 16 + l16;
                float v = acc[i][j][r];
                if (EPI != 0) {
                    v += bias[n];
                    if (EPI == 1) v = fmaxf(v, 0.f);
                    v *= keep;
                }
                C[(size_t)m * NC + n] = (OUT)v;
            }
        }
    }
}

// ---------------------------------------------------------------------------
// bf16 MFMA flash attention, S^T formulation — R7 structure: V^T staged via
// DMA (pre-transposed by the QKV GEMM), K and V^T staged identically with
// chunk-XOR swizzle; no in-kernel transpose, conflicts ~0.
// ---------------------------------------------------------------------------
__global__ __launch_bounds__(512, 6)
void attn_mfma(const bf16_t* __restrict__ QK, const bf16_t* __restrict__ VT,
               const int* __restrict__ lens, bf16_t* __restrict__ Z)
{
    __shared__ __align__(16) bf16_t Ks[2][64][64];   // [buf][key][d], chunk-swizzled
    __shared__ __align__(16) bf16_t Vs[2][64][64];   // [buf][d][tok], chunk-swizzled
    __shared__ __align__(16) bf16_t Ps[128][72];     // [q][key], wave-private rows

    const int tid  = threadIdx.x;
    const int lane = tid & 63;
    const int w    = tid >> 6;          // 0..7
    const int quad = lane >> 4;
    const int l16  = lane & 15;
    const int id   = blockIdx.x;
    const int b    = id & 7;
    const int h    = (id >> 3) & 15;
    const int qt   = id >> 7;           // 0..7
    const int len  = lens[b];
    const int qbase = qt * 128;
    const bf16_t* Qp  = QK + (size_t)b * S_ * 2048 + (size_t)h * 64;
    const bf16_t* Kp  = Qp + 1024;
    const bf16_t* Vtp = VT + ((size_t)b * 16 + h) * 64 * 1024;  // [64 d][1024 tok]
    const size_t zbase = (size_t)b * S_ * D_ + (size_t)h * 64;

    if (qbase >= len) {   // fully masked query tile -> zeros (bf16)
        const int r = tid >> 2, c0 = (tid & 3) * 16;
        bf16_t* zp = Z + zbase + (size_t)(qbase + r) * D_ + c0;
        uint4 zz = {0u, 0u, 0u, 0u};
        *(uint4*)zp = zz;
        *(uint4*)(zp + 8) = zz;
        return;
    }

    // Q B-frags, fixed for the whole kernel: B[k=d=quad*8+j][n=q=l16]
    const int qrow = qbase + w * 16 + l16;
    const bf16x8 bq0 = *(const bf16x8*)(Qp + (size_t)qrow * 2048 + quad * 8);
    const bf16x8 bq1 = *(const bf16x8*)(Qp + (size_t)qrow * 2048 + 32 + quad * 8);

    // staging geometry (K and V^T alike): row sr = tid>>3 (0..63); source
    // chunk = (tid&7) ^ (sr&7); LDS linear dest (thread tid -> byte tid*16).
    const int sr = tid >> 3;
    const int sc = ((tid & 7) ^ (sr & 7)) << 3;

    f32x4 o[4];
    #pragma unroll
    for (int dm = 0; dm < 4; dm++)
        #pragma unroll
        for (int r = 0; r < 4; r++) o[dm][r] = 0.f;
    float l_q = 0.f;

    const int ntiles = (len + 63) >> 6;

    // ---- prologue: stage K(0), V^T(0) ----
    gld16(Kp  + (size_t)sr * 2048 + sc, (char*)&Ks[0][0][0] + w * 1024);
    gld16(Vtp + (size_t)sr * 1024 + sc, (char*)&Vs[0][0][0] + w * 1024);
    __syncthreads();

    for (int t = 0; t < ntiles; t++) {
        const int k0 = t * 64;
        const int cb = t & 1, nb = (t + 1) & 1;
        const int kn0 = (t + 1 < ntiles ? t + 1 : t) * 64;

        // ---- issue DMA prefetch for tile t+1 ----
        gld16(Kp  + (size_t)(kn0 + sr) * 2048 + sc, (char*)&Ks[nb][0][0] + w * 1024);
        gld16(Vtp + (size_t)sr * 1024 + kn0 + sc,   (char*)&Vs[nb][0][0] + w * 1024);
        __builtin_amdgcn_sched_barrier(0);

        // ---- S^T = K Q^T from Ks[cb], exp, stage P ----
        #pragma unroll
        for (int kt = 0; kt < 4; kt++) {
            const int r = kt * 16 + l16;           // r&7 == l16&7
            const bf16x8 ak0 = *(const bf16x8*)&Ks[cb][r][(quad ^ (l16 & 7)) << 3];
            const bf16x8 ak1 = *(const bf16x8*)&Ks[cb][r][((4 + quad) ^ (l16 & 7)) << 3];
            f32x4 z4 = {0.f, 0.f, 0.f, 0.f};
            z4 = __builtin_amdgcn_mfma_f32_16x16x32_bf16(ak0, bq0, z4, 0, 0, 0);
            const f32x4 sfv = __builtin_amdgcn_mfma_f32_16x16x32_bf16(ak1, bq1, z4, 0, 0, 0);
            bf16x4v pk;
            #pragma unroll
            for (int r2 = 0; r2 < 4; r2++) {
                const int key = k0 + kt * 16 + quad * 4 + r2;
                float p = __expf(sfv[r2] * 0.125f);
                p = (key < len) ? p : 0.f;
                l_q += p;
                pk[r2] = (bf16_t)p;
            }
            *(bf16x4v*)&Ps[w * 16 + l16][kt * 16 + quad * 4] = pk;
        }

        __syncthreads();   // bar1: K/V(t+1) DMA drained, Ps rows complete

        // ---- O^T += V^T P^T from Vs[cb] ----
        const bf16x8 bp0 = *(const bf16x8*)&Ps[w * 16 + l16][quad * 8];
        const bf16x8 bp1 = *(const bf16x8*)&Ps[w * 16 + l16][32 + quad * 8];
        #pragma unroll
        for (int dm = 0; dm < 4; dm++) {
            const int vr = dm * 16 + l16;          // vr&7 == l16&7
            const bf16x8 av0 = *(const bf16x8*)&Vs[cb][vr][(quad ^ (l16 & 7)) << 3];
            const bf16x8 av1 = *(const bf16x8*)&Vs[cb][vr][((4 + quad) ^ (l16 & 7)) << 3];
            o[dm] = __builtin_amdgcn_mfma_f32_16x16x32_bf16(av0, bp0, o[dm], 0, 0, 0);
            o[dm] = __builtin_amdgcn_mfma_f32_16x16x32_bf16(av1, bp1, o[dm], 0, 0, 0);
        }

        // bar2: all waves done reading Vs[cb]/Ks[cb] before next-iter DMA
        // re-targets buffer cb.
        __builtin_amdgcn_sched_barrier(0);
        __builtin_amdgcn_s_barrier();
        __builtin_amdgcn_sched_barrier(0);
    }

    // ---- final l reduce + epilogue ----
    l_q += __shfl_xor(l_q, 16);
    l_q += __shfl_xor(l_q, 32);
    const int qg = qbase + w * 16 + l16;
    const float inv = (qg < len) ? 1.f / l_q : 0.f;
    bf16_t* zrow = Z + zbase + (size_t)qg * D_;
    #pragma unroll
    for (int dm = 0; dm < 4; dm++) {
        bf16x4v st;
        #pragma unroll
        for (int r = 0; r < 4; r++) st[r] = (bf16_t)(o[dm][r] * inv);
        *(bf16x4v*)(zrow + dm * 16 + quad * 4) = st;
    }
}

// ---------------------------------------------------------------------------
// Residual-add + LayerNorm, D=1024, one block per row.
// ---------------------------------------------------------------------------
__device__ __forceinline__ void ln_core(float vx, float vy, float vz, float vw,
                                        int tid, float& mean, float& rstd)
{
    __shared__ float red[8];
    float s = vx + vy + vz + vw;
    #pragma unroll
    for (int off = 32; off; off >>= 1) s += __shfl_xor(s, off, 64);
    const int wv = tid >> 6, lane = tid & 63;
    if (lane == 0) red[wv] = s;
    __syncthreads();
    mean = (red[0] + red[1] + red[2] + red[3]) * (1.f / D_);
    const float dx = vx - mean, dy = vy - mean, dz = vz - mean, dw = vw - mean;
    float s2 = dx * dx + dy * dy + dz * dz + dw * dw;
    #pragma unroll
    for (int off = 32; off; off >>= 1) s2 += __shfl_xor(s2, off, 64);
    if (lane == 0) red[4 + wv] = s2;
    __syncthreads();
    rstd = rsqrtf((red[4] + red[5] + red[6] + red[7]) * (1.f / D_) + EPS_);
}

__global__ __launch_bounds__(256)
void add_ln1(const float* __restrict__ X, const bf16_t* __restrict__ Y,
             const float* __restrict__ g, const float* __restrict__ beta,
             bf16_t* __restrict__ out)
{
    const int row = blockIdx.x, tid = threadIdx.x;
    const float4 xv = ((const float4*)(X + (size_t)row * D_))[tid];
    const bf16x4v yv = *(const bf16x4v*)(Y + (size_t)row * D_ + tid * 4);
    const float vx = xv.x + (float)yv[0], vy = xv.y + (float)yv[1];
    const float vz = xv.z + (float)yv[2], vw = xv.w + (float)yv[3];
    float mean, rstd;
    ln_core(vx, vy, vz, vw, tid, mean, rstd);
    const float4 gv = ((const float4*)g)[tid];
    const float4 bv = ((const float4*)beta)[tid];
    bf16x4v o;
    o[0] = (bf16_t)((vx - mean) * rstd * gv.x + bv.x);
    o[1] = (bf16_t)((vy - mean) * rstd * gv.y + bv.y);
    o[2] = (bf16_t)((vz - mean) * rstd * gv.z + bv.z);
    o[3] = (bf16_t)((vw - mean) * rstd * gv.w + bv.w);
    *(bf16x4v*)(out + (size_t)row * D_ + tid * 4) = o;
}

__global__ __launch_bounds__(256)
void add_ln2(const bf16_t* __restrict__ X, const float* __restrict__ Y,
             const float* __restrict__ g, const float* __restrict__ beta,
             float* __restrict__ out)
{
    const int row = blockIdx.x, tid = threadIdx.x;
    const bf16x4v xv = *(const bf16x4v*)(X + (size_t)row * D_ + tid * 4);
    const float4 yv = ((const float4*)(Y + (size_t)row * D_))[tid];
    const float vx = (float)xv[0] + yv.x, vy = (float)xv[1] + yv.y;
    const float vz = (float)xv[2] + yv.z, vw = (float)xv[3] + yv.w;
    float mean, rstd;
    ln_core(vx, vy, vz, vw, tid, mean, rstd);
    const float4 gv = ((const float4*)g)[tid];
    const float4 bv = ((const float4*)beta)[tid];
    float4 o;
    o.x = (vx - mean) * rstd * gv.x + bv.x;
    o.y = (vy - mean) * rstd * gv.y + bv.y;
    o.z = (vz - mean) * rstd * gv.z + bv.z;
    o.w = (vw - mean) * rstd * gv.w + bv.w;
    ((float4*)(out + (size_t)row * D_))[tid] = o;
}

// ---------------------------------------------------------------------------
extern "C" void kernel_launch(void* const* d_in, const int* in_sizes, int n_in,
                              void* d_out, int out_size, void* d_ws, size_t ws_size,
                              hipStream_t stream)
{
    const float* x    = (const float*)d_in[0];
    const float* Wq   = (const float*)d_in[1];
    const float* Wk   = (const float*)d_in[2];
    const float* Wv   = (const float*)d_in[3];
    const float* fc1w = (const float*)d_in[4];
    const float* fc1b = (const float*)d_in[5];
    const float* fc2w = (const float*)d_in[6];
    const float* fc2b = (const float*)d_in[7];
    const float* ln1w = (const float*)d_in[8];
    const float* ln1b = (const float*)d_in[9];
    const float* ln2w = (const float*)d_in[10];
    const float* ln2b = (const float*)d_in[11];
    const int*   lens = (const int*)d_in[12];
    float* out = (float*)d_out;

    char* ws = (char*)d_ws;
    const size_t MB = 1024 * 1024;
    bf16_t* QKb   = (bf16_t*)(ws);              // 32 MB: [8192][2048] (Q,K)
    bf16_t* VTb   = (bf16_t*)(ws + 32 * MB);    // 16 MB: [8*16*64][1024] (V^T)
    bf16_t* Zb    = (bf16_t*)(ws + 48 * MB);    // 16 MB: [8192][1024] bf16
    bf16_t* X1b   = (bf16_t*)(ws + 80 * MB);    // 16 MB
    bf16_t* xb    = (bf16_t*)(ws + 96 * MB);    // 16 MB (dead after QKV)
    bf16_t* H1b   = (bf16_t*)(ws + 96 * MB);    //   reuses xb slot
    float*  FF    = (float*)(ws + 48 * MB);     //   reuses Zb slot (32 MB)
    bf16_t* WtQKV = (bf16_t*)(ws + 112 * MB);   // 6 MB (packed)
    bf16_t* Wt1   = (bf16_t*)(ws + 118 * MB);   // 2 MB (packed)
    bf16_t* Wt2   = (bf16_t*)(ws + 120 * MB);   // 2 MB (packed)

    const int M = B_ * S_;

    prep<<<dim3(16, 16, 37), 256, 0, stream>>>(x, Wq, Wk, Wv, fc1w, fc2w,
                                               xb, WtQKV, Wt1, Wt2);

    gemm_bp<0, bf16_t><<<dim3(3072 / 128, M / 128), 256, 0, stream>>>(
        xb, WtQKV, nullptr, nullptr, QKb, VTb, M, 3072, 2048, D_);

    attn_mfma<<<dim3(1024), 512, 0, stream>>>(QKb, VTb, lens, Zb);

    add_ln1<<<M, 256, 0, stream>>>(x, Zb, ln1w, ln1b, X1b);

    gemm_bp<1, bf16_t><<<dim3(D_ / 128, M / 128), 256, 0, stream>>>(
        X1b, Wt1, fc1b, lens, H1b, nullptr, M, D_, D_, D_);
    gemm_bp<2, float><<<dim3(D_ / 128, M / 128), 256, 0, stream>>>(
        H1b, Wt2, fc2b, lens, FF, nullptr, M, D_, D_, D_);

    add_ln2<<<M, 256, 0, stream>>>(X1b, FF, ln2w, ln2b, out);
}

// Round 10
// 294.191 us; speedup vs baseline: 1.1820x; 1.0329x over previous
//
#include <hip/hip_runtime.h>
#include <math.h>

#define B_ 8
#define S_ 1024
#define D_ 1024
#define H_ 16
#define DK_ 64
#define EPS_ 1e-5f

typedef __bf16 bf16_t;
typedef __bf16 bf16x8 __attribute__((ext_vector_type(8)));
typedef __bf16 bf16x4v __attribute__((ext_vector_type(4)));
typedef float  f32x4  __attribute__((ext_vector_type(4)));

__device__ __forceinline__ void gld16(const void* g, void* l) {
    __builtin_amdgcn_global_load_lds(
        (const __attribute__((address_space(1))) void*)g,
        (__attribute__((address_space(3))) void*)l, 16, 0, 0);
}

// ---------------------------------------------------------------------------
// prep: weight transpose+convert+PACK (z=0..4) and x f32->bf16 (z=5..36).
// B-pack layout: elem(n,k) -> [n>>4][k>>3][n&15][k&7]; a wave's MFMA B-frag
// (16 n x 8 k) is 1 KB contiguous -> one coalesced b128 load, no B LDS.
// R9: packed store vectorized — each (n, k-chunk) unit is 16B contiguous in
// the pack layout, so 2 x bf16x8 stores/thread replace 16 scalar 2B stores.
// ---------------------------------------------------------------------------
__global__ __launch_bounds__(256)
void prep(const float* __restrict__ x,
          const float* __restrict__ Wq, const float* __restrict__ Wk,
          const float* __restrict__ Wv, const float* __restrict__ W1,
          const float* __restrict__ W2, bf16_t* __restrict__ xb,
          bf16_t* __restrict__ WtQKV, bf16_t* __restrict__ Wt1,
          bf16_t* __restrict__ Wt2)
{
    __shared__ float tile[64][65];
    const int tid = threadIdx.x;
    const int z = blockIdx.z;

    if (z >= 5) {   // x convert
        const int blk = (z - 5) * 256 + blockIdx.y * 16 + blockIdx.x;
        const int i = (blk * 256 + tid) * 4;
        const float4 v = *(const float4*)(x + i);
        bf16x4v o = { (bf16_t)v.x, (bf16_t)v.y, (bf16_t)v.z, (bf16_t)v.w };
        *(bf16x4v*)(xb + i) = o;
        return;
    }

    const int n0 = blockIdx.x * 64, k0 = blockIdx.y * 64;
    const int col = tid & 63, r0 = tid >> 6;
    const float* src = (z == 0) ? Wq : (z == 1) ? Wk : (z == 2) ? Wv
                     : (z == 3) ? W1 : W2;
    #pragma unroll
    for (int i = 0; i < 16; i++) {
        const int row = r0 + i * 4;
        float v;
        if (z < 3)
            v = src[((size_t)(n0 >> 6) << 16) + (size_t)(k0 + row) * 64 + col];
        else
            v = src[(size_t)(k0 + row) * D_ + n0 + col];
        tile[row][col] = v;   // tile[a][b] = elem(k = k0+a, n = n0+b)
    }
    __syncthreads();
    bf16_t* dst = (z < 3) ? (WtQKV + (size_t)z * D_ * D_)
                : (z == 3) ? Wt1 : Wt2;
    // vectorized packed store: unit u = (n-row nr, k-chunk c); 16B contiguous.
    #pragma unroll
    for (int uu = 0; uu < 2; uu++) {
        const int u = uu * 256 + tid;
        const int nr = u >> 3, c = u & 7;
        const int n = n0 + nr, kk = k0 + c * 8;
        bf16x8 pkv;
        #pragma unroll
        for (int e = 0; e < 8; e++) pkv[e] = (bf16_t)tile[c * 8 + e][nr];
        *(bf16x8*)(dst + ((size_t)(n >> 4) * (D_ >> 3) + (kk >> 3)) * 128
                   + (size_t)(n & 15) * 8) = pkv;
    }
}

// ---------------------------------------------------------------------------
// 128x128 bf16 MFMA GEMM: A via LDS (3-buffer rotation, global_load_lds),
// B direct to registers from packed layout.
// R9: MASKED M-TILE SKIP. Rows >= lens[batch] are masked downstream:
//   fc1/fc2 outputs get keep=0; attn never consumes K/V rows >= len
//   (key<len) nor Q rows >= len (inv=0). A 128-row m-tile entirely >= len
//   skips its whole K-loop and writes ZEROS (downstream reads need finite
//   values; zeros == reference's masked values exactly). ~19% of m-tiles
//   (len ~ U[512,1024]). Skip test is block-uniform (tiles never straddle
//   batches) -> no divergent barriers; decided before any barrier.
//   EPI==0 (QKV): n<2048 (Q,K) -> C stride NC; V cols (bn>=2048) stored
//   TRANSPOSED into VT[(b*16+h)*64+d][tok] so attn can DMA-stage V^T.
// ---------------------------------------------------------------------------
template<int EPI, typename OUT>
__global__ __launch_bounds__(256, 3)
void gemm_bp(const bf16_t* __restrict__ A, const bf16_t* __restrict__ Bp,
             const float* __restrict__ bias, const int* __restrict__ lens,
             OUT* __restrict__ C, bf16_t* __restrict__ VTout,
             int M, int N, int NC, int K)
{
    __shared__ __align__(16) bf16_t As[3][128 * 64];

    const int tid  = threadIdx.x;
    const int lane = tid & 63;
    const int w    = tid >> 6;
    const int quad = lane >> 4, l16 = lane & 15;
    const int wm = w & 1, wn = w >> 1;
    const int sw8 = l16 & 7;

    const int nwg  = gridDim.x * gridDim.y;
    const int orig = blockIdx.y * gridDim.x + blockIdx.x;
    const int swz  = (orig & 7) * (nwg >> 3) + (orig >> 3);
    const int bn = (swz % gridDim.x) * 128;
    const int bm = (swz / gridDim.x) * 128;

    // ---- masked m-tile skip (block-uniform) ----
    if (lens != nullptr && (bm & (S_ - 1)) >= lens[bm >> 10]) {
        const uint4 zz = {0u, 0u, 0u, 0u};
        if (EPI == 0 && bn >= 2048) {
            // VT zero: 128 d-rows x 128 tokens (256 B/row), 2048 uint4 total.
            const int bb = bm >> 10, s0 = bm & 1023;
            #pragma unroll
            for (int u = 0; u < 8; u++) {
                const int idx = u * 256 + tid;
                const int row = idx >> 4, c = idx & 15;
                *(uint4*)(VTout + ((size_t)bb * 1024 + (bn - 2048) + row) * 1024
                          + s0 + c * 8) = zz;
            }
        } else {
            // C zero: 128 rows x 128 cols of OUT at stride NC.
            constexpr int UPR = (128 * sizeof(OUT)) / 16;   // uint4 per row
            #pragma unroll
            for (int u = 0; u < (128 * UPR) / 256; u++) {
                const int idx = u * 256 + tid;
                const int row = idx / UPR, c = idx % UPR;
                *(uint4*)((char*)(C + (size_t)(bm + row) * NC + bn) + c * 16) = zz;
            }
        }
        return;
    }

    const int rS  = tid >> 3;
    const int cS  = ((tid & 7) ^ (rS & 7)) << 3;
    const int dOf = w * 1024;

    const size_t ntStride = (size_t)(K >> 3) * 128;
    const bf16_t* Bw = Bp + ((size_t)(bn >> 4) + (size_t)wn * 4) * ntStride
                          + (size_t)quad * 128 + (size_t)l16 * 8;

    f32x4 acc[4][4];
    #pragma unroll
    for (int i = 0; i < 4; i++)
        #pragma unroll
        for (int j = 0; j < 4; j++)
            #pragma unroll
            for (int r = 0; r < 4; r++) acc[i][j][r] = 0.f;

#define SA(b_, kt_) { \
    _Pragma("unroll") \
    for (int s_ = 0; s_ < 4; s_++) \
        gld16(A + (size_t)(bm + s_ * 32 + rS) * K + (kt_) * 64 + cS, \
              (char*)As[b_] + s_ * 4096 + dOf); }
#define LB(dst_, kt_) { \
    _Pragma("unroll") \
    for (int j_ = 0; j_ < 4; j_++) \
        _Pragma("unroll") \
        for (int kh_ = 0; kh_ < 2; kh_++) \
            dst_[j_][kh_] = *(const bf16x8*)(Bw + (size_t)j_ * ntStride \
                                             + ((kt_) * 8 + kh_ * 4) * 128); }
#define KSTEP(cb_, sb_, BC_, BX_, t_) { \
    const int ktn_ = ((t_) + 1 < NKT) ? (t_) + 1 : NKT - 1; \
    const int kt2_ = ((t_) + 2 < NKT) ? (t_) + 2 : NKT - 1; \
    SA(sb_, kt2_); \
    LB(BX_, ktn_); \
    __builtin_amdgcn_sched_barrier(0); \
    const bf16_t* Ac = As[cb_]; \
    _Pragma("unroll") \
    for (int kh_ = 0; kh_ < 2; kh_++) { \
        bf16x8 a_[4]; \
        _Pragma("unroll") \
        for (int i_ = 0; i_ < 4; i_++) \
            a_[i_] = *(const bf16x8*)&Ac[(wm * 64 + i_ * 16 + l16) * 64 \
                                         + (((kh_ * 4 + quad) ^ sw8) << 3)]; \
        _Pragma("unroll") \
        for (int i_ = 0; i_ < 4; i_++) \
            _Pragma("unroll") \
            for (int j_ = 0; j_ < 4; j_++) \
                acc[i_][j_] = __builtin_amdgcn_mfma_f32_16x16x32_bf16( \
                    a_[i_], BC_[j_][kh_], acc[i_][j_], 0, 0, 0); \
    } \
    __builtin_amdgcn_sched_barrier(0); \
    asm volatile("s_waitcnt vmcnt(12)" ::: "memory"); \
    __builtin_amdgcn_s_barrier(); }

    const int NKT = K >> 6;   // 16 here (even; unroll-2 loop)

    bf16x8 bA[4][2], bB[4][2];
    SA(0, 0);                  // A(0) -> buf 0
    SA(1, 1);                  // A(1) -> buf 1
    LB(bA, 0);                 // B(0) -> regs
    asm volatile("s_waitcnt vmcnt(12)" ::: "memory");   // A(0) landed
    __builtin_amdgcn_s_barrier();

    int cb = 0;
    for (int t = 0; t < NKT; t += 2) {
        const int sb0 = cb ? cb - 1 : 2;          // (cb+2)%3
        KSTEP(cb, sb0, bA, bB, t);
        const int cb1 = (cb + 1 == 3) ? 0 : cb + 1;
        const int sb1 = cb1 ? cb1 - 1 : 2;
        KSTEP(cb1, sb1, bB, bA, t + 1);
        cb = (cb1 + 1 == 3) ? 0 : cb1 + 1;
    }

#undef SA
#undef LB
#undef KSTEP

    // ---- epilogue ----
    if (EPI == 0 && bn >= 2048) {
        // V block: transposed store into VT[(n-2048)][tok], 8B per (i,j).
        #pragma unroll
        for (int i = 0; i < 4; i++) {
            const int m0 = bm + wm * 64 + i * 16 + quad * 4;   // 4-aligned
            const int bb = m0 >> 10, s0 = m0 & 1023;
            #pragma unroll
            for (int j = 0; j < 4; j++) {
                const int n = bn + wn * 64 + j * 16 + l16;
                bf16x4v vv;
                #pragma unroll
                for (int r = 0; r < 4; r++) vv[r] = (bf16_t)acc[i][j][r];
                *(bf16x4v*)(VTout + ((size_t)bb * 1024 + (n - 2048)) * 1024 + s0) = vv;
            }
        }
        return;
    }
    #pragma unroll
    for (int i = 0; i < 4; i++) {
        #pragma unroll
        for (int r = 0; r < 4; r++) {
            const int m = bm + wm * 64 + i * 16 + quad * 4 + r;
            float keep = 1.f;
            if (EPI != 0) {
                const int s = m & (S_ - 1);
                const int bb = m >> 10;
                keep = (s < lens[bb]) ? 1.f : 0.f;
            }
            #pragma unroll
            for (int j = 0; j < 4; j++) {
                const int n = bn + wn * 64 + j * 16 + l16;
                float v = acc[i][j][r];
                if (EPI != 0) {
                    v += bias[n];
                    if (EPI == 1) v = fmaxf(v, 0.f);
                    v *= keep;
                }
                C[(size_t)m * NC + n] = (OUT)v;
            }
        }
    }
}

// ---------------------------------------------------------------------------
// bf16 MFMA flash attention, S^T formulation — R7 structure: V^T staged via
// DMA (pre-transposed by the QKV GEMM), K and V^T staged identically with
// chunk-XOR swizzle; no in-kernel transpose, conflicts ~0.
// ---------------------------------------------------------------------------
__global__ __launch_bounds__(512, 6)
void attn_mfma(const bf16_t* __restrict__ QK, const bf16_t* __restrict__ VT,
               const int* __restrict__ lens, bf16_t* __restrict__ Z)
{
    __shared__ __align__(16) bf16_t Ks[2][64][64];   // [buf][key][d], chunk-swizzled
    __shared__ __align__(16) bf16_t Vs[2][64][64];   // [buf][d][tok], chunk-swizzled
    __shared__ __align__(16) bf16_t Ps[128][72];     // [q][key], wave-private rows

    const int tid  = threadIdx.x;
    const int lane = tid & 63;
    const int w    = tid >> 6;          // 0..7
    const int quad = lane >> 4;
    const int l16  = lane & 15;
    const int id   = blockIdx.x;
    const int b    = id & 7;
    const int h    = (id >> 3) & 15;
    const int qt   = id >> 7;           // 0..7
    const int len  = lens[b];
    const int qbase = qt * 128;
    const bf16_t* Qp  = QK + (size_t)b * S_ * 2048 + (size_t)h * 64;
    const bf16_t* Kp  = Qp + 1024;
    const bf16_t* Vtp = VT + ((size_t)b * 16 + h) * 64 * 1024;  // [64 d][1024 tok]
    const size_t zbase = (size_t)b * S_ * D_ + (size_t)h * 64;

    if (qbase >= len) {   // fully masked query tile -> zeros (bf16)
        const int r = tid >> 2, c0 = (tid & 3) * 16;
        bf16_t* zp = Z + zbase + (size_t)(qbase + r) * D_ + c0;
        uint4 zz = {0u, 0u, 0u, 0u};
        *(uint4*)zp = zz;
        *(uint4*)(zp + 8) = zz;
        return;
    }

    // Q B-frags, fixed for the whole kernel: B[k=d=quad*8+j][n=q=l16]
    const int qrow = qbase + w * 16 + l16;
    const bf16x8 bq0 = *(const bf16x8*)(Qp + (size_t)qrow * 2048 + quad * 8);
    const bf16x8 bq1 = *(const bf16x8*)(Qp + (size_t)qrow * 2048 + 32 + quad * 8);

    // staging geometry (K and V^T alike): row sr = tid>>3 (0..63); source
    // chunk = (tid&7) ^ (sr&7); LDS linear dest (thread tid -> byte tid*16).
    const int sr = tid >> 3;
    const int sc = ((tid & 7) ^ (sr & 7)) << 3;

    f32x4 o[4];
    #pragma unroll
    for (int dm = 0; dm < 4; dm++)
        #pragma unroll
        for (int r = 0; r < 4; r++) o[dm][r] = 0.f;
    float l_q = 0.f;

    const int ntiles = (len + 63) >> 6;

    // ---- prologue: stage K(0), V^T(0) ----
    gld16(Kp  + (size_t)sr * 2048 + sc, (char*)&Ks[0][0][0] + w * 1024);
    gld16(Vtp + (size_t)sr * 1024 + sc, (char*)&Vs[0][0][0] + w * 1024);
    __syncthreads();

    for (int t = 0; t < ntiles; t++) {
        const int k0 = t * 64;
        const int cb = t & 1, nb = (t + 1) & 1;
        const int kn0 = (t + 1 < ntiles ? t + 1 : t) * 64;

        // ---- issue DMA prefetch for tile t+1 ----
        gld16(Kp  + (size_t)(kn0 + sr) * 2048 + sc, (char*)&Ks[nb][0][0] + w * 1024);
        gld16(Vtp + (size_t)sr * 1024 + kn0 + sc,   (char*)&Vs[nb][0][0] + w * 1024);
        __builtin_amdgcn_sched_barrier(0);

        // ---- S^T = K Q^T from Ks[cb], exp, stage P ----
        #pragma unroll
        for (int kt = 0; kt < 4; kt++) {
            const int r = kt * 16 + l16;           // r&7 == l16&7
            const bf16x8 ak0 = *(const bf16x8*)&Ks[cb][r][(quad ^ (l16 & 7)) << 3];
            const bf16x8 ak1 = *(const bf16x8*)&Ks[cb][r][((4 + quad) ^ (l16 & 7)) << 3];
            f32x4 z4 = {0.f, 0.f, 0.f, 0.f};
            z4 = __builtin_amdgcn_mfma_f32_16x16x32_bf16(ak0, bq0, z4, 0, 0, 0);
            const f32x4 sfv = __builtin_amdgcn_mfma_f32_16x16x32_bf16(ak1, bq1, z4, 0, 0, 0);
            bf16x4v pk;
            #pragma unroll
            for (int r2 = 0; r2 < 4; r2++) {
                const int key = k0 + kt * 16 + quad * 4 + r2;
                float p = __expf(sfv[r2] * 0.125f);
                p = (key < len) ? p : 0.f;
                l_q += p;
                pk[r2] = (bf16_t)p;
            }
            *(bf16x4v*)&Ps[w * 16 + l16][kt * 16 + quad * 4] = pk;
        }

        __syncthreads();   // bar1: K/V(t+1) DMA drained, Ps rows complete

        // ---- O^T += V^T P^T from Vs[cb] ----
        const bf16x8 bp0 = *(const bf16x8*)&Ps[w * 16 + l16][quad * 8];
        const bf16x8 bp1 = *(const bf16x8*)&Ps[w * 16 + l16][32 + quad * 8];
        #pragma unroll
        for (int dm = 0; dm < 4; dm++) {
            const int vr = dm * 16 + l16;          // vr&7 == l16&7
            const bf16x8 av0 = *(const bf16x8*)&Vs[cb][vr][(quad ^ (l16 & 7)) << 3];
            const bf16x8 av1 = *(const bf16x8*)&Vs[cb][vr][((4 + quad) ^ (l16 & 7)) << 3];
            o[dm] = __builtin_amdgcn_mfma_f32_16x16x32_bf16(av0, bp0, o[dm], 0, 0, 0);
            o[dm] = __builtin_amdgcn_mfma_f32_16x16x32_bf16(av1, bp1, o[dm], 0, 0, 0);
        }

        // bar2: all waves done reading Vs[cb]/Ks[cb] before next-iter DMA
        // re-targets buffer cb.
        __builtin_amdgcn_sched_barrier(0);
        __builtin_amdgcn_s_barrier();
        __builtin_amdgcn_sched_barrier(0);
    }

    // ---- final l reduce + epilogue ----
    l_q += __shfl_xor(l_q, 16);
    l_q += __shfl_xor(l_q, 32);
    const int qg = qbase + w * 16 + l16;
    const float inv = (qg < len) ? 1.f / l_q : 0.f;
    bf16_t* zrow = Z + zbase + (size_t)qg * D_;
    #pragma unroll
    for (int dm = 0; dm < 4; dm++) {
        bf16x4v st;
        #pragma unroll
        for (int r = 0; r < 4; r++) st[r] = (bf16_t)(o[dm][r] * inv);
        *(bf16x4v*)(zrow + dm * 16 + quad * 4) = st;
    }
}

// ---------------------------------------------------------------------------
// Residual-add + LayerNorm, D=1024, one block per row.
// ---------------------------------------------------------------------------
__device__ __forceinline__ void ln_core(float vx, float vy, float vz, float vw,
                                        int tid, float& mean, float& rstd)
{
    __shared__ float red[8];
    float s = vx + vy + vz + vw;
    #pragma unroll
    for (int off = 32; off; off >>= 1) s += __shfl_xor(s, off, 64);
    const int wv = tid >> 6, lane = tid & 63;
    if (lane == 0) red[wv] = s;
    __syncthreads();
    mean = (red[0] + red[1] + red[2] + red[3]) * (1.f / D_);
    const float dx = vx - mean, dy = vy - mean, dz = vz - mean, dw = vw - mean;
    float s2 = dx * dx + dy * dy + dz * dz + dw * dw;
    #pragma unroll
    for (int off = 32; off; off >>= 1) s2 += __shfl_xor(s2, off, 64);
    if (lane == 0) red[4 + wv] = s2;
    __syncthreads();
    rstd = rsqrtf((red[4] + red[5] + red[6] + red[7]) * (1.f / D_) + EPS_);
}

__global__ __launch_bounds__(256)
void add_ln1(const float* __restrict__ X, const bf16_t* __restrict__ Y,
             const float* __restrict__ g, const float* __restrict__ beta,
             bf16_t* __restrict__ out)
{
    const int row = blockIdx.x, tid = threadIdx.x;
    const float4 xv = ((const float4*)(X + (size_t)row * D_))[tid];
    const bf16x4v yv = *(const bf16x4v*)(Y + (size_t)row * D_ + tid * 4);
    const float vx = xv.x + (float)yv[0], vy = xv.y + (float)yv[1];
    const float vz = xv.z + (float)yv[2], vw = xv.w + (float)yv[3];
    float mean, rstd;
    ln_core(vx, vy, vz, vw, tid, mean, rstd);
    const float4 gv = ((const float4*)g)[tid];
    const float4 bv = ((const float4*)beta)[tid];
    bf16x4v o;
    o[0] = (bf16_t)((vx - mean) * rstd * gv.x + bv.x);
    o[1] = (bf16_t)((vy - mean) * rstd * gv.y + bv.y);
    o[2] = (bf16_t)((vz - mean) * rstd * gv.z + bv.z);
    o[3] = (bf16_t)((vw - mean) * rstd * gv.w + bv.w);
    *(bf16x4v*)(out + (size_t)row * D_ + tid * 4) = o;
}

__global__ __launch_bounds__(256)
void add_ln2(const bf16_t* __restrict__ X, const float* __restrict__ Y,
             const float* __restrict__ g, const float* __restrict__ beta,
             float* __restrict__ out)
{
    const int row = blockIdx.x, tid = threadIdx.x;
    const bf16x4v xv = *(const bf16x4v*)(X + (size_t)row * D_ + tid * 4);
    const float4 yv = ((const float4*)(Y + (size_t)row * D_))[tid];
    const float vx = (float)xv[0] + yv.x, vy = (float)xv[1] + yv.y;
    const float vz = (float)xv[2] + yv.z, vw = (float)xv[3] + yv.w;
    float mean, rstd;
    ln_core(vx, vy, vz, vw, tid, mean, rstd);
    const float4 gv = ((const float4*)g)[tid];
    const float4 bv = ((const float4*)beta)[tid];
    float4 o;
    o.x = (vx - mean) * rstd * gv.x + bv.x;
    o.y = (vy - mean) * rstd * gv.y + bv.y;
    o.z = (vz - mean) * rstd * gv.z + bv.z;
    o.w = (vw - mean) * rstd * gv.w + bv.w;
    ((float4*)(out + (size_t)row * D_))[tid] = o;
}

// ---------------------------------------------------------------------------
extern "C" void kernel_launch(void* const* d_in, const int* in_sizes, int n_in,
                              void* d_out, int out_size, void* d_ws, size_t ws_size,
                              hipStream_t stream)
{
    const float* x    = (const float*)d_in[0];
    const float* Wq   = (const float*)d_in[1];
    const float* Wk   = (const float*)d_in[2];
    const float* Wv   = (const float*)d_in[3];
    const float* fc1w = (const float*)d_in[4];
    const float* fc1b = (const float*)d_in[5];
    const float* fc2w = (const float*)d_in[6];
    const float* fc2b = (const float*)d_in[7];
    const float* ln1w = (const float*)d_in[8];
    const float* ln1b = (const float*)d_in[9];
    const float* ln2w = (const float*)d_in[10];
    const float* ln2b = (const float*)d_in[11];
    const int*   lens = (const int*)d_in[12];
    float* out = (float*)d_out;

    char* ws = (char*)d_ws;
    const size_t MB = 1024 * 1024;
    bf16_t* QKb   = (bf16_t*)(ws);              // 32 MB: [8192][2048] (Q,K)
    bf16_t* VTb   = (bf16_t*)(ws + 32 * MB);    // 16 MB: [8*16*64][1024] (V^T)
    bf16_t* Zb    = (bf16_t*)(ws + 48 * MB);    // 16 MB: [8192][1024] bf16
    bf16_t* X1b   = (bf16_t*)(ws + 80 * MB);    // 16 MB
    bf16_t* xb    = (bf16_t*)(ws + 96 * MB);    // 16 MB (dead after QKV)
    bf16_t* H1b   = (bf16_t*)(ws + 96 * MB);    //   reuses xb slot
    float*  FF    = (float*)(ws + 48 * MB);     //   reuses Zb slot (32 MB)
    bf16_t* WtQKV = (bf16_t*)(ws + 112 * MB);   // 6 MB (packed)
    bf16_t* Wt1   = (bf16_t*)(ws + 118 * MB);   // 2 MB (packed)
    bf16_t* Wt2   = (bf16_t*)(ws + 120 * MB);   // 2 MB (packed)

    const int M = B_ * S_;

    prep<<<dim3(16, 16, 37), 256, 0, stream>>>(x, Wq, Wk, Wv, fc1w, fc2w,
                                               xb, WtQKV, Wt1, Wt2);

    gemm_bp<0, bf16_t><<<dim3(3072 / 128, M / 128), 256, 0, stream>>>(
        xb, WtQKV, nullptr, lens, QKb, VTb, M, 3072, 2048, D_);

    attn_mfma<<<dim3(1024), 512, 0, stream>>>(QKb, VTb, lens, Zb);

    add_ln1<<<M, 256, 0, stream>>>(x, Zb, ln1w, ln1b, X1b);

    gemm_bp<1, bf16_t><<<dim3(D_ / 128, M / 128), 256, 0, stream>>>(
        X1b, Wt1, fc1b, lens, H1b, nullptr, M, D_, D_, D_);
    gemm_bp<2, float><<<dim3(D_ / 128, M / 128), 256, 0, stream>>>(
        H1b, Wt2, fc2b, lens, FF, nullptr, M, D_, D_, D_);

    add_ln2<<<M, 256, 0, stream>>>(X1b, FF, ln2w, ln2b, out);
}